// Round 1
// 1284.600 us; speedup vs baseline: 1.1380x; 1.1380x over previous
//
#include <hip/hip_runtime.h>

namespace {
constexpr int kT = 1024, kD = 2048, kH = 16, kNOPE = 128, kROPE = 64, kVD = 128, kQKD = 192;
constexpr int kQL = 768, kKVL = 512, kIH = 32, kID = 128, kTOPK = 256, kE = 8, kF = 1024;
constexpr int kQKV_N = kQL + kKVL + kROPE; // 1344
constexpr int kQKV_NP = 1408;              // padded to 128
}

typedef __attribute__((ext_vector_type(4))) float floatx4;
typedef __attribute__((ext_vector_type(8))) short short8;
typedef unsigned short u16;

// ---------------- device helpers ----------------
__device__ __forceinline__ float wsum(float v) {
#pragma unroll
  for (int o = 32; o; o >>= 1) v += __shfl_xor(v, o, 64);
  return v;
}
__device__ __forceinline__ float wmax64(float v) {
#pragma unroll
  for (int o = 32; o; o >>= 1) v = fmaxf(v, __shfl_xor(v, o, 64));
  return v;
}
__device__ __forceinline__ int wsum_i(int v) {
#pragma unroll
  for (int o = 32; o; o >>= 1) v += __shfl_xor(v, o, 64);
  return v;
}
__device__ __forceinline__ float bsum256(float v, float* red) {
  v = wsum(v);
  if ((threadIdx.x & 63) == 0) red[threadIdx.x >> 6] = v;
  __syncthreads();
  float t = red[0] + red[1] + red[2] + red[3];
  __syncthreads();
  return t;
}
__device__ __forceinline__ unsigned sortkey(float f) {
  unsigned b = __float_as_uint(f);
  return (b & 0x80000000u) ? ~b : (b | 0x80000000u);
}
__device__ __forceinline__ float pow2ceil(float z) {
  unsigned b = __float_as_uint(z);
  if ((b & 0x7FFFFFu) == 0) return z;
  return __uint_as_float((((b >> 23) & 0xFFu) + 1u) << 23);
}
__device__ __forceinline__ float fp8q(float x) {
  float ax = fabsf(x);
  float q;
  if (ax < 0.015625f) {
    q = rintf(ax * 512.0f) * 0.001953125f;
  } else {
    unsigned b = __float_as_uint(ax);
    int e = (int)((b >> 23) & 0xFF) - 127;
    float quant = __uint_as_float((unsigned)(e - 3 + 127) << 23);
    float rq    = __uint_as_float((unsigned)(127 - (e - 3)) << 23);
    q = rintf(ax * rq) * quant;
  }
  return copysignf(q, x);
}
__device__ __forceinline__ u16 f2bf(float x) {
  unsigned u = __float_as_uint(x);
  u += 0x7FFFu + ((u >> 16) & 1u);
  return (u16)(u >> 16);
}
__device__ __forceinline__ float bf2f(u16 h) { return __uint_as_float((unsigned)h << 16); }

// async global->LDS, 16B per lane; lds ptr must be wave-uniform (HW adds lane*16)
__device__ __forceinline__ void gld_lds16(const void* g, void* l) {
  __builtin_amdgcn_global_load_lds(
      (const __attribute__((address_space(1))) unsigned int*)(unsigned long long)g,
      (__attribute__((address_space(3))) unsigned int*)(unsigned int)(unsigned long long)l,
      16, 0, 0);
}
// stage 128 rows x 32 bf16 cols; wave stages rows [wave*32, wave*32+32)
__device__ __forceinline__ void stage_tile(const u16* g, size_t strideUs, u16* tile, int wave, int lane) {
  int r = lane >> 2, c = lane & 3;
  const u16* gp = g + (size_t)(wave * 32 + r) * strideUs + c * 8;
  gld_lds16(gp, tile + (wave * 32) * 32);
  gld_lds16(gp + (size_t)16 * strideUs, tile + (wave * 32 + 16) * 32);
}

// ---------------- weight prep: f32 [K][N] -> bf16 BT [Npad][K] (+optional lo) ----------------
__global__ __launch_bounds__(256) void k_transpose_w(const float* __restrict__ in, u16* __restrict__ hi,
                                                     u16* __restrict__ lo, int K, int N, int Npad) {
  __shared__ float tile[32][33];
  int n0 = blockIdx.x * 32, k0 = blockIdx.y * 32;
  const float* ip = in + (size_t)blockIdx.z * K * N;
  u16* hp = hi + (size_t)blockIdx.z * Npad * K;
  u16* lp = lo ? lo + (size_t)blockIdx.z * Npad * K : nullptr;
  int t = threadIdx.x;
  int r = t >> 3, c4 = (t & 7) << 2;
  if (n0 < N) {
    float4 v = *(const float4*)&ip[(size_t)(k0 + r) * N + n0 + c4];
    tile[r][c4] = v.x; tile[r][c4 + 1] = v.y; tile[r][c4 + 2] = v.z; tile[r][c4 + 3] = v.w;
  } else {
    tile[r][c4] = 0.f; tile[r][c4 + 1] = 0.f; tile[r][c4 + 2] = 0.f; tile[r][c4 + 3] = 0.f;
  }
  __syncthreads();
  int n = t >> 3, kq = (t & 7) << 2;
  ushort4 h4, l4;
#pragma unroll
  for (int j = 0; j < 4; j++) {
    float f = tile[kq + j][n];
    u16 h = f2bf(f);
    ((u16*)&h4)[j] = h;
    ((u16*)&l4)[j] = f2bf(f - bf2f(h));
  }
  *(ushort4*)&hp[(size_t)(n0 + n) * K + k0 + kq] = h4;
  if (lp) *(ushort4*)&lp[(size_t)(n0 + n) * K + k0 + kq] = l4;
}

// ---------------- GEMM family: bf16 A [M][K], bf16 BT [N][K], global_load_lds staging ----------
// 128x128 tile, BK=32, 4 waves in 2x2 quadrants.

__global__ __launch_bounds__(256) void k_gemm_bt(const u16* __restrict__ A, const u16* __restrict__ BT,
                                                 float* __restrict__ C, const float* __restrict__ addend,
                                                 int M, int N, int K) {
  __shared__ __align__(16) u16 As[128 * 32];
  __shared__ __align__(16) u16 Bs[128 * 32];
  int tid = threadIdx.x, wave = tid >> 6, lane = tid & 63;
  int bm = blockIdx.y * 128, bn = blockIdx.x * 128;
  int wy = (wave >> 1) * 64, wx = (wave & 1) * 64;
  int lm = lane & 15, lk = lane >> 4;
  const u16* Ab = A + (size_t)bm * K;
  const u16* Bb = BT + (size_t)bn * K;
  floatx4 acc[4][4] = {};
  for (int k0 = 0; k0 < K; k0 += 32) {
    stage_tile(Ab + k0, K, As, wave, lane);
    stage_tile(Bb + k0, K, Bs, wave, lane);
    __syncthreads();
    short8 af[4], bfr[4];
#pragma unroll
    for (int mt = 0; mt < 4; mt++) af[mt] = *(short8*)&As[(wy + mt * 16 + lm) * 32 + lk * 8];
#pragma unroll
    for (int nt = 0; nt < 4; nt++) bfr[nt] = *(short8*)&Bs[(wx + nt * 16 + lm) * 32 + lk * 8];
#pragma unroll
    for (int mt = 0; mt < 4; mt++)
#pragma unroll
      for (int nt = 0; nt < 4; nt++)
        acc[mt][nt] = __builtin_amdgcn_mfma_f32_16x16x32_bf16(af[mt], bfr[nt], acc[mt][nt], 0, 0, 0);
    __syncthreads();
  }
#pragma unroll
  for (int mt = 0; mt < 4; mt++)
#pragma unroll
    for (int nt = 0; nt < 4; nt++)
#pragma unroll
      for (int r = 0; r < 4; r++) {
        int m = bm + wy + mt * 16 + lk * 4 + r;
        int n = bn + wx + nt * 16 + lm;
        float v = acc[mt][nt][r];
        if (addend) v += addend[(size_t)m * N + n];
        C[(size_t)m * N + n] = v;
      }
}

// 3-term split-precision GEMM: C = Ahi*Bhi + Ahi*Blo + Alo*Bhi (f32-class accuracy).
// N may be < padded BT rows; C guarded & strided by N.
__global__ __launch_bounds__(256) void k_gemm_split(const u16* __restrict__ Ah, const u16* __restrict__ Al,
                                                    const u16* __restrict__ Bh, const u16* __restrict__ Bl,
                                                    float* __restrict__ C, int M, int N, int K) {
  __shared__ __align__(16) u16 Ahs[128 * 32];
  __shared__ __align__(16) u16 Als[128 * 32];
  __shared__ __align__(16) u16 Bhs[128 * 32];
  __shared__ __align__(16) u16 Bls[128 * 32];
  int tid = threadIdx.x, wave = tid >> 6, lane = tid & 63;
  int bm = blockIdx.y * 128, bn = blockIdx.x * 128;
  int wy = (wave >> 1) * 64, wx = (wave & 1) * 64;
  int lm = lane & 15, lk = lane >> 4;
  floatx4 acc[4][4] = {};
  for (int k0 = 0; k0 < K; k0 += 32) {
    stage_tile(Ah + (size_t)bm * K + k0, K, Ahs, wave, lane);
    stage_tile(Al + (size_t)bm * K + k0, K, Als, wave, lane);
    stage_tile(Bh + (size_t)bn * K + k0, K, Bhs, wave, lane);
    stage_tile(Bl + (size_t)bn * K + k0, K, Bls, wave, lane);
    __syncthreads();
    short8 ah[4], al[4], bh[4], bl[4];
#pragma unroll
    for (int mt = 0; mt < 4; mt++) { ah[mt] = *(short8*)&Ahs[(wy + mt * 16 + lm) * 32 + lk * 8];
                                     al[mt] = *(short8*)&Als[(wy + mt * 16 + lm) * 32 + lk * 8]; }
#pragma unroll
    for (int nt = 0; nt < 4; nt++) { bh[nt] = *(short8*)&Bhs[(wx + nt * 16 + lm) * 32 + lk * 8];
                                     bl[nt] = *(short8*)&Bls[(wx + nt * 16 + lm) * 32 + lk * 8]; }
#pragma unroll
    for (int mt = 0; mt < 4; mt++)
#pragma unroll
      for (int nt = 0; nt < 4; nt++) {
        floatx4 a = acc[mt][nt];
        a = __builtin_amdgcn_mfma_f32_16x16x32_bf16(al[mt], bh[nt], a, 0, 0, 0);
        a = __builtin_amdgcn_mfma_f32_16x16x32_bf16(ah[mt], bl[nt], a, 0, 0, 0);
        a = __builtin_amdgcn_mfma_f32_16x16x32_bf16(ah[mt], bh[nt], a, 0, 0, 0);
        acc[mt][nt] = a;
      }
    __syncthreads();
  }
#pragma unroll
  for (int mt = 0; mt < 4; mt++)
#pragma unroll
    for (int nt = 0; nt < 4; nt++)
#pragma unroll
      for (int r = 0; r < 4; r++) {
        int m = bm + wy + mt * 16 + lk * 4 + r;
        int n = bn + wx + nt * 16 + lm;
        if (n < N) C[(size_t)m * N + n] = acc[mt][nt][r];
      }
}

// dual-B gate+up with silu epilogue -> bf16 out; optional row gather (MoE), z = expert
__global__ __launch_bounds__(256) void k_dual_bt(const u16* __restrict__ A, const u16* __restrict__ GT,
                                                 const u16* __restrict__ UT, u16* __restrict__ out,
                                                 const int* __restrict__ toki, const int* __restrict__ cnt,
                                                 int M, int N, int K) {
  int e = blockIdx.z;
  int n_rows = toki ? cnt[e] : M;
  int bm = blockIdx.y * 128;
  if (bm >= n_rows) return;
  int bn = blockIdx.x * 128;
  const int* tk = toki ? (toki + e * kT) : nullptr;
  const u16* Gb = GT + (size_t)e * N * K + (size_t)bn * K;
  const u16* Ub = UT + (size_t)e * N * K + (size_t)bn * K;
  u16* oP = out + (size_t)e * kT * N;
  __shared__ __align__(16) u16 As[128 * 32];
  __shared__ __align__(16) u16 Gs[128 * 32];
  __shared__ __align__(16) u16 Us[128 * 32];
  int tid = threadIdx.x, wave = tid >> 6, lane = tid & 63;
  int wy = (wave >> 1) * 64, wx = (wave & 1) * 64;
  int lm = lane & 15, lk = lane >> 4;
  int r = lane >> 2, c = lane & 3;
  int r0 = bm + wave * 32 + r, r1 = r0 + 16;
  size_t arow0 = tk ? (size_t)((r0 < n_rows) ? tk[r0] : 0) : (size_t)r0;
  size_t arow1 = tk ? (size_t)((r1 < n_rows) ? tk[r1] : 0) : (size_t)r1;
  floatx4 ag[4][4] = {}, au[4][4] = {};
  for (int k0 = 0; k0 < K; k0 += 32) {
    gld_lds16(A + arow0 * K + k0 + c * 8, As + (wave * 32) * 32);
    gld_lds16(A + arow1 * K + k0 + c * 8, As + (wave * 32 + 16) * 32);
    stage_tile(Gb + k0, K, Gs, wave, lane);
    stage_tile(Ub + k0, K, Us, wave, lane);
    __syncthreads();
    short8 af[4], gf[4], uf[4];
#pragma unroll
    for (int mt = 0; mt < 4; mt++) af[mt] = *(short8*)&As[(wy + mt * 16 + lm) * 32 + lk * 8];
#pragma unroll
    for (int nt = 0; nt < 4; nt++) { gf[nt] = *(short8*)&Gs[(wx + nt * 16 + lm) * 32 + lk * 8];
                                     uf[nt] = *(short8*)&Us[(wx + nt * 16 + lm) * 32 + lk * 8]; }
#pragma unroll
    for (int mt = 0; mt < 4; mt++)
#pragma unroll
      for (int nt = 0; nt < 4; nt++) {
        ag[mt][nt] = __builtin_amdgcn_mfma_f32_16x16x32_bf16(af[mt], gf[nt], ag[mt][nt], 0, 0, 0);
        au[mt][nt] = __builtin_amdgcn_mfma_f32_16x16x32_bf16(af[mt], uf[nt], au[mt][nt], 0, 0, 0);
      }
    __syncthreads();
  }
#pragma unroll
  for (int mt = 0; mt < 4; mt++)
#pragma unroll
    for (int nt = 0; nt < 4; nt++)
#pragma unroll
      for (int r2 = 0; r2 < 4; r2++) {
        int gm = bm + wy + mt * 16 + lk * 4 + r2;
        if (gm >= n_rows) continue;
        int n = bn + wx + nt * 16 + lm;
        float gv = ag[mt][nt][r2], uv = au[mt][nt][r2];
        oP[(size_t)gm * N + n] = f2bf(gv * (1.0f / (1.0f + expf(-gv))) * uv);
      }
}

// down: out[tok] += w * (hmid[e] @ wd[e]); A compact bf16 per expert; atomic scatter f32
__global__ __launch_bounds__(256) void k_down_bt(const u16* __restrict__ hmid, const u16* __restrict__ DT,
                                                 const int* __restrict__ toki, const float* __restrict__ tokw,
                                                 const int* __restrict__ cnt, float* __restrict__ out) {
  int e = blockIdx.z;
  int n_rows = cnt[e];
  int bm = blockIdx.y * 128;
  if (bm >= n_rows) return;
  int bn = blockIdx.x * 128;
  const u16* Ab = hmid + (size_t)e * kT * kF + (size_t)bm * kF;
  const u16* Bb = DT + (size_t)e * kD * kF + (size_t)bn * kF;
  __shared__ __align__(16) u16 As[128 * 32];
  __shared__ __align__(16) u16 Bs[128 * 32];
  int tid = threadIdx.x, wave = tid >> 6, lane = tid & 63;
  int wy = (wave >> 1) * 64, wx = (wave & 1) * 64;
  int lm = lane & 15, lk = lane >> 4;
  floatx4 acc[4][4] = {};
  for (int k0 = 0; k0 < kF; k0 += 32) {
    stage_tile(Ab + k0, kF, As, wave, lane);
    stage_tile(Bb + k0, kF, Bs, wave, lane);
    __syncthreads();
    short8 af[4], bfr[4];
#pragma unroll
    for (int mt = 0; mt < 4; mt++) af[mt] = *(short8*)&As[(wy + mt * 16 + lm) * 32 + lk * 8];
#pragma unroll
    for (int nt = 0; nt < 4; nt++) bfr[nt] = *(short8*)&Bs[(wx + nt * 16 + lm) * 32 + lk * 8];
#pragma unroll
    for (int mt = 0; mt < 4; mt++)
#pragma unroll
      for (int nt = 0; nt < 4; nt++)
        acc[mt][nt] = __builtin_amdgcn_mfma_f32_16x16x32_bf16(af[mt], bfr[nt], acc[mt][nt], 0, 0, 0);
    __syncthreads();
  }
#pragma unroll
  for (int mt = 0; mt < 4; mt++)
#pragma unroll
    for (int r = 0; r < 4; r++) {
      int gm = bm + wy + mt * 16 + lk * 4 + r;
      if (gm >= n_rows) continue;
      int tt = toki[e * kT + gm];
      float w = tokw[e * kT + gm];
#pragma unroll
      for (int nt = 0; nt < 4; nt++) {
        int n = bn + wx + nt * 16 + lm;
        atomicAdd(&out[(size_t)tt * kD + n], w * acc[mt][nt][r]);
      }
    }
}

// ---------------- flash MFMA attention (bf16 out) ----------------
__global__ __launch_bounds__(256) void k_attn_mfma(const float* __restrict__ q, const float* __restrict__ kv,
                                                   const float* __restrict__ kpe,
                                                   const unsigned long long* __restrict__ mbits,
                                                   u16* __restrict__ o) {
  __shared__ __align__(16) u16 Ks[64 * 200];
  __shared__ __align__(16) u16 Vs[128 * 72];
  __shared__ __align__(16) u16 Ps[4 * 16 * 72];
  int h = blockIdx.y;
  int qb = gridDim.x - 1 - blockIdx.x;
  int qbase = qb * 64;
  int tid = threadIdx.x;
  int wave = tid >> 6, lane = tid & 63;
  int lm = lane & 15, lk = lane >> 4;
  short8 qf[6];
  {
    const float* qrow = q + ((size_t)(qbase + wave * 16 + lm) * kH + h) * kQKD;
#pragma unroll
    for (int ks = 0; ks < 6; ks++) {
      const float4 a0 = *(const float4*)&qrow[ks * 32 + lk * 8];
      const float4 a1 = *(const float4*)&qrow[ks * 32 + lk * 8 + 4];
      short8 f;
      f[0] = (short)f2bf(a0.x); f[1] = (short)f2bf(a0.y); f[2] = (short)f2bf(a0.z); f[3] = (short)f2bf(a0.w);
      f[4] = (short)f2bf(a1.x); f[5] = (short)f2bf(a1.y); f[6] = (short)f2bf(a1.z); f[7] = (short)f2bf(a1.w);
      qf[ks] = f;
    }
  }
  float m_r[4] = {-1e30f, -1e30f, -1e30f, -1e30f};
  float l_r[4] = {};
  floatx4 Oacc[8] = {};
  int sr = tid >> 2, sj = tid & 3;
  int nch = qb + 1;
  for (int ch = 0; ch < nch; ch++) {
    int s0 = ch << 6;
    __syncthreads();
    {
      const float* kvrow = kv + ((size_t)(s0 + sr) * kH + h) * 256;
      const float* kprow = kpe + (size_t)(s0 + sr) * 64;
#pragma unroll
      for (int i = 0; i < 12; i++) {
        int c4 = (i << 2) + sj;
        float4 v4 = (c4 < 32) ? *(const float4*)&kvrow[c4 * 4] : *(const float4*)&kprow[(c4 - 32) * 4];
        ushort4 p; p.x = f2bf(v4.x); p.y = f2bf(v4.y); p.z = f2bf(v4.z); p.w = f2bf(v4.w);
        *(ushort4*)&Ks[sr * 200 + c4 * 4] = p;
      }
      const float* vrow = kvrow + 128;
#pragma unroll
      for (int i = 0; i < 8; i++) {
        int c4 = (i << 2) + sj;
        float4 v4 = *(const float4*)&vrow[c4 * 4];
        Vs[(c4 * 4 + 0) * 72 + sr] = f2bf(v4.x);
        Vs[(c4 * 4 + 1) * 72 + sr] = f2bf(v4.y);
        Vs[(c4 * 4 + 2) * 72 + sr] = f2bf(v4.z);
        Vs[(c4 * 4 + 3) * 72 + sr] = f2bf(v4.w);
      }
    }
    __syncthreads();
    floatx4 sacc[4] = {};
#pragma unroll
    for (int ks = 0; ks < 6; ks++) {
      short8 kf[4];
#pragma unroll
      for (int nt = 0; nt < 4; nt++) kf[nt] = *(short8*)&Ks[(nt * 16 + lm) * 200 + ks * 32 + lk * 8];
#pragma unroll
      for (int nt = 0; nt < 4; nt++)
        sacc[nt] = __builtin_amdgcn_mfma_f32_16x16x32_bf16(qf[ks], kf[nt], sacc[nt], 0, 0, 0);
    }
    unsigned long long mw[4];
#pragma unroll
    for (int r = 0; r < 4; r++) mw[r] = mbits[(size_t)(qbase + wave * 16 + lk * 4 + r) * 16 + ch];
    float mx[4] = {-1e30f, -1e30f, -1e30f, -1e30f};
#pragma unroll
    for (int nt = 0; nt < 4; nt++)
#pragma unroll
      for (int r = 0; r < 4; r++) {
        int sel = (int)((mw[r] >> (nt * 16 + lm)) & 1ull);
        float sv = sel ? sacc[nt][r] * 0.07216878364870323f : -1e30f;
        sacc[nt][r] = sv;
        mx[r] = fmaxf(mx[r], sv);
      }
#pragma unroll
    for (int off = 1; off < 16; off <<= 1)
#pragma unroll
      for (int r = 0; r < 4; r++) mx[r] = fmaxf(mx[r], __shfl_xor(mx[r], off, 64));
    float al[4], psum[4] = {};
#pragma unroll
    for (int r = 0; r < 4; r++) {
      float mnew = fmaxf(m_r[r], mx[r]);
      al[r] = __expf(m_r[r] - mnew);
      m_r[r] = mnew;
    }
#pragma unroll
    for (int nt = 0; nt < 4; nt++)
#pragma unroll
      for (int r = 0; r < 4; r++) {
        float p = (sacc[nt][r] > -0.9e30f) ? __expf(sacc[nt][r] - m_r[r]) : 0.0f;
        psum[r] += p;
        Ps[wave * 1152 + (lk * 4 + r) * 72 + nt * 16 + lm] = f2bf(p);
      }
#pragma unroll
    for (int off = 1; off < 16; off <<= 1)
#pragma unroll
      for (int r = 0; r < 4; r++) psum[r] += __shfl_xor(psum[r], off, 64);
#pragma unroll
    for (int r = 0; r < 4; r++) l_r[r] = l_r[r] * al[r] + psum[r];
#pragma unroll
    for (int nv = 0; nv < 8; nv++)
#pragma unroll
      for (int r = 0; r < 4; r++) Oacc[nv][r] *= al[r];
    short8 pf[2];
#pragma unroll
    for (int k2 = 0; k2 < 2; k2++) pf[k2] = *(short8*)&Ps[wave * 1152 + lm * 72 + k2 * 32 + lk * 8];
#pragma unroll
    for (int k2 = 0; k2 < 2; k2++)
#pragma unroll
      for (int nv = 0; nv < 8; nv++) {
        short8 vf = *(short8*)&Vs[(nv * 16 + lm) * 72 + k2 * 32 + lk * 8];
        Oacc[nv] = __builtin_amdgcn_mfma_f32_16x16x32_bf16(pf[k2], vf, Oacc[nv], 0, 0, 0);
      }
  }
  float invl[4];
#pragma unroll
  for (int r = 0; r < 4; r++) invl[r] = 1.0f / l_r[r];
#pragma unroll
  for (int nv = 0; nv < 8; nv++)
#pragma unroll
    for (int r = 0; r < 4; r++) {
      int t_row = qbase + wave * 16 + lk * 4 + r;
      o[((size_t)t_row * kH + h) * kVD + nv * 16 + lm] = f2bf(Oacc[nv][r] * invl[r]);
    }
}

// ---------------- norm / small kernels ----------------
__global__ __launch_bounds__(256) void k_add_rms(const float* __restrict__ h, const float* __restrict__ r,
                                                 const float* __restrict__ w, float* __restrict__ resid,
                                                 float* __restrict__ out, u16* __restrict__ oh,
                                                 u16* __restrict__ ol) {
  __shared__ float row[kD];
  __shared__ float red[4];
  int t = blockIdx.x;
  size_t base = (size_t)t * kD;
  float ss = 0.f;
  for (int c = threadIdx.x; c < kD; c += 256) {
    float v = h[base + c] + r[base + c];
    row[c] = v; resid[base + c] = v; ss += v * v;
  }
  float tot = bsum256(ss, red);
  float inv = 1.0f / sqrtf(tot * (1.0f / kD) + 1e-6f);
  for (int c = threadIdx.x; c < kD; c += 256) {
    float v = row[c] * inv * w[c];
    out[base + c] = v;
    u16 hb = f2bf(v);
    oh[base + c] = hb;
    ol[base + c] = f2bf(v - bf2f(hb));
  }
}

// rmsnorm with optional f32 / bf16-hi / bf16-lo outputs
__global__ __launch_bounds__(256) void k_rms_rows(const float* __restrict__ in, int stride, int off,
                                                  const float* __restrict__ w, float* __restrict__ outf,
                                                  u16* __restrict__ oh, u16* __restrict__ ol, int cols) {
  __shared__ float row[kD];
  __shared__ float red[4];
  int t = blockIdx.x;
  const float* x = in + (size_t)t * stride + off;
  float ss = 0.f;
  for (int c = threadIdx.x; c < cols; c += 256) { float v = x[c]; row[c] = v; ss += v * v; }
  float tot = bsum256(ss, red);
  float inv = 1.0f / sqrtf(tot / (float)cols + 1e-6f);
  for (int c = threadIdx.x; c < cols; c += 256) {
    float v = row[c] * inv * w[c];
    if (outf) outf[(size_t)t * cols + c] = v;
    if (oh) {
      u16 hb = f2bf(v);
      oh[(size_t)t * cols + c] = hb;
      if (ol) ol[(size_t)t * cols + c] = f2bf(v - bf2f(hb));
    }
  }
}

// fused iw = (hs @ w_idx_w) * iqsc * ID^-0.5 * IH^-0.5
// one block per token; thread owns column h = tid&31, K-slice g = tid>>5 (8 groups).
// lanes 0..31 read contiguous 128B of w per step (coalesced); hs[d] is a per-group broadcast.
// w (256 KB) stays L2-resident across the 1024 blocks.
__global__ __launch_bounds__(256) void k_iw_fused(const float* __restrict__ hs, const float* __restrict__ w,
                                                  const float* __restrict__ iqsc, float* __restrict__ out) {
  __shared__ float red[4][32];
  int t = blockIdx.x;
  int tid = threadIdx.x;
  int h = tid & 31, g = tid >> 5;
  const float* hrow = hs + (size_t)t * kD;
  float acc = 0.f;
#pragma unroll 4
  for (int d = g; d < kD; d += 8) acc += hrow[d] * w[(size_t)d * kIH + h];
  // pair-reduce g and g^1 within the wave (lane l <-> l^32)
  acc += __shfl_xor(acc, 32, 64);
  int wave = tid >> 6, lane = tid & 63;
  if (lane < 32) red[wave][lane] = acc;
  __syncthreads();
  if (tid < 32) {
    float v = red[0][tid] + red[1][tid] + red[2][tid] + red[3][tid];
    out[t * kIH + tid] = v * iqsc[t * kIH + tid] * 0.08838834764831845f * 0.17677669529663687f;
  }
}

__global__ __launch_bounds__(256) void k_rope_q(float* __restrict__ q, const int* __restrict__ pos) {
  int t = blockIdx.x;
  float p = (float)pos[t];
  for (int idx = threadIdx.x; idx < kH * 32; idx += 256) {
    int h = idx >> 5, j = idx & 31;
    float invf = 1.0f / powf(10000.0f, (float)j * 0.03125f);
    float ang = p * invf; float s, c; sincosf(ang, &s, &c);
    size_t base = ((size_t)t * kH + h) * kQKD + kNOPE + 2 * j;
    float x1 = q[base], x2 = q[base + 1];
    q[base] = x1 * c - x2 * s;
    q[base + 1] = x2 * c + x1 * s;
  }
}

__global__ __launch_bounds__(256) void k_rope_iq(float* __restrict__ iq, const int* __restrict__ pos) {
  int t = blockIdx.x;
  float p = (float)pos[t];
  for (int idx = threadIdx.x; idx < kIH * 32; idx += 256) {
    int h = idx >> 5, j = idx & 31;
    float invf = 1.0f / powf(10000.0f, (float)j * 0.03125f);
    float ang = p * invf; float s, c; sincosf(ang, &s, &c);
    size_t base = ((size_t)t * kIH + h) * kID + 2 * j;
    float x1 = iq[base], x2 = iq[base + 1];
    iq[base] = x1 * c - x2 * s;
    iq[base + 1] = x2 * c + x1 * s;
  }
}

__global__ __launch_bounds__(64) void k_rope_kpe(const float* __restrict__ qkv, const int* __restrict__ pos,
                                                 float* __restrict__ kpe) {
  int t = blockIdx.x; int j = threadIdx.x;
  if (j >= 32) return;
  float p = (float)pos[t];
  float invf = 1.0f / powf(10000.0f, (float)j * 0.03125f);
  float ang = p * invf; float s, c; sincosf(ang, &s, &c);
  const float* src = qkv + (size_t)t * kQKV_N + kQL + kKVL;
  float x1 = src[2 * j], x2 = src[2 * j + 1];
  kpe[(size_t)t * 64 + 2 * j] = x1 * c - x2 * s;
  kpe[(size_t)t * 64 + 2 * j + 1] = x2 * c + x1 * s;
}

__global__ __launch_bounds__(64) void k_quant_rows(float* __restrict__ x, float* __restrict__ scales) {
  int row = blockIdx.x;
  float* p = x + (size_t)row * kID;
  int l = threadIdx.x;
  float v0 = p[2 * l], v1 = p[2 * l + 1];
  float am = wmax64(fmaxf(fabsf(v0), fabsf(v1)));
  float scale = pow2ceil(fmaxf(am / 448.0f, 1e-10f));
  float inv = 1.0f / scale;
  p[2 * l]     = fp8q(fminf(fmaxf(v0 * inv, -448.f), 448.f));
  p[2 * l + 1] = fp8q(fminf(fmaxf(v1 * inv, -448.f), 448.f));
  if (l == 0) scales[row] = scale;
}

__global__ __launch_bounds__(64) void k_ik_process(const float* __restrict__ raw, const float* __restrict__ w,
                                                   const float* __restrict__ b, const int* __restrict__ pos,
                                                   float* __restrict__ outq, float* __restrict__ scales) {
  int t = blockIdx.x; int l = threadIdx.x;
  const float* x = raw + (size_t)t * kID;
  float x0 = x[2 * l], x1 = x[2 * l + 1];
  float mean = wsum(x0 + x1) * (1.0f / 128.0f);
  float d0 = x0 - mean, d1 = x1 - mean;
  float var = wsum(d0 * d0 + d1 * d1) * (1.0f / 128.0f);
  float inv = 1.0f / sqrtf(var + 1e-6f);
  float y0 = d0 * inv * w[2 * l] + b[2 * l];
  float y1 = d1 * inv * w[2 * l + 1] + b[2 * l + 1];
  if (l < 32) {
    float p = (float)pos[t];
    float invf = 1.0f / powf(10000.0f, (float)l * 0.03125f);
    float ang = p * invf; float sn, cs; sincosf(ang, &sn, &cs);
    float r0 = y0 * cs - y1 * sn, r1 = y1 * cs + y0 * sn;
    y0 = r0; y1 = r1;
  }
  float am = wmax64(fmaxf(fabsf(y0), fabsf(y1)));
  float scale = pow2ceil(fmaxf(am / 448.0f, 1e-10f));
  float is = 1.0f / scale;
  outq[(size_t)t * kID + 2 * l]     = fp8q(fminf(fmaxf(y0 * is, -448.f), 448.f));
  outq[(size_t)t * kID + 2 * l + 1] = fp8q(fminf(fmaxf(y1 * is, -448.f), 448.f));
  if (l == 0) scales[t] = scale;
}

__global__ __launch_bounds__(256) void k_scores(const float* __restrict__ iq, const float* __restrict__ ik,
                                                const float* __restrict__ iksc, const float* __restrict__ iw,
                                                float* __restrict__ scores) {
  __shared__ __align__(16) float iqs[kIH * kID];
  __shared__ float iws[kIH];
  int t = blockIdx.x;
  for (int i = threadIdx.x; i < kIH * kID; i += 256) iqs[i] = iq[(size_t)t * kIH * kID + i];
  if (threadIdx.x < kIH) iws[threadIdx.x] = iw[t * kIH + threadIdx.x];
  __syncthreads();
  for (int s = threadIdx.x; s <= t; s += 256) {
    float acc[kIH];
#pragma unroll
    for (int h = 0; h < kIH; h++) acc[h] = 0.f;
    const float4* kr = (const float4*)(ik + (size_t)s * kID);
    for (int d4 = 0; d4 < kID / 4; d4++) {
      float4 kv4 = kr[d4];
#pragma unroll
      for (int h = 0; h < kIH; h++) {
        const float4 q4 = *(const float4*)&iqs[h * kID + d4 * 4];
        acc[h] += q4.x * kv4.x + q4.y * kv4.y + q4.z * kv4.z + q4.w * kv4.w;
      }
    }
    float scv = iksc[s];
    float tot = 0.f;
#pragma unroll
    for (int h = 0; h < kIH; h++) tot += iws[h] * fmaxf(acc[h] * scv, 0.f);
    scores[(size_t)t * kT + s] = tot;
  }
}

__global__ __launch_bounds__(64) void k_topk(const float* __restrict__ scores, unsigned long long* __restrict__ mbits) {
  int t = blockIdx.x; int l = threadIdx.x;
  __shared__ unsigned short tmp[64];
  unsigned long long* mrow = mbits + (size_t)t * 16;
  if (t < kTOPK) {
    if (l < 16) {
      int lo = l * 64, hi = lo + 63;
      unsigned long long bits;
      if (hi <= t) bits = ~0ull;
      else if (lo > t) bits = 0ull;
      else bits = (1ull << (t - lo + 1)) - 1ull;
      mrow[l] = bits;
    }
    return;
  }
  unsigned key[16];
  const float* srow = scores + (size_t)t * kT;
#pragma unroll
  for (int i = 0; i < 16; i++) {
    int s = l * 16 + i;
    key[i] = (s <= t) ? sortkey(srow[s]) : 0u;
  }
  unsigned prefix = 0; int remaining = kTOPK;
  for (int bit = 31; bit >= 0; bit--) {
    unsigned himask = 0xFFFFFFFFu << bit;
    unsigned cmp = prefix | (1u << bit);
    int c = 0;
#pragma unroll
    for (int i = 0; i < 16; i++) c += ((key[i] & himask) == cmp) ? 1 : 0;
    c = wsum_i(c);
    if (c >= remaining) prefix = cmp; else remaining -= c;
  }
  int ceq = 0, cgt = 0;
#pragma unroll
  for (int i = 0; i < 16; i++) { ceq += (key[i] == prefix) ? 1 : 0; cgt += (key[i] > prefix) ? 1 : 0; }
  int v = ceq;
#pragma unroll
  for (int o = 1; o < 64; o <<= 1) { int u = __shfl_up(v, o, 64); if (l >= o) v += u; }
  int rank = v - ceq;
  int need = kTOPK - wsum_i(cgt);
  unsigned short mybits = 0;
#pragma unroll
  for (int i = 0; i < 16; i++) {
    int sel;
    if (key[i] > prefix) sel = 1;
    else if (key[i] == prefix) { sel = (rank < need) ? 1 : 0; rank++; }
    else sel = 0;
    mybits |= (unsigned short)(sel << i);
  }
  tmp[l] = mybits;
  __syncthreads();
  if (l < 16) {
    mrow[l] = (unsigned long long)tmp[4 * l] | ((unsigned long long)tmp[4 * l + 1] << 16) |
              ((unsigned long long)tmp[4 * l + 2] << 32) | ((unsigned long long)tmp[4 * l + 3] << 48);
  }
}

__global__ __launch_bounds__(64) void k_route(const float* __restrict__ hs2, const float* __restrict__ wg,
                                              int* __restrict__ cnt, int* __restrict__ toki,
                                              float* __restrict__ tokw) {
  int t = blockIdx.x; int l = threadIdx.x;
  float acc[8] = {};
  for (int d = l; d < kD; d += 64) {
    float hv = hs2[(size_t)t * kD + d];
    const float* wr = wg + (size_t)d * 8;
#pragma unroll
    for (int e = 0; e < 8; e++) acc[e] += hv * wr[e];
  }
#pragma unroll
  for (int e = 0; e < 8; e++) acc[e] = wsum(acc[e]);
  if (l == 0) {
    float g[8];
#pragma unroll
    for (int e = 0; e < 8; e++) g[e] = 1.0f / (1.0f + expf(-acc[e]));
    int i0 = 0;
    for (int e = 1; e < 8; e++) if (g[e] > g[i0]) i0 = e;
    int i1 = (i0 == 0) ? 1 : 0;
    for (int e = 0; e < 8; e++) if (e != i0 && g[e] > g[i1]) i1 = e;
    float ssum = g[i0] + g[i1];
    float w0 = g[i0] / ssum * 2.5f, w1 = g[i1] / ssum * 2.5f;
    int s0 = atomicAdd(&cnt[i0], 1); toki[i0 * kT + s0] = t; tokw[i0 * kT + s0] = w0;
    int s1 = atomicAdd(&cnt[i1], 1); toki[i1 * kT + s1] = t; tokw[i1 * kT + s1] = w1;
  }
}

// ---------------- launch ----------------
extern "C" void kernel_launch(void* const* d_in, const int* in_sizes, int n_in,
                              void* d_out, int out_size, void* d_ws, size_t ws_size,
                              hipStream_t stream) {
  (void)in_sizes; (void)n_in; (void)out_size; (void)ws_size;
  const int*   positions  = (const int*)d_in[0];
  const float* hidden     = (const float*)d_in[1];
  const float* residual   = (const float*)d_in[2];
  const float* input_ln_w = (const float*)d_in[3];
  const float* post_ln_w  = (const float*)d_in[4];
  const float* w_qkv_a    = (const float*)d_in[5];
  const float* q_a_ln_w   = (const float*)d_in[6];
  const float* w_q_b      = (const float*)d_in[7];
  const float* kv_a_ln_w  = (const float*)d_in[8];
  const float* w_kv_b     = (const float*)d_in[9];
  const float* w_o        = (const float*)d_in[10];
  const float* w_idx_q_b  = (const float*)d_in[11];
  const float* w_idx_k    = (const float*)d_in[12];
  const float* idx_k_ln_w = (const float*)d_in[13];
  const float* idx_k_ln_b = (const float*)d_in[14];
  const float* w_idx_w    = (const float*)d_in[15];
  const float* w_gate     = (const float*)d_in[16];
  const float* w_moe_gate = (const float*)d_in[17];
  const float* w_moe_up   = (const float*)d_in[18];
  const float* w_moe_down = (const float*)d_in[19];
  const float* w_sh_gate  = (const float*)d_in[20];
  const float* w_sh_up    = (const float*)d_in[21];
  const float* w_sh_down  = (const float*)d_in[22];

  float* out0 = (float*)d_out;
  float* out1 = out0 + (size_t)kT * kD;

  char* W = (char*)d_ws;
  size_t off = 0;
  auto alloc = [&](size_t bytes) { char* p = W + off; off += (bytes + 255) & ~(size_t)255; return p; };
  // f32 buffers
  float* resid   = (float*)alloc((size_t)kT * kD * 4);
  float* hs      = (float*)alloc((size_t)kT * kD * 4);
  float* qkv     = (float*)alloc((size_t)kT * kQKV_N * 4);
  float* qb      = (float*)alloc((size_t)kT * kH * kQKD * 4);
  float* kvb     = (float*)alloc((size_t)kT * kH * 256 * 4);
  float* iqb     = (float*)alloc((size_t)kT * kIH * kID * 4);
  float* ikraw   = (float*)alloc((size_t)kT * kID * 4);
  float* ikb     = (float*)alloc((size_t)kT * kID * 4);
  float* iksc    = (float*)alloc(kT * 4);
  float* iqsc    = (float*)alloc((size_t)kT * kIH * 4);
  float* iwb     = (float*)alloc((size_t)kT * kIH * 4);
  float* kpe     = (float*)alloc((size_t)kT * kROPE * 4);
  float* scoresb = (float*)alloc((size_t)kT * kT * 4);
  float* hs2     = (float*)alloc((size_t)kT * kD * 4);
  unsigned long long* mbits = (unsigned long long*)alloc((size_t)kT * 16 * 8);
  float* tokw    = (float*)alloc((size_t)kE * kT * 4);
  int*   toki    = (int*)alloc((size_t)kE * kT * 4);
  int*   cnt     = (int*)alloc(64);
  // bf16 activations
  u16* hs_h   = (u16*)alloc((size_t)kT * kD * 2);
  u16* hs_l   = (u16*)alloc((size_t)kT * kD * 2);
  u16* qc_h   = (u16*)alloc((size_t)kT * kQL * 2);
  u16* qc_l   = (u16*)alloc((size_t)kT * kQL * 2);
  u16* kvc_h  = (u16*)alloc((size_t)kT * kKVL * 2);
  u16* o_bf   = (u16*)alloc((size_t)kT * kH * kVD * 2);
  u16* hs2_h  = (u16*)alloc((size_t)kT * kD * 2);
  u16* sg_bf  = (u16*)alloc((size_t)kT * kF * 2);
  u16* hmid_bf= (u16*)alloc((size_t)kE * kT * kF * 2);
  // bf16 transposed weights
  u16* qkvBT_h = (u16*)alloc((size_t)kQKV_NP * kD * 2);
  u16* qkvBT_l = (u16*)alloc((size_t)kQKV_NP * kD * 2);
  u16* qbBT    = (u16*)alloc((size_t)kH * kQKD * kQL * 2);
  u16* kvbBT   = (u16*)alloc((size_t)kH * 256 * kKVL * 2);
  u16* woBT    = (u16*)alloc((size_t)kD * kH * kVD * 2);
  u16* iqBT_h  = (u16*)alloc((size_t)kIH * kID * kQL * 2);
  u16* iqBT_l  = (u16*)alloc((size_t)kIH * kID * kQL * 2);
  u16* ikBT_h  = (u16*)alloc((size_t)kID * kD * 2);
  u16* ikBT_l  = (u16*)alloc((size_t)kID * kD * 2);
  u16* shgBT   = (u16*)alloc((size_t)kF * kD * 2);
  u16* shuBT   = (u16*)alloc((size_t)kF * kD * 2);
  u16* shdBT   = (u16*)alloc((size_t)kD * kF * 2);
  u16* moegBT  = (u16*)alloc((size_t)kE * kF * kD * 2);
  u16* moeuBT  = (u16*)alloc((size_t)kE * kF * kD * 2);
  u16* moedBT  = (u16*)alloc((size_t)kE * kD * kF * 2);

  // ---- weight prep (runs every launch; inputs are constant) ----
  { dim3 g(kQKV_NP / 32, kD / 32); k_transpose_w<<<g, 256, 0, stream>>>(w_qkv_a, qkvBT_h, qkvBT_l, kD, kQKV_N, kQKV_NP); }
  { dim3 g(kH * kQKD / 32, kQL / 32); k_transpose_w<<<g, 256, 0, stream>>>(w_q_b, qbBT, nullptr, kQL, kH * kQKD, kH * kQKD); }
  { dim3 g(kH * 256 / 32, kKVL / 32); k_transpose_w<<<g, 256, 0, stream>>>(w_kv_b, kvbBT, nullptr, kKVL, kH * 256, kH * 256); }
  { dim3 g(kD / 32, kH * kVD / 32); k_transpose_w<<<g, 256, 0, stream>>>(w_o, woBT, nullptr, kH * kVD, kD, kD); }
  { dim3 g(kIH * kID / 32, kQL / 32); k_transpose_w<<<g, 256, 0, stream>>>(w_idx_q_b, iqBT_h, iqBT_l, kQL, kIH * kID, kIH * kID); }
  { dim3 g(kID / 32, kD / 32); k_transpose_w<<<g, 256, 0, stream>>>(w_idx_k, ikBT_h, ikBT_l, kD, kID, kID); }
  { dim3 g(kF / 32, kD / 32); k_transpose_w<<<g, 256, 0, stream>>>(w_sh_gate, shgBT, nullptr, kD, kF, kF); }
  { dim3 g(kF / 32, kD / 32); k_transpose_w<<<g, 256, 0, stream>>>(w_sh_up, shuBT, nullptr, kD, kF, kF); }
  { dim3 g(kD / 32, kF / 32); k_transpose_w<<<g, 256, 0, stream>>>(w_sh_down, shdBT, nullptr, kF, kD, kD); }
  { dim3 g(kF / 32, kD / 32, kE); k_transpose_w<<<g, 256, 0, stream>>>(w_moe_gate, moegBT, nullptr, kD, kF, kF); }
  { dim3 g(kF / 32, kD / 32, kE); k_transpose_w<<<g, 256, 0, stream>>>(w_moe_up, moeuBT, nullptr, kD, kF, kF); }
  { dim3 g(kD / 32, kF / 32, kE); k_transpose_w<<<g, 256, 0, stream>>>(w_moe_down, moedBT, nullptr, kF, kD, kD); }

  // ---- forward ----
  k_add_rms<<<kT, 256, 0, stream>>>(hidden, residual, input_ln_w, resid, hs, hs_h, hs_l);
  { dim3 g(kQKV_NP / 128, kT / 128); k_gemm_split<<<g, 256, 0, stream>>>(hs_h, hs_l, qkvBT_h, qkvBT_l, qkv, kT, kQKV_N, kD); }
  k_rms_rows<<<kT, 256, 0, stream>>>(qkv, kQKV_N, 0, q_a_ln_w, nullptr, qc_h, qc_l, kQL);
  k_rms_rows<<<kT, 256, 0, stream>>>(qkv, kQKV_N, kQL, kv_a_ln_w, nullptr, kvc_h, nullptr, kKVL);
  { dim3 g(kH * kQKD / 128, kT / 128); k_gemm_bt<<<g, 256, 0, stream>>>(qc_h, qbBT, qb, nullptr, kT, kH * kQKD, kQL); }
  { dim3 g(kIH * kID / 128, kT / 128); k_gemm_split<<<g, 256, 0, stream>>>(qc_h, qc_l, iqBT_h, iqBT_l, iqb, kT, kIH * kID, kQL); }
  { dim3 g(kH * 256 / 128, kT / 128); k_gemm_bt<<<g, 256, 0, stream>>>(kvc_h, kvbBT, kvb, nullptr, kT, kH * 256, kKVL); }
  { dim3 g(kID / 128, kT / 128); k_gemm_split<<<g, 256, 0, stream>>>(hs_h, hs_l, ikBT_h, ikBT_l, ikraw, kT, kID, kD); }
  k_rope_q<<<kT, 256, 0, stream>>>(qb, positions);
  k_rope_iq<<<kT, 256, 0, stream>>>(iqb, positions);
  k_rope_kpe<<<kT, 64, 0, stream>>>(qkv, positions, kpe);
  k_quant_rows<<<kT * kIH, 64, 0, stream>>>(iqb, iqsc);
  k_ik_process<<<kT, 64, 0, stream>>>(ikraw, idx_k_ln_w, idx_k_ln_b, positions, ikb, iksc);
  k_iw_fused<<<kT, 256, 0, stream>>>(hs, w_idx_w, iqsc, iwb);
  k_scores<<<kT, 256, 0, stream>>>(iqb, ikb, iksc, iwb, scoresb);
  k_topk<<<kT, 64, 0, stream>>>(scoresb, mbits);
  { dim3 g(kT / 64, kH); k_attn_mfma<<<g, 256, 0, stream>>>(qb, kvb, kpe, mbits, o_bf); }
  { dim3 g(kD / 128, kT / 128); k_gemm_bt<<<g, 256, 0, stream>>>(o_bf, woBT, out1, resid, kT, kD, kH * kVD); }
  k_rms_rows<<<kT, 256, 0, stream>>>(out1, kD, 0, post_ln_w, hs2, hs2_h, nullptr, kD);
  hipMemsetAsync(cnt, 0, 8 * sizeof(int), stream);
  k_route<<<kT, 64, 0, stream>>>(hs2, w_gate, cnt, toki, tokw);
  { dim3 g(kF / 128, kT / 128, 1); k_dual_bt<<<g, 256, 0, stream>>>(hs2_h, shgBT, shuBT, sg_bf, nullptr, nullptr, kT, kF, kD); }
  { dim3 g(kD / 128, kT / 128); k_gemm_bt<<<g, 256, 0, stream>>>(sg_bf, shdBT, out0, nullptr, kT, kD, kF); }
  { dim3 g(kF / 128, kT / 128, kE); k_dual_bt<<<g, 256, 0, stream>>>(hs2_h, moegBT, moeuBT, hmid_bf, toki, cnt, kT, kF, kD); }
  { dim3 g(kD / 128, kT / 128, kE); k_down_bt<<<g, 256, 0, stream>>>(hmid_bf, moedBT, toki, tokw, cnt, out0); }
}

// Round 2
// 1148.176 us; speedup vs baseline: 1.2732x; 1.1188x over previous
//
#include <hip/hip_runtime.h>

namespace {
constexpr int kT = 1024, kD = 2048, kH = 16, kNOPE = 128, kROPE = 64, kVD = 128, kQKD = 192;
constexpr int kQL = 768, kKVL = 512, kIH = 32, kID = 128, kTOPK = 256, kE = 8, kF = 1024;
constexpr int kQKV_N = kQL + kKVL + kROPE; // 1344
constexpr int kQKV_NP = 1408;              // padded to 128
}

typedef __attribute__((ext_vector_type(4))) float floatx4;
typedef __attribute__((ext_vector_type(8))) short short8;
typedef unsigned short u16;

// ---------------- device helpers ----------------
__device__ __forceinline__ float wsum(float v) {
#pragma unroll
  for (int o = 32; o; o >>= 1) v += __shfl_xor(v, o, 64);
  return v;
}
__device__ __forceinline__ float wmax64(float v) {
#pragma unroll
  for (int o = 32; o; o >>= 1) v = fmaxf(v, __shfl_xor(v, o, 64));
  return v;
}
__device__ __forceinline__ int wsum_i(int v) {
#pragma unroll
  for (int o = 32; o; o >>= 1) v += __shfl_xor(v, o, 64);
  return v;
}
__device__ __forceinline__ float bsum256(float v, float* red) {
  v = wsum(v);
  if ((threadIdx.x & 63) == 0) red[threadIdx.x >> 6] = v;
  __syncthreads();
  float t = red[0] + red[1] + red[2] + red[3];
  __syncthreads();
  return t;
}
__device__ __forceinline__ unsigned sortkey(float f) {
  unsigned b = __float_as_uint(f);
  return (b & 0x80000000u) ? ~b : (b | 0x80000000u);
}
__device__ __forceinline__ float pow2ceil(float z) {
  unsigned b = __float_as_uint(z);
  if ((b & 0x7FFFFFu) == 0) return z;
  return __uint_as_float((((b >> 23) & 0xFFu) + 1u) << 23);
}
__device__ __forceinline__ float fp8q(float x) {
  float ax = fabsf(x);
  float q;
  if (ax < 0.015625f) {
    q = rintf(ax * 512.0f) * 0.001953125f;
  } else {
    unsigned b = __float_as_uint(ax);
    int e = (int)((b >> 23) & 0xFF) - 127;
    float quant = __uint_as_float((unsigned)(e - 3 + 127) << 23);
    float rq    = __uint_as_float((unsigned)(127 - (e - 3)) << 23);
    q = rintf(ax * rq) * quant;
  }
  return copysignf(q, x);
}
__device__ __forceinline__ u16 f2bf(float x) {
  unsigned u = __float_as_uint(x);
  u += 0x7FFFu + ((u >> 16) & 1u);
  return (u16)(u >> 16);
}
__device__ __forceinline__ float bf2f(u16 h) { return __uint_as_float((unsigned)h << 16); }

// async global->LDS, 16B per lane; lds ptr must be wave-uniform (HW adds lane*16)
__device__ __forceinline__ void gld_lds16(const void* g, void* l) {
  __builtin_amdgcn_global_load_lds(
      (const __attribute__((address_space(1))) unsigned int*)(unsigned long long)g,
      (__attribute__((address_space(3))) unsigned int*)(unsigned int)(unsigned long long)l,
      16, 0, 0);
}
// stage 128 rows x 32 bf16 cols; wave stages rows [wave*32, wave*32+32)
__device__ __forceinline__ void stage_tile(const u16* g, size_t strideUs, u16* tile, int wave, int lane) {
  int r = lane >> 2, c = lane & 3;
  const u16* gp = g + (size_t)(wave * 32 + r) * strideUs + c * 8;
  gld_lds16(gp, tile + (wave * 32) * 32);
  gld_lds16(gp + (size_t)16 * strideUs, tile + (wave * 32 + 16) * 32);
}

// ---------------- weight prep: f32 [K][N] -> bf16 BT [Npad][K] (+optional lo) ----------------
__global__ __launch_bounds__(256) void k_transpose_w(const float* __restrict__ in, u16* __restrict__ hi,
                                                     u16* __restrict__ lo, int K, int N, int Npad) {
  __shared__ float tile[32][33];
  int n0 = blockIdx.x * 32, k0 = blockIdx.y * 32;
  const float* ip = in + (size_t)blockIdx.z * K * N;
  u16* hp = hi + (size_t)blockIdx.z * Npad * K;
  u16* lp = lo ? lo + (size_t)blockIdx.z * Npad * K : nullptr;
  int t = threadIdx.x;
  int r = t >> 3, c4 = (t & 7) << 2;
  if (n0 < N) {
    float4 v = *(const float4*)&ip[(size_t)(k0 + r) * N + n0 + c4];
    tile[r][c4] = v.x; tile[r][c4 + 1] = v.y; tile[r][c4 + 2] = v.z; tile[r][c4 + 3] = v.w;
  } else {
    tile[r][c4] = 0.f; tile[r][c4 + 1] = 0.f; tile[r][c4 + 2] = 0.f; tile[r][c4 + 3] = 0.f;
  }
  __syncthreads();
  int n = t >> 3, kq = (t & 7) << 2;
  ushort4 h4, l4;
#pragma unroll
  for (int j = 0; j < 4; j++) {
    float f = tile[kq + j][n];
    u16 h = f2bf(f);
    ((u16*)&h4)[j] = h;
    ((u16*)&l4)[j] = f2bf(f - bf2f(h));
  }
  *(ushort4*)&hp[(size_t)(n0 + n) * K + k0 + kq] = h4;
  if (lp) *(ushort4*)&lp[(size_t)(n0 + n) * K + k0 + kq] = l4;
}

// ---------------- GEMM family: bf16 A [M][K], bf16 BT [N][K], global_load_lds staging ----------
// 128x128 tile, BK=32, 4 waves in 2x2 quadrants.

__global__ __launch_bounds__(256) void k_gemm_bt(const u16* __restrict__ A, const u16* __restrict__ BT,
                                                 float* __restrict__ C, const float* __restrict__ addend,
                                                 int M, int N, int K) {
  __shared__ __align__(16) u16 As[128 * 32];
  __shared__ __align__(16) u16 Bs[128 * 32];
  int tid = threadIdx.x, wave = tid >> 6, lane = tid & 63;
  int bm = blockIdx.y * 128, bn = blockIdx.x * 128;
  int wy = (wave >> 1) * 64, wx = (wave & 1) * 64;
  int lm = lane & 15, lk = lane >> 4;
  const u16* Ab = A + (size_t)bm * K;
  const u16* Bb = BT + (size_t)bn * K;
  floatx4 acc[4][4] = {};
  for (int k0 = 0; k0 < K; k0 += 32) {
    stage_tile(Ab + k0, K, As, wave, lane);
    stage_tile(Bb + k0, K, Bs, wave, lane);
    __syncthreads();
    short8 af[4], bfr[4];
#pragma unroll
    for (int mt = 0; mt < 4; mt++) af[mt] = *(short8*)&As[(wy + mt * 16 + lm) * 32 + lk * 8];
#pragma unroll
    for (int nt = 0; nt < 4; nt++) bfr[nt] = *(short8*)&Bs[(wx + nt * 16 + lm) * 32 + lk * 8];
#pragma unroll
    for (int mt = 0; mt < 4; mt++)
#pragma unroll
      for (int nt = 0; nt < 4; nt++)
        acc[mt][nt] = __builtin_amdgcn_mfma_f32_16x16x32_bf16(af[mt], bfr[nt], acc[mt][nt], 0, 0, 0);
    __syncthreads();
  }
#pragma unroll
  for (int mt = 0; mt < 4; mt++)
#pragma unroll
    for (int nt = 0; nt < 4; nt++)
#pragma unroll
      for (int r = 0; r < 4; r++) {
        int m = bm + wy + mt * 16 + lk * 4 + r;
        int n = bn + wx + nt * 16 + lm;
        float v = acc[mt][nt][r];
        if (addend) v += addend[(size_t)m * N + n];
        C[(size_t)m * N + n] = v;
      }
}

// 3-term split-precision GEMM: C = Ahi*Bhi + Ahi*Blo + Alo*Bhi (f32-class accuracy).
// N may be < padded BT rows; C guarded & strided by N.
__global__ __launch_bounds__(256) void k_gemm_split(const u16* __restrict__ Ah, const u16* __restrict__ Al,
                                                    const u16* __restrict__ Bh, const u16* __restrict__ Bl,
                                                    float* __restrict__ C, int M, int N, int K) {
  __shared__ __align__(16) u16 Ahs[128 * 32];
  __shared__ __align__(16) u16 Als[128 * 32];
  __shared__ __align__(16) u16 Bhs[128 * 32];
  __shared__ __align__(16) u16 Bls[128 * 32];
  int tid = threadIdx.x, wave = tid >> 6, lane = tid & 63;
  int bm = blockIdx.y * 128, bn = blockIdx.x * 128;
  int wy = (wave >> 1) * 64, wx = (wave & 1) * 64;
  int lm = lane & 15, lk = lane >> 4;
  floatx4 acc[4][4] = {};
  for (int k0 = 0; k0 < K; k0 += 32) {
    stage_tile(Ah + (size_t)bm * K + k0, K, Ahs, wave, lane);
    stage_tile(Al + (size_t)bm * K + k0, K, Als, wave, lane);
    stage_tile(Bh + (size_t)bn * K + k0, K, Bhs, wave, lane);
    stage_tile(Bl + (size_t)bn * K + k0, K, Bls, wave, lane);
    __syncthreads();
    short8 ah[4], al[4], bh[4], bl[4];
#pragma unroll
    for (int mt = 0; mt < 4; mt++) { ah[mt] = *(short8*)&Ahs[(wy + mt * 16 + lm) * 32 + lk * 8];
                                     al[mt] = *(short8*)&Als[(wy + mt * 16 + lm) * 32 + lk * 8]; }
#pragma unroll
    for (int nt = 0; nt < 4; nt++) { bh[nt] = *(short8*)&Bhs[(wx + nt * 16 + lm) * 32 + lk * 8];
                                     bl[nt] = *(short8*)&Bls[(wx + nt * 16 + lm) * 32 + lk * 8]; }
#pragma unroll
    for (int mt = 0; mt < 4; mt++)
#pragma unroll
      for (int nt = 0; nt < 4; nt++) {
        floatx4 a = acc[mt][nt];
        a = __builtin_amdgcn_mfma_f32_16x16x32_bf16(al[mt], bh[nt], a, 0, 0, 0);
        a = __builtin_amdgcn_mfma_f32_16x16x32_bf16(ah[mt], bl[nt], a, 0, 0, 0);
        a = __builtin_amdgcn_mfma_f32_16x16x32_bf16(ah[mt], bh[nt], a, 0, 0, 0);
        acc[mt][nt] = a;
      }
    __syncthreads();
  }
#pragma unroll
  for (int mt = 0; mt < 4; mt++)
#pragma unroll
    for (int nt = 0; nt < 4; nt++)
#pragma unroll
      for (int r = 0; r < 4; r++) {
        int m = bm + wy + mt * 16 + lk * 4 + r;
        int n = bn + wx + nt * 16 + lm;
        if (n < N) C[(size_t)m * N + n] = acc[mt][nt][r];
      }
}

// dual-B gate+up with silu epilogue -> bf16 out; optional row gather (MoE), z = expert
__global__ __launch_bounds__(256) void k_dual_bt(const u16* __restrict__ A, const u16* __restrict__ GT,
                                                 const u16* __restrict__ UT, u16* __restrict__ out,
                                                 const int* __restrict__ toki, const int* __restrict__ cnt,
                                                 int M, int N, int K) {
  int e = blockIdx.z;
  int n_rows = toki ? cnt[e] : M;
  int bm = blockIdx.y * 128;
  if (bm >= n_rows) return;
  int bn = blockIdx.x * 128;
  const int* tk = toki ? (toki + e * kT) : nullptr;
  const u16* Gb = GT + (size_t)e * N * K + (size_t)bn * K;
  const u16* Ub = UT + (size_t)e * N * K + (size_t)bn * K;
  u16* oP = out + (size_t)e * kT * N;
  __shared__ __align__(16) u16 As[128 * 32];
  __shared__ __align__(16) u16 Gs[128 * 32];
  __shared__ __align__(16) u16 Us[128 * 32];
  int tid = threadIdx.x, wave = tid >> 6, lane = tid & 63;
  int wy = (wave >> 1) * 64, wx = (wave & 1) * 64;
  int lm = lane & 15, lk = lane >> 4;
  int r = lane >> 2, c = lane & 3;
  int r0 = bm + wave * 32 + r, r1 = r0 + 16;
  size_t arow0 = tk ? (size_t)((r0 < n_rows) ? tk[r0] : 0) : (size_t)r0;
  size_t arow1 = tk ? (size_t)((r1 < n_rows) ? tk[r1] : 0) : (size_t)r1;
  floatx4 ag[4][4] = {}, au[4][4] = {};
  for (int k0 = 0; k0 < K; k0 += 32) {
    gld_lds16(A + arow0 * K + k0 + c * 8, As + (wave * 32) * 32);
    gld_lds16(A + arow1 * K + k0 + c * 8, As + (wave * 32 + 16) * 32);
    stage_tile(Gb + k0, K, Gs, wave, lane);
    stage_tile(Ub + k0, K, Us, wave, lane);
    __syncthreads();
    short8 af[4], gf[4], uf[4];
#pragma unroll
    for (int mt = 0; mt < 4; mt++) af[mt] = *(short8*)&As[(wy + mt * 16 + lm) * 32 + lk * 8];
#pragma unroll
    for (int nt = 0; nt < 4; nt++) { gf[nt] = *(short8*)&Gs[(wx + nt * 16 + lm) * 32 + lk * 8];
                                     uf[nt] = *(short8*)&Us[(wx + nt * 16 + lm) * 32 + lk * 8]; }
#pragma unroll
    for (int mt = 0; mt < 4; mt++)
#pragma unroll
      for (int nt = 0; nt < 4; nt++) {
        ag[mt][nt] = __builtin_amdgcn_mfma_f32_16x16x32_bf16(af[mt], gf[nt], ag[mt][nt], 0, 0, 0);
        au[mt][nt] = __builtin_amdgcn_mfma_f32_16x16x32_bf16(af[mt], uf[nt], au[mt][nt], 0, 0, 0);
      }
    __syncthreads();
  }
#pragma unroll
  for (int mt = 0; mt < 4; mt++)
#pragma unroll
    for (int nt = 0; nt < 4; nt++)
#pragma unroll
      for (int r2 = 0; r2 < 4; r2++) {
        int gm = bm + wy + mt * 16 + lk * 4 + r2;
        if (gm >= n_rows) continue;
        int n = bn + wx + nt * 16 + lm;
        float gv = ag[mt][nt][r2], uv = au[mt][nt][r2];
        oP[(size_t)gm * N + n] = f2bf(gv * (1.0f / (1.0f + expf(-gv))) * uv);
      }
}

// down: out[tok] += w * (hmid[e] @ wd[e]); A compact bf16 per expert; atomic scatter f32
__global__ __launch_bounds__(256) void k_down_bt(const u16* __restrict__ hmid, const u16* __restrict__ DT,
                                                 const int* __restrict__ toki, const float* __restrict__ tokw,
                                                 const int* __restrict__ cnt, float* __restrict__ out) {
  int e = blockIdx.z;
  int n_rows = cnt[e];
  int bm = blockIdx.y * 128;
  if (bm >= n_rows) return;
  int bn = blockIdx.x * 128;
  const u16* Ab = hmid + (size_t)e * kT * kF + (size_t)bm * kF;
  const u16* Bb = DT + (size_t)e * kD * kF + (size_t)bn * kF;
  __shared__ __align__(16) u16 As[128 * 32];
  __shared__ __align__(16) u16 Bs[128 * 32];
  int tid = threadIdx.x, wave = tid >> 6, lane = tid & 63;
  int wy = (wave >> 1) * 64, wx = (wave & 1) * 64;
  int lm = lane & 15, lk = lane >> 4;
  floatx4 acc[4][4] = {};
  for (int k0 = 0; k0 < kF; k0 += 32) {
    stage_tile(Ab + k0, kF, As, wave, lane);
    stage_tile(Bb + k0, kF, Bs, wave, lane);
    __syncthreads();
    short8 af[4], bfr[4];
#pragma unroll
    for (int mt = 0; mt < 4; mt++) af[mt] = *(short8*)&As[(wy + mt * 16 + lm) * 32 + lk * 8];
#pragma unroll
    for (int nt = 0; nt < 4; nt++) bfr[nt] = *(short8*)&Bs[(wx + nt * 16 + lm) * 32 + lk * 8];
#pragma unroll
    for (int mt = 0; mt < 4; mt++)
#pragma unroll
      for (int nt = 0; nt < 4; nt++)
        acc[mt][nt] = __builtin_amdgcn_mfma_f32_16x16x32_bf16(af[mt], bfr[nt], acc[mt][nt], 0, 0, 0);
    __syncthreads();
  }
#pragma unroll
  for (int mt = 0; mt < 4; mt++)
#pragma unroll
    for (int r = 0; r < 4; r++) {
      int gm = bm + wy + mt * 16 + lk * 4 + r;
      if (gm >= n_rows) continue;
      int tt = toki[e * kT + gm];
      float w = tokw[e * kT + gm];
#pragma unroll
      for (int nt = 0; nt < 4; nt++) {
        int n = bn + wx + nt * 16 + lm;
        atomicAdd(&out[(size_t)tt * kD + n], w * acc[mt][nt][r]);
      }
    }
}

// ---------------- flash MFMA attention (bf16 out) ----------------
__global__ __launch_bounds__(256) void k_attn_mfma(const float* __restrict__ q, const float* __restrict__ kv,
                                                   const float* __restrict__ kpe,
                                                   const unsigned long long* __restrict__ mbits,
                                                   u16* __restrict__ o) {
  __shared__ __align__(16) u16 Ks[64 * 200];
  __shared__ __align__(16) u16 Vs[128 * 72];
  __shared__ __align__(16) u16 Ps[4 * 16 * 72];
  int h = blockIdx.y;
  int qb = gridDim.x - 1 - blockIdx.x;
  int qbase = qb * 64;
  int tid = threadIdx.x;
  int wave = tid >> 6, lane = tid & 63;
  int lm = lane & 15, lk = lane >> 4;
  short8 qf[6];
  {
    const float* qrow = q + ((size_t)(qbase + wave * 16 + lm) * kH + h) * kQKD;
#pragma unroll
    for (int ks = 0; ks < 6; ks++) {
      const float4 a0 = *(const float4*)&qrow[ks * 32 + lk * 8];
      const float4 a1 = *(const float4*)&qrow[ks * 32 + lk * 8 + 4];
      short8 f;
      f[0] = (short)f2bf(a0.x); f[1] = (short)f2bf(a0.y); f[2] = (short)f2bf(a0.z); f[3] = (short)f2bf(a0.w);
      f[4] = (short)f2bf(a1.x); f[5] = (short)f2bf(a1.y); f[6] = (short)f2bf(a1.z); f[7] = (short)f2bf(a1.w);
      qf[ks] = f;
    }
  }
  float m_r[4] = {-1e30f, -1e30f, -1e30f, -1e30f};
  float l_r[4] = {};
  floatx4 Oacc[8] = {};
  int sr = tid >> 2, sj = tid & 3;
  int nch = qb + 1;
  for (int ch = 0; ch < nch; ch++) {
    int s0 = ch << 6;
    __syncthreads();
    {
      const float* kvrow = kv + ((size_t)(s0 + sr) * kH + h) * 256;
      const float* kprow = kpe + (size_t)(s0 + sr) * 64;
#pragma unroll
      for (int i = 0; i < 12; i++) {
        int c4 = (i << 2) + sj;
        float4 v4 = (c4 < 32) ? *(const float4*)&kvrow[c4 * 4] : *(const float4*)&kprow[(c4 - 32) * 4];
        ushort4 p; p.x = f2bf(v4.x); p.y = f2bf(v4.y); p.z = f2bf(v4.z); p.w = f2bf(v4.w);
        *(ushort4*)&Ks[sr * 200 + c4 * 4] = p;
      }
      const float* vrow = kvrow + 128;
#pragma unroll
      for (int i = 0; i < 8; i++) {
        int c4 = (i << 2) + sj;
        float4 v4 = *(const float4*)&vrow[c4 * 4];
        Vs[(c4 * 4 + 0) * 72 + sr] = f2bf(v4.x);
        Vs[(c4 * 4 + 1) * 72 + sr] = f2bf(v4.y);
        Vs[(c4 * 4 + 2) * 72 + sr] = f2bf(v4.z);
        Vs[(c4 * 4 + 3) * 72 + sr] = f2bf(v4.w);
      }
    }
    __syncthreads();
    floatx4 sacc[4] = {};
#pragma unroll
    for (int ks = 0; ks < 6; ks++) {
      short8 kf[4];
#pragma unroll
      for (int nt = 0; nt < 4; nt++) kf[nt] = *(short8*)&Ks[(nt * 16 + lm) * 200 + ks * 32 + lk * 8];
#pragma unroll
      for (int nt = 0; nt < 4; nt++)
        sacc[nt] = __builtin_amdgcn_mfma_f32_16x16x32_bf16(qf[ks], kf[nt], sacc[nt], 0, 0, 0);
    }
    unsigned long long mw[4];
#pragma unroll
    for (int r = 0; r < 4; r++) mw[r] = mbits[(size_t)(qbase + wave * 16 + lk * 4 + r) * 16 + ch];
    float mx[4] = {-1e30f, -1e30f, -1e30f, -1e30f};
#pragma unroll
    for (int nt = 0; nt < 4; nt++)
#pragma unroll
      for (int r = 0; r < 4; r++) {
        int sel = (int)((mw[r] >> (nt * 16 + lm)) & 1ull);
        float sv = sel ? sacc[nt][r] * 0.07216878364870323f : -1e30f;
        sacc[nt][r] = sv;
        mx[r] = fmaxf(mx[r], sv);
      }
#pragma unroll
    for (int off = 1; off < 16; off <<= 1)
#pragma unroll
      for (int r = 0; r < 4; r++) mx[r] = fmaxf(mx[r], __shfl_xor(mx[r], off, 64));
    float al[4], psum[4] = {};
#pragma unroll
    for (int r = 0; r < 4; r++) {
      float mnew = fmaxf(m_r[r], mx[r]);
      al[r] = __expf(m_r[r] - mnew);
      m_r[r] = mnew;
    }
#pragma unroll
    for (int nt = 0; nt < 4; nt++)
#pragma unroll
      for (int r = 0; r < 4; r++) {
        float p = (sacc[nt][r] > -0.9e30f) ? __expf(sacc[nt][r] - m_r[r]) : 0.0f;
        psum[r] += p;
        Ps[wave * 1152 + (lk * 4 + r) * 72 + nt * 16 + lm] = f2bf(p);
      }
#pragma unroll
    for (int off = 1; off < 16; off <<= 1)
#pragma unroll
      for (int r = 0; r < 4; r++) psum[r] += __shfl_xor(psum[r], off, 64);
#pragma unroll
    for (int r = 0; r < 4; r++) l_r[r] = l_r[r] * al[r] + psum[r];
#pragma unroll
    for (int nv = 0; nv < 8; nv++)
#pragma unroll
      for (int r = 0; r < 4; r++) Oacc[nv][r] *= al[r];
    short8 pf[2];
#pragma unroll
    for (int k2 = 0; k2 < 2; k2++) pf[k2] = *(short8*)&Ps[wave * 1152 + lm * 72 + k2 * 32 + lk * 8];
#pragma unroll
    for (int k2 = 0; k2 < 2; k2++)
#pragma unroll
      for (int nv = 0; nv < 8; nv++) {
        short8 vf = *(short8*)&Vs[(nv * 16 + lm) * 72 + k2 * 32 + lk * 8];
        Oacc[nv] = __builtin_amdgcn_mfma_f32_16x16x32_bf16(pf[k2], vf, Oacc[nv], 0, 0, 0);
      }
  }
  float invl[4];
#pragma unroll
  for (int r = 0; r < 4; r++) invl[r] = 1.0f / l_r[r];
#pragma unroll
  for (int nv = 0; nv < 8; nv++)
#pragma unroll
    for (int r = 0; r < 4; r++) {
      int t_row = qbase + wave * 16 + lk * 4 + r;
      o[((size_t)t_row * kH + h) * kVD + nv * 16 + lm] = f2bf(Oacc[nv][r] * invl[r]);
    }
}

// ---------------- norm / small kernels ----------------
__global__ __launch_bounds__(256) void k_add_rms(const float* __restrict__ h, const float* __restrict__ r,
                                                 const float* __restrict__ w, float* __restrict__ resid,
                                                 float* __restrict__ out, u16* __restrict__ oh,
                                                 u16* __restrict__ ol) {
  __shared__ float row[kD];
  __shared__ float red[4];
  int t = blockIdx.x;
  size_t base = (size_t)t * kD;
  float ss = 0.f;
  for (int c = threadIdx.x; c < kD; c += 256) {
    float v = h[base + c] + r[base + c];
    row[c] = v; resid[base + c] = v; ss += v * v;
  }
  float tot = bsum256(ss, red);
  float inv = 1.0f / sqrtf(tot * (1.0f / kD) + 1e-6f);
  for (int c = threadIdx.x; c < kD; c += 256) {
    float v = row[c] * inv * w[c];
    out[base + c] = v;
    u16 hb = f2bf(v);
    oh[base + c] = hb;
    ol[base + c] = f2bf(v - bf2f(hb));
  }
}

// rmsnorm with optional f32 / bf16-hi / bf16-lo outputs
__global__ __launch_bounds__(256) void k_rms_rows(const float* __restrict__ in, int stride, int off,
                                                  const float* __restrict__ w, float* __restrict__ outf,
                                                  u16* __restrict__ oh, u16* __restrict__ ol, int cols) {
  __shared__ float row[kD];
  __shared__ float red[4];
  int t = blockIdx.x;
  const float* x = in + (size_t)t * stride + off;
  float ss = 0.f;
  for (int c = threadIdx.x; c < cols; c += 256) { float v = x[c]; row[c] = v; ss += v * v; }
  float tot = bsum256(ss, red);
  float inv = 1.0f / sqrtf(tot / (float)cols + 1e-6f);
  for (int c = threadIdx.x; c < cols; c += 256) {
    float v = row[c] * inv * w[c];
    if (outf) outf[(size_t)t * cols + c] = v;
    if (oh) {
      u16 hb = f2bf(v);
      oh[(size_t)t * cols + c] = hb;
      if (ol) ol[(size_t)t * cols + c] = f2bf(v - bf2f(hb));
    }
  }
}

// fused iw = (hs @ w_idx_w) * iqsc * ID^-0.5 * IH^-0.5
__global__ __launch_bounds__(256) void k_iw_fused(const float* __restrict__ hs, const float* __restrict__ w,
                                                  const float* __restrict__ iqsc, float* __restrict__ out) {
  __shared__ float red[4][32];
  int t = blockIdx.x;
  int tid = threadIdx.x;
  int h = tid & 31, g = tid >> 5;
  const float* hrow = hs + (size_t)t * kD;
  float acc = 0.f;
#pragma unroll 4
  for (int d = g; d < kD; d += 8) acc += hrow[d] * w[(size_t)d * kIH + h];
  acc += __shfl_xor(acc, 32, 64);
  int wave = tid >> 6, lane = tid & 63;
  if (lane < 32) red[wave][lane] = acc;
  __syncthreads();
  if (tid < 32) {
    float v = red[0][tid] + red[1][tid] + red[2][tid] + red[3][tid];
    out[t * kIH + tid] = v * iqsc[t * kIH + tid] * 0.08838834764831845f * 0.17677669529663687f;
  }
}

__global__ __launch_bounds__(256) void k_rope_q(float* __restrict__ q, const int* __restrict__ pos) {
  int t = blockIdx.x;
  float p = (float)pos[t];
  for (int idx = threadIdx.x; idx < kH * 32; idx += 256) {
    int h = idx >> 5, j = idx & 31;
    float invf = 1.0f / powf(10000.0f, (float)j * 0.03125f);
    float ang = p * invf; float s, c; sincosf(ang, &s, &c);
    size_t base = ((size_t)t * kH + h) * kQKD + kNOPE + 2 * j;
    float x1 = q[base], x2 = q[base + 1];
    q[base] = x1 * c - x2 * s;
    q[base + 1] = x2 * c + x1 * s;
  }
}

__global__ __launch_bounds__(256) void k_rope_iq(float* __restrict__ iq, const int* __restrict__ pos) {
  int t = blockIdx.x;
  float p = (float)pos[t];
  for (int idx = threadIdx.x; idx < kIH * 32; idx += 256) {
    int h = idx >> 5, j = idx & 31;
    float invf = 1.0f / powf(10000.0f, (float)j * 0.03125f);
    float ang = p * invf; float s, c; sincosf(ang, &s, &c);
    size_t base = ((size_t)t * kIH + h) * kID + 2 * j;
    float x1 = iq[base], x2 = iq[base + 1];
    iq[base] = x1 * c - x2 * s;
    iq[base + 1] = x2 * c + x1 * s;
  }
}

__global__ __launch_bounds__(64) void k_rope_kpe(const float* __restrict__ qkv, const int* __restrict__ pos,
                                                 float* __restrict__ kpe) {
  int t = blockIdx.x; int j = threadIdx.x;
  if (j >= 32) return;
  float p = (float)pos[t];
  float invf = 1.0f / powf(10000.0f, (float)j * 0.03125f);
  float ang = p * invf; float s, c; sincosf(ang, &s, &c);
  const float* src = qkv + (size_t)t * kQKV_N + kQL + kKVL;
  float x1 = src[2 * j], x2 = src[2 * j + 1];
  kpe[(size_t)t * 64 + 2 * j] = x1 * c - x2 * s;
  kpe[(size_t)t * 64 + 2 * j + 1] = x2 * c + x1 * s;
}

// quantize rows of f32 [rows][kID] -> fp8-grid values stored as bf16 (exact), + pow2 scale
__global__ __launch_bounds__(64) void k_quant_rows(const float* __restrict__ x, u16* __restrict__ outq,
                                                   float* __restrict__ scales) {
  int row = blockIdx.x;
  const float* p = x + (size_t)row * kID;
  int l = threadIdx.x;
  float v0 = p[2 * l], v1 = p[2 * l + 1];
  float am = wmax64(fmaxf(fabsf(v0), fabsf(v1)));
  float scale = pow2ceil(fmaxf(am / 448.0f, 1e-10f));
  float inv = 1.0f / scale;
  float q0 = fp8q(fminf(fmaxf(v0 * inv, -448.f), 448.f));
  float q1 = fp8q(fminf(fmaxf(v1 * inv, -448.f), 448.f));
  ushort2 pk; pk.x = f2bf(q0); pk.y = f2bf(q1);
  *(ushort2*)&outq[(size_t)row * kID + 2 * l] = pk;
  if (l == 0) scales[row] = scale;
}

__global__ __launch_bounds__(64) void k_ik_process(const float* __restrict__ raw, const float* __restrict__ w,
                                                   const float* __restrict__ b, const int* __restrict__ pos,
                                                   u16* __restrict__ outq, float* __restrict__ scales) {
  int t = blockIdx.x; int l = threadIdx.x;
  const float* x = raw + (size_t)t * kID;
  float x0 = x[2 * l], x1 = x[2 * l + 1];
  float mean = wsum(x0 + x1) * (1.0f / 128.0f);
  float d0 = x0 - mean, d1 = x1 - mean;
  float var = wsum(d0 * d0 + d1 * d1) * (1.0f / 128.0f);
  float inv = 1.0f / sqrtf(var + 1e-6f);
  float y0 = d0 * inv * w[2 * l] + b[2 * l];
  float y1 = d1 * inv * w[2 * l + 1] + b[2 * l + 1];
  if (l < 32) {
    float p = (float)pos[t];
    float invf = 1.0f / powf(10000.0f, (float)l * 0.03125f);
    float ang = p * invf; float sn, cs; sincosf(ang, &sn, &cs);
    float r0 = y0 * cs - y1 * sn, r1 = y1 * cs + y0 * sn;
    y0 = r0; y1 = r1;
  }
  float am = wmax64(fmaxf(fabsf(y0), fabsf(y1)));
  float scale = pow2ceil(fmaxf(am / 448.0f, 1e-10f));
  float is = 1.0f / scale;
  float q0 = fp8q(fminf(fmaxf(y0 * is, -448.f), 448.f));
  float q1 = fp8q(fminf(fmaxf(y1 * is, -448.f), 448.f));
  ushort2 pk; pk.x = f2bf(q0); pk.y = f2bf(q1);
  *(ushort2*)&outq[(size_t)t * kID + 2 * l] = pk;
  if (l == 0) scales[t] = scale;
}

// MFMA indexer scores: scores[t][s] = sum_h iw[t][h] * relu( (iq[t,h,:] . ik[s,:]) * iksc[s] )
// A = iq_bf [kT*kIH][kID], B = ik_bf [kT][kID]. Block = 128 M-rows (4 tokens x 32 heads) x 128 sources.
// Blocks fully above the causal diagonal are skipped; s>t entries within diagonal blocks write
// garbage that k_topk never reads.
__global__ __launch_bounds__(256) void k_scores_mfma(const u16* __restrict__ iq, const u16* __restrict__ ik,
                                                     const float* __restrict__ iksc, const float* __restrict__ iw,
                                                     float* __restrict__ scores) {
  int tb = blockIdx.y * 4;   // 4 tokens per block
  int bn = blockIdx.x * 128; // source base
  if (bn > tb + 3) return;   // entirely s > t
  __shared__ __align__(16) u16 As[128 * 32];
  __shared__ __align__(16) u16 Bs[128 * 32];
  int tid = threadIdx.x, wave = tid >> 6, lane = tid & 63;
  int wy = (wave >> 1) * 64, wx = (wave & 1) * 64;
  int lm = lane & 15, lk = lane >> 4;
  const u16* Ab = iq + (size_t)(tb * kIH) * kID;
  const u16* Bb = ik + (size_t)bn * kID;
  floatx4 acc[4][4] = {};
  for (int k0 = 0; k0 < kID; k0 += 32) {
    stage_tile(Ab + k0, kID, As, wave, lane);
    stage_tile(Bb + k0, kID, Bs, wave, lane);
    __syncthreads();
    short8 af[4], bfr[4];
#pragma unroll
    for (int mt = 0; mt < 4; mt++) af[mt] = *(short8*)&As[(wy + mt * 16 + lm) * 32 + lk * 8];
#pragma unroll
    for (int nt = 0; nt < 4; nt++) bfr[nt] = *(short8*)&Bs[(wx + nt * 16 + lm) * 32 + lk * 8];
#pragma unroll
    for (int mt = 0; mt < 4; mt++)
#pragma unroll
      for (int nt = 0; nt < 4; nt++)
        acc[mt][nt] = __builtin_amdgcn_mfma_f32_16x16x32_bf16(af[mt], bfr[nt], acc[mt][nt], 0, 0, 0);
    __syncthreads();
  }
  // epilogue: relu * iksc[s] weighted by iw[t][h], reduce over h (m-rows), store per token
  float scv[4];
#pragma unroll
  for (int nt = 0; nt < 4; nt++) scv[nt] = iksc[bn + wx + nt * 16 + lm];
  float iwv[4][4]; // [mt][r]: h = (mt&1)*16 + lk*4 + r; token = tb + (wy>>5) + (mt>>1)
#pragma unroll
  for (int mt = 0; mt < 4; mt++)
#pragma unroll
    for (int r = 0; r < 4; r++)
      iwv[mt][r] = iw[(tb + (wy >> 5) + (mt >> 1)) * kIH + (mt & 1) * 16 + lk * 4 + r];
#pragma unroll
  for (int tp = 0; tp < 2; tp++) {
    int tglob = tb + (wy >> 5) + tp;
#pragma unroll
    for (int nt = 0; nt < 4; nt++) {
      float v = 0.f;
#pragma unroll
      for (int mh = 0; mh < 2; mh++) {
        int mt = tp * 2 + mh;
#pragma unroll
        for (int r = 0; r < 4; r++)
          v += fmaxf(acc[mt][nt][r] * scv[nt], 0.f) * iwv[mt][r];
      }
      v += __shfl_xor(v, 16, 64);
      v += __shfl_xor(v, 32, 64);
      if (lk == 0) scores[(size_t)tglob * kT + bn + wx + nt * 16 + lm] = v;
    }
  }
}

__global__ __launch_bounds__(64) void k_topk(const float* __restrict__ scores, unsigned long long* __restrict__ mbits) {
  int t = blockIdx.x; int l = threadIdx.x;
  __shared__ unsigned short tmp[64];
  unsigned long long* mrow = mbits + (size_t)t * 16;
  if (t < kTOPK) {
    if (l < 16) {
      int lo = l * 64, hi = lo + 63;
      unsigned long long bits;
      if (hi <= t) bits = ~0ull;
      else if (lo > t) bits = 0ull;
      else bits = (1ull << (t - lo + 1)) - 1ull;
      mrow[l] = bits;
    }
    return;
  }
  unsigned key[16];
  const float* srow = scores + (size_t)t * kT;
#pragma unroll
  for (int i = 0; i < 16; i++) {
    int s = l * 16 + i;
    key[i] = (s <= t) ? sortkey(srow[s]) : 0u;
  }
  unsigned prefix = 0; int remaining = kTOPK;
  for (int bit = 31; bit >= 0; bit--) {
    unsigned himask = 0xFFFFFFFFu << bit;
    unsigned cmp = prefix | (1u << bit);
    int c = 0;
#pragma unroll
    for (int i = 0; i < 16; i++) c += ((key[i] & himask) == cmp) ? 1 : 0;
    c = wsum_i(c);
    if (c >= remaining) prefix = cmp; else remaining -= c;
  }
  int ceq = 0, cgt = 0;
#pragma unroll
  for (int i = 0; i < 16; i++) { ceq += (key[i] == prefix) ? 1 : 0; cgt += (key[i] > prefix) ? 1 : 0; }
  int v = ceq;
#pragma unroll
  for (int o = 1; o < 64; o <<= 1) { int u = __shfl_up(v, o, 64); if (l >= o) v += u; }
  int rank = v - ceq;
  int need = kTOPK - wsum_i(cgt);
  unsigned short mybits = 0;
#pragma unroll
  for (int i = 0; i < 16; i++) {
    int sel;
    if (key[i] > prefix) sel = 1;
    else if (key[i] == prefix) { sel = (rank < need) ? 1 : 0; rank++; }
    else sel = 0;
    mybits |= (unsigned short)(sel << i);
  }
  tmp[l] = mybits;
  __syncthreads();
  if (l < 16) {
    mrow[l] = (unsigned long long)tmp[4 * l] | ((unsigned long long)tmp[4 * l + 1] << 16) |
              ((unsigned long long)tmp[4 * l + 2] << 32) | ((unsigned long long)tmp[4 * l + 3] << 48);
  }
}

__global__ __launch_bounds__(64) void k_route(const float* __restrict__ hs2, const float* __restrict__ wg,
                                              int* __restrict__ cnt, int* __restrict__ toki,
                                              float* __restrict__ tokw) {
  int t = blockIdx.x; int l = threadIdx.x;
  float acc[8] = {};
  for (int d = l; d < kD; d += 64) {
    float hv = hs2[(size_t)t * kD + d];
    const float* wr = wg + (size_t)d * 8;
#pragma unroll
    for (int e = 0; e < 8; e++) acc[e] += hv * wr[e];
  }
#pragma unroll
  for (int e = 0; e < 8; e++) acc[e] = wsum(acc[e]);
  if (l == 0) {
    float g[8];
#pragma unroll
    for (int e = 0; e < 8; e++) g[e] = 1.0f / (1.0f + expf(-acc[e]));
    int i0 = 0;
    for (int e = 1; e < 8; e++) if (g[e] > g[i0]) i0 = e;
    int i1 = (i0 == 0) ? 1 : 0;
    for (int e = 0; e < 8; e++) if (e != i0 && g[e] > g[i1]) i1 = e;
    float ssum = g[i0] + g[i1];
    float w0 = g[i0] / ssum * 2.5f, w1 = g[i1] / ssum * 2.5f;
    int s0 = atomicAdd(&cnt[i0], 1); toki[i0 * kT + s0] = t; tokw[i0 * kT + s0] = w0;
    int s1 = atomicAdd(&cnt[i1], 1); toki[i1 * kT + s1] = t; tokw[i1 * kT + s1] = w1;
  }
}

// ---------------- launch ----------------
extern "C" void kernel_launch(void* const* d_in, const int* in_sizes, int n_in,
                              void* d_out, int out_size, void* d_ws, size_t ws_size,
                              hipStream_t stream) {
  (void)in_sizes; (void)n_in; (void)out_size; (void)ws_size;
  const int*   positions  = (const int*)d_in[0];
  const float* hidden     = (const float*)d_in[1];
  const float* residual   = (const float*)d_in[2];
  const float* input_ln_w = (const float*)d_in[3];
  const float* post_ln_w  = (const float*)d_in[4];
  const float* w_qkv_a    = (const float*)d_in[5];
  const float* q_a_ln_w   = (const float*)d_in[6];
  const float* w_q_b      = (const float*)d_in[7];
  const float* kv_a_ln_w  = (const float*)d_in[8];
  const float* w_kv_b     = (const float*)d_in[9];
  const float* w_o        = (const float*)d_in[10];
  const float* w_idx_q_b  = (const float*)d_in[11];
  const float* w_idx_k    = (const float*)d_in[12];
  const float* idx_k_ln_w = (const float*)d_in[13];
  const float* idx_k_ln_b = (const float*)d_in[14];
  const float* w_idx_w    = (const float*)d_in[15];
  const float* w_gate     = (const float*)d_in[16];
  const float* w_moe_gate = (const float*)d_in[17];
  const float* w_moe_up   = (const float*)d_in[18];
  const float* w_moe_down = (const float*)d_in[19];
  const float* w_sh_gate  = (const float*)d_in[20];
  const float* w_sh_up    = (const float*)d_in[21];
  const float* w_sh_down  = (const float*)d_in[22];

  float* out0 = (float*)d_out;
  float* out1 = out0 + (size_t)kT * kD;

  char* W = (char*)d_ws;
  size_t off = 0;
  auto alloc = [&](size_t bytes) { char* p = W + off; off += (bytes + 255) & ~(size_t)255; return p; };
  // f32 buffers
  float* resid   = (float*)alloc((size_t)kT * kD * 4);
  float* hs      = (float*)alloc((size_t)kT * kD * 4);
  float* qkv     = (float*)alloc((size_t)kT * kQKV_N * 4);
  float* qb      = (float*)alloc((size_t)kT * kH * kQKD * 4);
  float* kvb     = (float*)alloc((size_t)kT * kH * 256 * 4);
  float* iqb     = (float*)alloc((size_t)kT * kIH * kID * 4);
  float* ikraw   = (float*)alloc((size_t)kT * kID * 4);
  float* iksc    = (float*)alloc(kT * 4);
  float* iqsc    = (float*)alloc((size_t)kT * kIH * 4);
  float* iwb     = (float*)alloc((size_t)kT * kIH * 4);
  float* kpe     = (float*)alloc((size_t)kT * kROPE * 4);
  float* scoresb = (float*)alloc((size_t)kT * kT * 4);
  float* hs2     = (float*)alloc((size_t)kT * kD * 4);
  unsigned long long* mbits = (unsigned long long*)alloc((size_t)kT * 16 * 8);
  float* tokw    = (float*)alloc((size_t)kE * kT * 4);
  int*   toki    = (int*)alloc((size_t)kE * kT * 4);
  int*   cnt     = (int*)alloc(64);
  // bf16 activations
  u16* hs_h   = (u16*)alloc((size_t)kT * kD * 2);
  u16* hs_l   = (u16*)alloc((size_t)kT * kD * 2);
  u16* qc_h   = (u16*)alloc((size_t)kT * kQL * 2);
  u16* qc_l   = (u16*)alloc((size_t)kT * kQL * 2);
  u16* kvc_h  = (u16*)alloc((size_t)kT * kKVL * 2);
  u16* o_bf   = (u16*)alloc((size_t)kT * kH * kVD * 2);
  u16* hs2_h  = (u16*)alloc((size_t)kT * kD * 2);
  u16* sg_bf  = (u16*)alloc((size_t)kT * kF * 2);
  u16* hmid_bf= (u16*)alloc((size_t)kE * kT * kF * 2);
  u16* iq_bf  = (u16*)alloc((size_t)kT * kIH * kID * 2);
  u16* ik_bf  = (u16*)alloc((size_t)kT * kID * 2);
  // bf16 transposed weights
  u16* qkvBT_h = (u16*)alloc((size_t)kQKV_NP * kD * 2);
  u16* qkvBT_l = (u16*)alloc((size_t)kQKV_NP * kD * 2);
  u16* qbBT    = (u16*)alloc((size_t)kH * kQKD * kQL * 2);
  u16* kvbBT   = (u16*)alloc((size_t)kH * 256 * kKVL * 2);
  u16* woBT    = (u16*)alloc((size_t)kD * kH * kVD * 2);
  u16* iqBT_h  = (u16*)alloc((size_t)kIH * kID * kQL * 2);
  u16* iqBT_l  = (u16*)alloc((size_t)kIH * kID * kQL * 2);
  u16* ikBT_h  = (u16*)alloc((size_t)kID * kD * 2);
  u16* ikBT_l  = (u16*)alloc((size_t)kID * kD * 2);
  u16* shgBT   = (u16*)alloc((size_t)kF * kD * 2);
  u16* shuBT   = (u16*)alloc((size_t)kF * kD * 2);
  u16* shdBT   = (u16*)alloc((size_t)kD * kF * 2);
  u16* moegBT  = (u16*)alloc((size_t)kE * kF * kD * 2);
  u16* moeuBT  = (u16*)alloc((size_t)kE * kF * kD * 2);
  u16* moedBT  = (u16*)alloc((size_t)kE * kD * kF * 2);

  // ---- weight prep (runs every launch; inputs are constant) ----
  { dim3 g(kQKV_NP / 32, kD / 32); k_transpose_w<<<g, 256, 0, stream>>>(w_qkv_a, qkvBT_h, qkvBT_l, kD, kQKV_N, kQKV_NP); }
  { dim3 g(kH * kQKD / 32, kQL / 32); k_transpose_w<<<g, 256, 0, stream>>>(w_q_b, qbBT, nullptr, kQL, kH * kQKD, kH * kQKD); }
  { dim3 g(kH * 256 / 32, kKVL / 32); k_transpose_w<<<g, 256, 0, stream>>>(w_kv_b, kvbBT, nullptr, kKVL, kH * 256, kH * 256); }
  { dim3 g(kD / 32, kH * kVD / 32); k_transpose_w<<<g, 256, 0, stream>>>(w_o, woBT, nullptr, kH * kVD, kD, kD); }
  { dim3 g(kIH * kID / 32, kQL / 32); k_transpose_w<<<g, 256, 0, stream>>>(w_idx_q_b, iqBT_h, iqBT_l, kQL, kIH * kID, kIH * kID); }
  { dim3 g(kID / 32, kD / 32); k_transpose_w<<<g, 256, 0, stream>>>(w_idx_k, ikBT_h, ikBT_l, kD, kID, kID); }
  { dim3 g(kF / 32, kD / 32); k_transpose_w<<<g, 256, 0, stream>>>(w_sh_gate, shgBT, nullptr, kD, kF, kF); }
  { dim3 g(kF / 32, kD / 32); k_transpose_w<<<g, 256, 0, stream>>>(w_sh_up, shuBT, nullptr, kD, kF, kF); }
  { dim3 g(kD / 32, kF / 32); k_transpose_w<<<g, 256, 0, stream>>>(w_sh_down, shdBT, nullptr, kF, kD, kD); }
  { dim3 g(kF / 32, kD / 32, kE); k_transpose_w<<<g, 256, 0, stream>>>(w_moe_gate, moegBT, nullptr, kD, kF, kF); }
  { dim3 g(kF / 32, kD / 32, kE); k_transpose_w<<<g, 256, 0, stream>>>(w_moe_up, moeuBT, nullptr, kD, kF, kF); }
  { dim3 g(kD / 32, kF / 32, kE); k_transpose_w<<<g, 256, 0, stream>>>(w_moe_down, moedBT, nullptr, kF, kD, kD); }

  // ---- forward ----
  k_add_rms<<<kT, 256, 0, stream>>>(hidden, residual, input_ln_w, resid, hs, hs_h, hs_l);
  { dim3 g(kQKV_NP / 128, kT / 128); k_gemm_split<<<g, 256, 0, stream>>>(hs_h, hs_l, qkvBT_h, qkvBT_l, qkv, kT, kQKV_N, kD); }
  k_rms_rows<<<kT, 256, 0, stream>>>(qkv, kQKV_N, 0, q_a_ln_w, nullptr, qc_h, qc_l, kQL);
  k_rms_rows<<<kT, 256, 0, stream>>>(qkv, kQKV_N, kQL, kv_a_ln_w, nullptr, kvc_h, nullptr, kKVL);
  { dim3 g(kH * kQKD / 128, kT / 128); k_gemm_bt<<<g, 256, 0, stream>>>(qc_h, qbBT, qb, nullptr, kT, kH * kQKD, kQL); }
  { dim3 g(kIH * kID / 128, kT / 128); k_gemm_split<<<g, 256, 0, stream>>>(qc_h, qc_l, iqBT_h, iqBT_l, iqb, kT, kIH * kID, kQL); }
  { dim3 g(kH * 256 / 128, kT / 128); k_gemm_bt<<<g, 256, 0, stream>>>(kvc_h, kvbBT, kvb, nullptr, kT, kH * 256, kKVL); }
  { dim3 g(kID / 128, kT / 128); k_gemm_split<<<g, 256, 0, stream>>>(hs_h, hs_l, ikBT_h, ikBT_l, ikraw, kT, kID, kD); }
  k_rope_q<<<kT, 256, 0, stream>>>(qb, positions);
  k_rope_iq<<<kT, 256, 0, stream>>>(iqb, positions);
  k_rope_kpe<<<kT, 64, 0, stream>>>(qkv, positions, kpe);
  k_quant_rows<<<kT * kIH, 64, 0, stream>>>(iqb, iq_bf, iqsc);
  k_ik_process<<<kT, 64, 0, stream>>>(ikraw, idx_k_ln_w, idx_k_ln_b, positions, ik_bf, iksc);
  k_iw_fused<<<kT, 256, 0, stream>>>(hs, w_idx_w, iqsc, iwb);
  { dim3 g(kT / 128, kT / 4); k_scores_mfma<<<g, 256, 0, stream>>>(iq_bf, ik_bf, iksc, iwb, scoresb); }
  k_topk<<<kT, 64, 0, stream>>>(scoresb, mbits);
  { dim3 g(kT / 64, kH); k_attn_mfma<<<g, 256, 0, stream>>>(qb, kvb, kpe, mbits, o_bf); }
  { dim3 g(kD / 128, kT / 128); k_gemm_bt<<<g, 256, 0, stream>>>(o_bf, woBT, out1, resid, kT, kD, kH * kVD); }
  k_rms_rows<<<kT, 256, 0, stream>>>(out1, kD, 0, post_ln_w, hs2, hs2_h, nullptr, kD);
  hipMemsetAsync(cnt, 0, 8 * sizeof(int), stream);
  k_route<<<kT, 64, 0, stream>>>(hs2, w_gate, cnt, toki, tokw);
  { dim3 g(kF / 128, kT / 128, 1); k_dual_bt<<<g, 256, 0, stream>>>(hs2_h, shgBT, shuBT, sg_bf, nullptr, nullptr, kT, kF, kD); }
  { dim3 g(kD / 128, kT / 128); k_gemm_bt<<<g, 256, 0, stream>>>(sg_bf, shdBT, out0, nullptr, kT, kD, kF); }
  { dim3 g(kF / 128, kT / 128, kE); k_dual_bt<<<g, 256, 0, stream>>>(hs2_h, moegBT, moeuBT, hmid_bf, toki, cnt, kT, kF, kD); }
  { dim3 g(kD / 128, kT / 128, kE); k_down_bt<<<g, 256, 0, stream>>>(hmid_bf, moedBT, toki, tokw, cnt, out0); }
}

// Round 4
// 1005.327 us; speedup vs baseline: 1.4541x; 1.1421x over previous
//
#include <hip/hip_runtime.h>

namespace {
constexpr int kT = 1024, kD = 2048, kH = 16, kNOPE = 128, kROPE = 64, kVD = 128, kQKD = 192;
constexpr int kQL = 768, kKVL = 512, kIH = 32, kID = 128, kTOPK = 256, kE = 8, kF = 1024;
constexpr int kQKV_N = kQL + kKVL + kROPE; // 1344
constexpr int kQKV_NP = 1408;              // padded to 128
constexpr int kIKOFF = 1408;               // ik columns start here in fused buffer
constexpr int kQKV_F = 1536;               // fused qkv+ik padded width
}

typedef __attribute__((ext_vector_type(4))) float floatx4;
typedef __attribute__((ext_vector_type(8))) short short8;
typedef unsigned short u16;

// ---------------- device helpers ----------------
__device__ __forceinline__ float wsum(float v) {
#pragma unroll
  for (int o = 32; o; o >>= 1) v += __shfl_xor(v, o, 64);
  return v;
}
__device__ __forceinline__ float wmax64(float v) {
#pragma unroll
  for (int o = 32; o; o >>= 1) v = fmaxf(v, __shfl_xor(v, o, 64));
  return v;
}
__device__ __forceinline__ int wsum_i(int v) {
#pragma unroll
  for (int o = 32; o; o >>= 1) v += __shfl_xor(v, o, 64);
  return v;
}
__device__ __forceinline__ float bsum256(float v, float* red) {
  v = wsum(v);
  if ((threadIdx.x & 63) == 0) red[threadIdx.x >> 6] = v;
  __syncthreads();
  float t = red[0] + red[1] + red[2] + red[3];
  __syncthreads();
  return t;
}
__device__ __forceinline__ unsigned sortkey(float f) {
  unsigned b = __float_as_uint(f);
  return (b & 0x80000000u) ? ~b : (b | 0x80000000u);
}
__device__ __forceinline__ float pow2ceil(float z) {
  unsigned b = __float_as_uint(z);
  if ((b & 0x7FFFFFu) == 0) return z;
  return __uint_as_float((((b >> 23) & 0xFFu) + 1u) << 23);
}
__device__ __forceinline__ float fp8q(float x) {
  float ax = fabsf(x);
  float q;
  if (ax < 0.015625f) {
    q = rintf(ax * 512.0f) * 0.001953125f;
  } else {
    unsigned b = __float_as_uint(ax);
    int e = (int)((b >> 23) & 0xFF) - 127;
    float quant = __uint_as_float((unsigned)(e - 3 + 127) << 23);
    float rq    = __uint_as_float((unsigned)(127 - (e - 3)) << 23);
    q = rintf(ax * rq) * quant;
  }
  return copysignf(q, x);
}
__device__ __forceinline__ u16 f2bf(float x) {
  unsigned u = __float_as_uint(x);
  u += 0x7FFFu + ((u >> 16) & 1u);
  return (u16)(u >> 16);
}
__device__ __forceinline__ float bf2f(u16 h) { return __uint_as_float((unsigned)h << 16); }

// async global->LDS, 16B per lane; lds ptr must be wave-uniform (HW adds lane*16)
__device__ __forceinline__ void gld_lds16(const void* g, void* l) {
  __builtin_amdgcn_global_load_lds(
      (const __attribute__((address_space(1))) unsigned int*)(unsigned long long)g,
      (__attribute__((address_space(3))) unsigned int*)(unsigned int)(unsigned long long)l,
      16, 0, 0);
}
// stage 128 rows x 32 bf16 cols; wave stages rows [wave*32, wave*32+32)
__device__ __forceinline__ void stage_tile(const u16* g, size_t strideUs, u16* tile, int wave, int lane) {
  int r = lane >> 2, c = lane & 3;
  const u16* gp = g + (size_t)(wave * 32 + r) * strideUs + c * 8;
  gld_lds16(gp, tile + (wave * 32) * 32);
  gld_lds16(gp + (size_t)16 * strideUs, tile + (wave * 32 + 16) * 32);
}

// ---------------- weight prep: f32 [K][N] -> bf16 BT [Npad][K] (+optional lo) ----------------
__global__ __launch_bounds__(256) void k_transpose_w(const float* __restrict__ in, u16* __restrict__ hi,
                                                     u16* __restrict__ lo, int K, int N, int Npad) {
  __shared__ float tile[32][33];
  int n0 = blockIdx.x * 32, k0 = blockIdx.y * 32;
  const float* ip = in + (size_t)blockIdx.z * K * N;
  u16* hp = hi + (size_t)blockIdx.z * Npad * K;
  u16* lp = lo ? lo + (size_t)blockIdx.z * Npad * K : nullptr;
  int t = threadIdx.x;
  int r = t >> 3, c4 = (t & 7) << 2;
  if (n0 < N) {
    float4 v = *(const float4*)&ip[(size_t)(k0 + r) * N + n0 + c4];
    tile[r][c4] = v.x; tile[r][c4 + 1] = v.y; tile[r][c4 + 2] = v.z; tile[r][c4 + 3] = v.w;
  } else {
    tile[r][c4] = 0.f; tile[r][c4 + 1] = 0.f; tile[r][c4 + 2] = 0.f; tile[r][c4 + 3] = 0.f;
  }
  __syncthreads();
  int n = t >> 3, kq = (t & 7) << 2;
  ushort4 h4, l4;
#pragma unroll
  for (int j = 0; j < 4; j++) {
    float f = tile[kq + j][n];
    u16 h = f2bf(f);
    ((u16*)&h4)[j] = h;
    ((u16*)&l4)[j] = f2bf(f - bf2f(h));
  }
  *(ushort4*)&hp[(size_t)(n0 + n) * K + k0 + kq] = h4;
  if (lp) *(ushort4*)&lp[(size_t)(n0 + n) * K + k0 + kq] = l4;
}

// ---------------- GEMM family: bf16 A [M][K], bf16 BT [N][K], global_load_lds staging ----------
// 128x128 tile, BK=32, 4 waves in 2x2 quadrants.

__global__ __launch_bounds__(256) void k_gemm_bt(const u16* __restrict__ A, const u16* __restrict__ BT,
                                                 float* __restrict__ C, const float* __restrict__ addend,
                                                 int M, int N, int K) {
  __shared__ __align__(16) u16 As[128 * 32];
  __shared__ __align__(16) u16 Bs[128 * 32];
  int tid = threadIdx.x, wave = tid >> 6, lane = tid & 63;
  int bm = blockIdx.y * 128, bn = blockIdx.x * 128;
  int wy = (wave >> 1) * 64, wx = (wave & 1) * 64;
  int lm = lane & 15, lk = lane >> 4;
  const u16* Ab = A + (size_t)bm * K;
  const u16* Bb = BT + (size_t)bn * K;
  floatx4 acc[4][4] = {};
  for (int k0 = 0; k0 < K; k0 += 32) {
    stage_tile(Ab + k0, K, As, wave, lane);
    stage_tile(Bb + k0, K, Bs, wave, lane);
    __syncthreads();
    short8 af[4], bfr[4];
#pragma unroll
    for (int mt = 0; mt < 4; mt++) af[mt] = *(short8*)&As[(wy + mt * 16 + lm) * 32 + lk * 8];
#pragma unroll
    for (int nt = 0; nt < 4; nt++) bfr[nt] = *(short8*)&Bs[(wx + nt * 16 + lm) * 32 + lk * 8];
#pragma unroll
    for (int mt = 0; mt < 4; mt++)
#pragma unroll
      for (int nt = 0; nt < 4; nt++)
        acc[mt][nt] = __builtin_amdgcn_mfma_f32_16x16x32_bf16(af[mt], bfr[nt], acc[mt][nt], 0, 0, 0);
    __syncthreads();
  }
#pragma unroll
  for (int mt = 0; mt < 4; mt++)
#pragma unroll
    for (int nt = 0; nt < 4; nt++)
#pragma unroll
      for (int r = 0; r < 4; r++) {
        int m = bm + wy + mt * 16 + lk * 4 + r;
        int n = bn + wx + nt * 16 + lm;
        float v = acc[mt][nt][r];
        if (addend) v += addend[(size_t)m * N + n];
        C[(size_t)m * N + n] = v;
      }
}

// 3-term split-precision GEMM: C = Ahi*Bhi + Ahi*Blo + Alo*Bhi (f32-class accuracy).
// N may be < padded BT rows; C guarded & strided by N.
__global__ __launch_bounds__(256) void k_gemm_split(const u16* __restrict__ Ah, const u16* __restrict__ Al,
                                                    const u16* __restrict__ Bh, const u16* __restrict__ Bl,
                                                    float* __restrict__ C, int M, int N, int K) {
  __shared__ __align__(16) u16 Ahs[128 * 32];
  __shared__ __align__(16) u16 Als[128 * 32];
  __shared__ __align__(16) u16 Bhs[128 * 32];
  __shared__ __align__(16) u16 Bls[128 * 32];
  int tid = threadIdx.x, wave = tid >> 6, lane = tid & 63;
  int bm = blockIdx.y * 128, bn = blockIdx.x * 128;
  int wy = (wave >> 1) * 64, wx = (wave & 1) * 64;
  int lm = lane & 15, lk = lane >> 4;
  floatx4 acc[4][4] = {};
  for (int k0 = 0; k0 < K; k0 += 32) {
    stage_tile(Ah + (size_t)bm * K + k0, K, Ahs, wave, lane);
    stage_tile(Al + (size_t)bm * K + k0, K, Als, wave, lane);
    stage_tile(Bh + (size_t)bn * K + k0, K, Bhs, wave, lane);
    stage_tile(Bl + (size_t)bn * K + k0, K, Bls, wave, lane);
    __syncthreads();
    short8 ah[4], al[4], bh[4], bl[4];
#pragma unroll
    for (int mt = 0; mt < 4; mt++) { ah[mt] = *(short8*)&Ahs[(wy + mt * 16 + lm) * 32 + lk * 8];
                                     al[mt] = *(short8*)&Als[(wy + mt * 16 + lm) * 32 + lk * 8]; }
#pragma unroll
    for (int nt = 0; nt < 4; nt++) { bh[nt] = *(short8*)&Bhs[(wx + nt * 16 + lm) * 32 + lk * 8];
                                     bl[nt] = *(short8*)&Bls[(wx + nt * 16 + lm) * 32 + lk * 8]; }
#pragma unroll
    for (int mt = 0; mt < 4; mt++)
#pragma unroll
      for (int nt = 0; nt < 4; nt++) {
        floatx4 a = acc[mt][nt];
        a = __builtin_amdgcn_mfma_f32_16x16x32_bf16(al[mt], bh[nt], a, 0, 0, 0);
        a = __builtin_amdgcn_mfma_f32_16x16x32_bf16(ah[mt], bl[nt], a, 0, 0, 0);
        a = __builtin_amdgcn_mfma_f32_16x16x32_bf16(ah[mt], bh[nt], a, 0, 0, 0);
        acc[mt][nt] = a;
      }
    __syncthreads();
  }
#pragma unroll
  for (int mt = 0; mt < 4; mt++)
#pragma unroll
    for (int nt = 0; nt < 4; nt++)
#pragma unroll
      for (int r = 0; r < 4; r++) {
        int m = bm + wy + mt * 16 + lk * 4 + r;
        int n = bn + wx + nt * 16 + lm;
        if (n < N) C[(size_t)m * N + n] = acc[mt][nt][r];
      }
}

// split-K 3-term GEMM: partial C per kz chunk, unguarded padded-N writes.
// Cp layout: [KSPLIT][M][Npad] f32.
__global__ __launch_bounds__(256) void k_gemm_splitk(const u16* __restrict__ Ah, const u16* __restrict__ Al,
                                                     const u16* __restrict__ Bh, const u16* __restrict__ Bl,
                                                     float* __restrict__ Cp, int M, int Npad, int K, int kchunk) {
  __shared__ __align__(16) u16 Ahs[128 * 32];
  __shared__ __align__(16) u16 Als[128 * 32];
  __shared__ __align__(16) u16 Bhs[128 * 32];
  __shared__ __align__(16) u16 Bls[128 * 32];
  int tid = threadIdx.x, wave = tid >> 6, lane = tid & 63;
  int bm = blockIdx.y * 128, bn = blockIdx.x * 128;
  int kz = blockIdx.z;
  int kbeg = kz * kchunk, kend = kbeg + kchunk;
  int wy = (wave >> 1) * 64, wx = (wave & 1) * 64;
  int lm = lane & 15, lk = lane >> 4;
  floatx4 acc[4][4] = {};
  for (int k0 = kbeg; k0 < kend; k0 += 32) {
    stage_tile(Ah + (size_t)bm * K + k0, K, Ahs, wave, lane);
    stage_tile(Al + (size_t)bm * K + k0, K, Als, wave, lane);
    stage_tile(Bh + (size_t)bn * K + k0, K, Bhs, wave, lane);
    stage_tile(Bl + (size_t)bn * K + k0, K, Bls, wave, lane);
    __syncthreads();
    short8 ah[4], al[4], bh[4], bl[4];
#pragma unroll
    for (int mt = 0; mt < 4; mt++) { ah[mt] = *(short8*)&Ahs[(wy + mt * 16 + lm) * 32 + lk * 8];
                                     al[mt] = *(short8*)&Als[(wy + mt * 16 + lm) * 32 + lk * 8]; }
#pragma unroll
    for (int nt = 0; nt < 4; nt++) { bh[nt] = *(short8*)&Bhs[(wx + nt * 16 + lm) * 32 + lk * 8];
                                     bl[nt] = *(short8*)&Bls[(wx + nt * 16 + lm) * 32 + lk * 8]; }
#pragma unroll
    for (int mt = 0; mt < 4; mt++)
#pragma unroll
      for (int nt = 0; nt < 4; nt++) {
        floatx4 a = acc[mt][nt];
        a = __builtin_amdgcn_mfma_f32_16x16x32_bf16(al[mt], bh[nt], a, 0, 0, 0);
        a = __builtin_amdgcn_mfma_f32_16x16x32_bf16(ah[mt], bl[nt], a, 0, 0, 0);
        a = __builtin_amdgcn_mfma_f32_16x16x32_bf16(ah[mt], bh[nt], a, 0, 0, 0);
        acc[mt][nt] = a;
      }
    __syncthreads();
  }
  float* Co = Cp + (size_t)kz * M * Npad;
#pragma unroll
  for (int mt = 0; mt < 4; mt++)
#pragma unroll
    for (int nt = 0; nt < 4; nt++)
#pragma unroll
      for (int r = 0; r < 4; r++) {
        int m = bm + wy + mt * 16 + lk * 4 + r;
        int n = bn + wx + nt * 16 + lm;
        Co[(size_t)m * Npad + n] = acc[mt][nt][r];
      }
}

// sum 4 partials: C[i] = sum_z Cp[z][i], vectorized float4
__global__ __launch_bounds__(256) void k_reduce4(const float* __restrict__ Cp, float* __restrict__ C, int n4) {
  int i = blockIdx.x * 256 + threadIdx.x;
  if (i >= n4) return;
  const floatx4* p = (const floatx4*)Cp;
  floatx4 v = p[i] + p[i + n4] + p[i + 2 * n4] + p[i + 3 * n4];
  ((floatx4*)C)[i] = v;
}

// dual-B gate+up with silu epilogue -> bf16 out; optional row gather (MoE), z = expert
__global__ __launch_bounds__(256) void k_dual_bt(const u16* __restrict__ A, const u16* __restrict__ GT,
                                                 const u16* __restrict__ UT, u16* __restrict__ out,
                                                 const int* __restrict__ toki, const int* __restrict__ cnt,
                                                 int M, int N, int K) {
  int e = blockIdx.z;
  int n_rows = toki ? cnt[e] : M;
  int bm = blockIdx.y * 128;
  if (bm >= n_rows) return;
  int bn = blockIdx.x * 128;
  const int* tk = toki ? (toki + e * kT) : nullptr;
  const u16* Gb = GT + (size_t)e * N * K + (size_t)bn * K;
  const u16* Ub = UT + (size_t)e * N * K + (size_t)bn * K;
  u16* oP = out + (size_t)e * kT * N;
  __shared__ __align__(16) u16 As[128 * 32];
  __shared__ __align__(16) u16 Gs[128 * 32];
  __shared__ __align__(16) u16 Us[128 * 32];
  int tid = threadIdx.x, wave = tid >> 6, lane = tid & 63;
  int wy = (wave >> 1) * 64, wx = (wave & 1) * 64;
  int lm = lane & 15, lk = lane >> 4;
  int r = lane >> 2, c = lane & 3;
  int r0 = bm + wave * 32 + r, r1 = r0 + 16;
  size_t arow0 = tk ? (size_t)((r0 < n_rows) ? tk[r0] : 0) : (size_t)r0;
  size_t arow1 = tk ? (size_t)((r1 < n_rows) ? tk[r1] : 0) : (size_t)r1;
  floatx4 ag[4][4] = {}, au[4][4] = {};
  for (int k0 = 0; k0 < K; k0 += 32) {
    gld_lds16(A + arow0 * K + k0 + c * 8, As + (wave * 32) * 32);
    gld_lds16(A + arow1 * K + k0 + c * 8, As + (wave * 32 + 16) * 32);
    stage_tile(Gb + k0, K, Gs, wave, lane);
    stage_tile(Ub + k0, K, Us, wave, lane);
    __syncthreads();
    short8 af[4], gf[4], uf[4];
#pragma unroll
    for (int mt = 0; mt < 4; mt++) af[mt] = *(short8*)&As[(wy + mt * 16 + lm) * 32 + lk * 8];
#pragma unroll
    for (int nt = 0; nt < 4; nt++) { gf[nt] = *(short8*)&Gs[(wx + nt * 16 + lm) * 32 + lk * 8];
                                     uf[nt] = *(short8*)&Us[(wx + nt * 16 + lm) * 32 + lk * 8]; }
#pragma unroll
    for (int mt = 0; mt < 4; mt++)
#pragma unroll
      for (int nt = 0; nt < 4; nt++) {
        ag[mt][nt] = __builtin_amdgcn_mfma_f32_16x16x32_bf16(af[mt], gf[nt], ag[mt][nt], 0, 0, 0);
        au[mt][nt] = __builtin_amdgcn_mfma_f32_16x16x32_bf16(af[mt], uf[nt], au[mt][nt], 0, 0, 0);
      }
    __syncthreads();
  }
#pragma unroll
  for (int mt = 0; mt < 4; mt++)
#pragma unroll
    for (int nt = 0; nt < 4; nt++)
#pragma unroll
      for (int r2 = 0; r2 < 4; r2++) {
        int gm = bm + wy + mt * 16 + lk * 4 + r2;
        if (gm >= n_rows) continue;
        int n = bn + wx + nt * 16 + lm;
        float gv = ag[mt][nt][r2], uv = au[mt][nt][r2];
        oP[(size_t)gm * N + n] = f2bf(gv * (1.0f / (1.0f + expf(-gv))) * uv);
      }
}

// down: out[tok] += w * (hmid[e] @ wd[e]); A compact bf16 per expert; atomic scatter f32
__global__ __launch_bounds__(256) void k_down_bt(const u16* __restrict__ hmid, const u16* __restrict__ DT,
                                                 const int* __restrict__ toki, const float* __restrict__ tokw,
                                                 const int* __restrict__ cnt, float* __restrict__ out) {
  int e = blockIdx.z;
  int n_rows = cnt[e];
  int bm = blockIdx.y * 128;
  if (bm >= n_rows) return;
  int bn = blockIdx.x * 128;
  const u16* Ab = hmid + (size_t)e * kT * kF + (size_t)bm * kF;
  const u16* Bb = DT + (size_t)e * kD * kF + (size_t)bn * kF;
  __shared__ __align__(16) u16 As[128 * 32];
  __shared__ __align__(16) u16 Bs[128 * 32];
  int tid = threadIdx.x, wave = tid >> 6, lane = tid & 63;
  int wy = (wave >> 1) * 64, wx = (wave & 1) * 64;
  int lm = lane & 15, lk = lane >> 4;
  floatx4 acc[4][4] = {};
  for (int k0 = 0; k0 < kF; k0 += 32) {
    stage_tile(Ab + k0, kF, As, wave, lane);
    stage_tile(Bb + k0, kF, Bs, wave, lane);
    __syncthreads();
    short8 af[4], bfr[4];
#pragma unroll
    for (int mt = 0; mt < 4; mt++) af[mt] = *(short8*)&As[(wy + mt * 16 + lm) * 32 + lk * 8];
#pragma unroll
    for (int nt = 0; nt < 4; nt++) bfr[nt] = *(short8*)&Bs[(wx + nt * 16 + lm) * 32 + lk * 8];
#pragma unroll
    for (int mt = 0; mt < 4; mt++)
#pragma unroll
      for (int nt = 0; nt < 4; nt++)
        acc[mt][nt] = __builtin_amdgcn_mfma_f32_16x16x32_bf16(af[mt], bfr[nt], acc[mt][nt], 0, 0, 0);
    __syncthreads();
  }
#pragma unroll
  for (int mt = 0; mt < 4; mt++)
#pragma unroll
    for (int r = 0; r < 4; r++) {
      int gm = bm + wy + mt * 16 + lk * 4 + r;
      if (gm >= n_rows) continue;
      int tt = toki[e * kT + gm];
      float w = tokw[e * kT + gm];
#pragma unroll
      for (int nt = 0; nt < 4; nt++) {
        int n = bn + wx + nt * 16 + lm;
        atomicAdd(&out[(size_t)tt * kD + n], w * acc[mt][nt][r]);
      }
    }
}

// ---------------- flash MFMA attention (bf16 out) ----------------
__global__ __launch_bounds__(256) void k_attn_mfma(const float* __restrict__ q, const float* __restrict__ kv,
                                                   const float* __restrict__ kpe,
                                                   const unsigned long long* __restrict__ mbits,
                                                   u16* __restrict__ o) {
  __shared__ __align__(16) u16 Ks[64 * 200];
  __shared__ __align__(16) u16 Vs[128 * 72];
  __shared__ __align__(16) u16 Ps[4 * 16 * 72];
  int h = blockIdx.y;
  int qb = gridDim.x - 1 - blockIdx.x;
  int qbase = qb * 64;
  int tid = threadIdx.x;
  int wave = tid >> 6, lane = tid & 63;
  int lm = lane & 15, lk = lane >> 4;
  short8 qf[6];
  {
    const float* qrow = q + ((size_t)(qbase + wave * 16 + lm) * kH + h) * kQKD;
#pragma unroll
    for (int ks = 0; ks < 6; ks++) {
      const float4 a0 = *(const float4*)&qrow[ks * 32 + lk * 8];
      const float4 a1 = *(const float4*)&qrow[ks * 32 + lk * 8 + 4];
      short8 f;
      f[0] = (short)f2bf(a0.x); f[1] = (short)f2bf(a0.y); f[2] = (short)f2bf(a0.z); f[3] = (short)f2bf(a0.w);
      f[4] = (short)f2bf(a1.x); f[5] = (short)f2bf(a1.y); f[6] = (short)f2bf(a1.z); f[7] = (short)f2bf(a1.w);
      qf[ks] = f;
    }
  }
  float m_r[4] = {-1e30f, -1e30f, -1e30f, -1e30f};
  float l_r[4] = {};
  floatx4 Oacc[8] = {};
  int sr = tid >> 2, sj = tid & 3;
  int nch = qb + 1;
  for (int ch = 0; ch < nch; ch++) {
    int s0 = ch << 6;
    __syncthreads();
    {
      const float* kvrow = kv + ((size_t)(s0 + sr) * kH + h) * 256;
      const float* kprow = kpe + (size_t)(s0 + sr) * 64;
#pragma unroll
      for (int i = 0; i < 12; i++) {
        int c4 = (i << 2) + sj;
        float4 v4 = (c4 < 32) ? *(const float4*)&kvrow[c4 * 4] : *(const float4*)&kprow[(c4 - 32) * 4];
        ushort4 p; p.x = f2bf(v4.x); p.y = f2bf(v4.y); p.z = f2bf(v4.z); p.w = f2bf(v4.w);
        *(ushort4*)&Ks[sr * 200 + c4 * 4] = p;
      }
      const float* vrow = kvrow + 128;
#pragma unroll
      for (int i = 0; i < 8; i++) {
        int c4 = (i << 2) + sj;
        float4 v4 = *(const float4*)&vrow[c4 * 4];
        Vs[(c4 * 4 + 0) * 72 + sr] = f2bf(v4.x);
        Vs[(c4 * 4 + 1) * 72 + sr] = f2bf(v4.y);
        Vs[(c4 * 4 + 2) * 72 + sr] = f2bf(v4.z);
        Vs[(c4 * 4 + 3) * 72 + sr] = f2bf(v4.w);
      }
    }
    __syncthreads();
    floatx4 sacc[4] = {};
#pragma unroll
    for (int ks = 0; ks < 6; ks++) {
      short8 kf[4];
#pragma unroll
      for (int nt = 0; nt < 4; nt++) kf[nt] = *(short8*)&Ks[(nt * 16 + lm) * 200 + ks * 32 + lk * 8];
#pragma unroll
      for (int nt = 0; nt < 4; nt++)
        sacc[nt] = __builtin_amdgcn_mfma_f32_16x16x32_bf16(qf[ks], kf[nt], sacc[nt], 0, 0, 0);
    }
    unsigned long long mw[4];
#pragma unroll
    for (int r = 0; r < 4; r++) mw[r] = mbits[(size_t)(qbase + wave * 16 + lk * 4 + r) * 16 + ch];
    float mx[4] = {-1e30f, -1e30f, -1e30f, -1e30f};
#pragma unroll
    for (int nt = 0; nt < 4; nt++)
#pragma unroll
      for (int r = 0; r < 4; r++) {
        int sel = (int)((mw[r] >> (nt * 16 + lm)) & 1ull);
        float sv = sel ? sacc[nt][r] * 0.07216878364870323f : -1e30f;
        sacc[nt][r] = sv;
        mx[r] = fmaxf(mx[r], sv);
      }
#pragma unroll
    for (int off = 1; off < 16; off <<= 1)
#pragma unroll
      for (int r = 0; r < 4; r++) mx[r] = fmaxf(mx[r], __shfl_xor(mx[r], off, 64));
    float al[4], psum[4] = {};
#pragma unroll
    for (int r = 0; r < 4; r++) {
      float mnew = fmaxf(m_r[r], mx[r]);
      al[r] = __expf(m_r[r] - mnew);
      m_r[r] = mnew;
    }
#pragma unroll
    for (int nt = 0; nt < 4; nt++)
#pragma unroll
      for (int r = 0; r < 4; r++) {
        float p = (sacc[nt][r] > -0.9e30f) ? __expf(sacc[nt][r] - m_r[r]) : 0.0f;
        psum[r] += p;
        Ps[wave * 1152 + (lk * 4 + r) * 72 + nt * 16 + lm] = f2bf(p);
      }
#pragma unroll
    for (int off = 1; off < 16; off <<= 1)
#pragma unroll
      for (int r = 0; r < 4; r++) psum[r] += __shfl_xor(psum[r], off, 64);
#pragma unroll
    for (int r = 0; r < 4; r++) l_r[r] = l_r[r] * al[r] + psum[r];
#pragma unroll
    for (int nv = 0; nv < 8; nv++)
#pragma unroll
      for (int r = 0; r < 4; r++) Oacc[nv][r] *= al[r];
    short8 pf[2];
#pragma unroll
    for (int k2 = 0; k2 < 2; k2++) pf[k2] = *(short8*)&Ps[wave * 1152 + lm * 72 + k2 * 32 + lk * 8];
#pragma unroll
    for (int k2 = 0; k2 < 2; k2++)
#pragma unroll
      for (int nv = 0; nv < 8; nv++) {
        short8 vf = *(short8*)&Vs[(nv * 16 + lm) * 72 + k2 * 32 + lk * 8];
        Oacc[nv] = __builtin_amdgcn_mfma_f32_16x16x32_bf16(pf[k2], vf, Oacc[nv], 0, 0, 0);
      }
  }
  float invl[4];
#pragma unroll
  for (int r = 0; r < 4; r++) invl[r] = 1.0f / l_r[r];
#pragma unroll
  for (int nv = 0; nv < 8; nv++)
#pragma unroll
    for (int r = 0; r < 4; r++) {
      int t_row = qbase + wave * 16 + lk * 4 + r;
      o[((size_t)t_row * kH + h) * kVD + nv * 16 + lm] = f2bf(Oacc[nv][r] * invl[r]);
    }
}

// ---------------- norm / small kernels ----------------
__global__ __launch_bounds__(256) void k_add_rms(const float* __restrict__ h, const float* __restrict__ r,
                                                 const float* __restrict__ w, float* __restrict__ resid,
                                                 float* __restrict__ out, u16* __restrict__ oh,
                                                 u16* __restrict__ ol) {
  __shared__ float row[kD];
  __shared__ float red[4];
  int t = blockIdx.x;
  size_t base = (size_t)t * kD;
  float ss = 0.f;
  for (int c = threadIdx.x; c < kD; c += 256) {
    float v = h[base + c] + r[base + c];
    row[c] = v; resid[base + c] = v; ss += v * v;
  }
  float tot = bsum256(ss, red);
  float inv = 1.0f / sqrtf(tot * (1.0f / kD) + 1e-6f);
  for (int c = threadIdx.x; c < kD; c += 256) {
    float v = row[c] * inv * w[c];
    out[base + c] = v;
    u16 hb = f2bf(v);
    oh[base + c] = hb;
    ol[base + c] = f2bf(v - bf2f(hb));
  }
}

// rmsnorm with optional f32 / bf16-hi / bf16-lo outputs
__global__ __launch_bounds__(256) void k_rms_rows(const float* __restrict__ in, int stride, int off,
                                                  const float* __restrict__ w, float* __restrict__ outf,
                                                  u16* __restrict__ oh, u16* __restrict__ ol, int cols) {
  __shared__ float row[kD];
  __shared__ float red[4];
  int t = blockIdx.x;
  const float* x = in + (size_t)t * stride + off;
  float ss = 0.f;
  for (int c = threadIdx.x; c < cols; c += 256) { float v = x[c]; row[c] = v; ss += v * v; }
  float tot = bsum256(ss, red);
  float inv = 1.0f / sqrtf(tot / (float)cols + 1e-6f);
  for (int c = threadIdx.x; c < cols; c += 256) {
    float v = row[c] * inv * w[c];
    if (outf) outf[(size_t)t * cols + c] = v;
    if (oh) {
      u16 hb = f2bf(v);
      oh[(size_t)t * cols + c] = hb;
      if (ol) ol[(size_t)t * cols + c] = f2bf(v - bf2f(hb));
    }
  }
}

// fused iw = (hs @ w_idx_w) * iqsc * ID^-0.5 * IH^-0.5
__global__ __launch_bounds__(256) void k_iw_fused(const float* __restrict__ hs, const float* __restrict__ w,
                                                  const float* __restrict__ iqsc, float* __restrict__ out) {
  __shared__ float red[4][32];
  int t = blockIdx.x;
  int tid = threadIdx.x;
  int h = tid & 31, g = tid >> 5;
  const float* hrow = hs + (size_t)t * kD;
  float acc = 0.f;
#pragma unroll 4
  for (int d = g; d < kD; d += 8) acc += hrow[d] * w[(size_t)d * kIH + h];
  acc += __shfl_xor(acc, 32, 64);
  int wave = tid >> 6, lane = tid & 63;
  if (lane < 32) red[wave][lane] = acc;
  __syncthreads();
  if (tid < 32) {
    float v = red[0][tid] + red[1][tid] + red[2][tid] + red[3][tid];
    out[t * kIH + tid] = v * iqsc[t * kIH + tid] * 0.08838834764831845f * 0.17677669529663687f;
  }
}

__global__ __launch_bounds__(256) void k_rope_q(float* __restrict__ q, const int* __restrict__ pos) {
  int t = blockIdx.x;
  float p = (float)pos[t];
  for (int idx = threadIdx.x; idx < kH * 32; idx += 256) {
    int h = idx >> 5, j = idx & 31;
    float invf = 1.0f / powf(10000.0f, (float)j * 0.03125f);
    float ang = p * invf; float s, c; sincosf(ang, &s, &c);
    size_t base = ((size_t)t * kH + h) * kQKD + kNOPE + 2 * j;
    float x1 = q[base], x2 = q[base + 1];
    q[base] = x1 * c - x2 * s;
    q[base + 1] = x2 * c + x1 * s;
  }
}

__global__ __launch_bounds__(256) void k_rope_iq(float* __restrict__ iq, const int* __restrict__ pos) {
  int t = blockIdx.x;
  float p = (float)pos[t];
  for (int idx = threadIdx.x; idx < kIH * 32; idx += 256) {
    int h = idx >> 5, j = idx & 31;
    float invf = 1.0f / powf(10000.0f, (float)j * 0.03125f);
    float ang = p * invf; float s, c; sincosf(ang, &s, &c);
    size_t base = ((size_t)t * kIH + h) * kID + 2 * j;
    float x1 = iq[base], x2 = iq[base + 1];
    iq[base] = x1 * c - x2 * s;
    iq[base + 1] = x2 * c + x1 * s;
  }
}

__global__ __launch_bounds__(64) void k_rope_kpe(const float* __restrict__ qkv, int stride,
                                                 const int* __restrict__ pos, float* __restrict__ kpe) {
  int t = blockIdx.x; int j = threadIdx.x;
  if (j >= 32) return;
  float p = (float)pos[t];
  float invf = 1.0f / powf(10000.0f, (float)j * 0.03125f);
  float ang = p * invf; float s, c; sincosf(ang, &s, &c);
  const float* src = qkv + (size_t)t * stride + kQL + kKVL;
  float x1 = src[2 * j], x2 = src[2 * j + 1];
  kpe[(size_t)t * 64 + 2 * j] = x1 * c - x2 * s;
  kpe[(size_t)t * 64 + 2 * j + 1] = x2 * c + x1 * s;
}

// quantize rows of f32 [rows][kID] -> fp8-grid values stored as bf16 (exact), + pow2 scale
__global__ __launch_bounds__(64) void k_quant_rows(const float* __restrict__ x, u16* __restrict__ outq,
                                                   float* __restrict__ scales) {
  int row = blockIdx.x;
  const float* p = x + (size_t)row * kID;
  int l = threadIdx.x;
  float v0 = p[2 * l], v1 = p[2 * l + 1];
  float am = wmax64(fmaxf(fabsf(v0), fabsf(v1)));
  float scale = pow2ceil(fmaxf(am / 448.0f, 1e-10f));
  float inv = 1.0f / scale;
  float q0 = fp8q(fminf(fmaxf(v0 * inv, -448.f), 448.f));
  float q1 = fp8q(fminf(fmaxf(v1 * inv, -448.f), 448.f));
  ushort2 pk; pk.x = f2bf(q0); pk.y = f2bf(q1);
  *(ushort2*)&outq[(size_t)row * kID + 2 * l] = pk;
  if (l == 0) scales[row] = scale;
}

__global__ __launch_bounds__(64) void k_ik_process(const float* __restrict__ raw, int stride,
                                                   const float* __restrict__ w,
                                                   const float* __restrict__ b, const int* __restrict__ pos,
                                                   u16* __restrict__ outq, float* __restrict__ scales) {
  int t = blockIdx.x; int l = threadIdx.x;
  const float* x = raw + (size_t)t * stride;
  float x0 = x[2 * l], x1 = x[2 * l + 1];
  float mean = wsum(x0 + x1) * (1.0f / 128.0f);
  float d0 = x0 - mean, d1 = x1 - mean;
  float var = wsum(d0 * d0 + d1 * d1) * (1.0f / 128.0f);
  float inv = 1.0f / sqrtf(var + 1e-6f);
  float y0 = d0 * inv * w[2 * l] + b[2 * l];
  float y1 = d1 * inv * w[2 * l + 1] + b[2 * l + 1];
  if (l < 32) {
    float p = (float)pos[t];
    float invf = 1.0f / powf(10000.0f, (float)l * 0.03125f);
    float ang = p * invf; float sn, cs; sincosf(ang, &sn, &cs);
    float r0 = y0 * cs - y1 * sn, r1 = y1 * cs + y0 * sn;
    y0 = r0; y1 = r1;
  }
  float am = wmax64(fmaxf(fabsf(y0), fabsf(y1)));
  float scale = pow2ceil(fmaxf(am / 448.0f, 1e-10f));
  float is = 1.0f / scale;
  float q0 = fp8q(fminf(fmaxf(y0 * is, -448.f), 448.f));
  float q1 = fp8q(fminf(fmaxf(y1 * is, -448.f), 448.f));
  ushort2 pk; pk.x = f2bf(q0); pk.y = f2bf(q1);
  *(ushort2*)&outq[(size_t)t * kID + 2 * l] = pk;
  if (l == 0) scales[t] = scale;
}

// MFMA indexer scores: scores[t][s] = sum_h iw[t][h] * relu( (iq[t,h,:] . ik[s,:]) * iksc[s] )
__global__ __launch_bounds__(256) void k_scores_mfma(const u16* __restrict__ iq, const u16* __restrict__ ik,
                                                     const float* __restrict__ iksc, const float* __restrict__ iw,
                                                     float* __restrict__ scores) {
  int tb = blockIdx.y * 4;   // 4 tokens per block
  int bn = blockIdx.x * 128; // source base
  if (bn > tb + 3) return;   // entirely s > t
  __shared__ __align__(16) u16 As[128 * 32];
  __shared__ __align__(16) u16 Bs[128 * 32];
  int tid = threadIdx.x, wave = tid >> 6, lane = tid & 63;
  int wy = (wave >> 1) * 64, wx = (wave & 1) * 64;
  int lm = lane & 15, lk = lane >> 4;
  const u16* Ab = iq + (size_t)(tb * kIH) * kID;
  const u16* Bb = ik + (size_t)bn * kID;
  floatx4 acc[4][4] = {};
  for (int k0 = 0; k0 < kID; k0 += 32) {
    stage_tile(Ab + k0, kID, As, wave, lane);
    stage_tile(Bb + k0, kID, Bs, wave, lane);
    __syncthreads();
    short8 af[4], bfr[4];
#pragma unroll
    for (int mt = 0; mt < 4; mt++) af[mt] = *(short8*)&As[(wy + mt * 16 + lm) * 32 + lk * 8];
#pragma unroll
    for (int nt = 0; nt < 4; nt++) bfr[nt] = *(short8*)&Bs[(wx + nt * 16 + lm) * 32 + lk * 8];
#pragma unroll
    for (int mt = 0; mt < 4; mt++)
#pragma unroll
      for (int nt = 0; nt < 4; nt++)
        acc[mt][nt] = __builtin_amdgcn_mfma_f32_16x16x32_bf16(af[mt], bfr[nt], acc[mt][nt], 0, 0, 0);
    __syncthreads();
  }
  float scv[4];
#pragma unroll
  for (int nt = 0; nt < 4; nt++) scv[nt] = iksc[bn + wx + nt * 16 + lm];
  float iwv[4][4];
#pragma unroll
  for (int mt = 0; mt < 4; mt++)
#pragma unroll
    for (int r = 0; r < 4; r++)
      iwv[mt][r] = iw[(tb + (wy >> 5) + (mt >> 1)) * kIH + (mt & 1) * 16 + lk * 4 + r];
#pragma unroll
  for (int tp = 0; tp < 2; tp++) {
    int tglob = tb + (wy >> 5) + tp;
#pragma unroll
    for (int nt = 0; nt < 4; nt++) {
      float v = 0.f;
#pragma unroll
      for (int mh = 0; mh < 2; mh++) {
        int mt = tp * 2 + mh;
#pragma unroll
        for (int r = 0; r < 4; r++)
          v += fmaxf(acc[mt][nt][r] * scv[nt], 0.f) * iwv[mt][r];
      }
      v += __shfl_xor(v, 16, 64);
      v += __shfl_xor(v, 32, 64);
      if (lk == 0) scores[(size_t)tglob * kT + bn + wx + nt * 16 + lm] = v;
    }
  }
}

__global__ __launch_bounds__(64) void k_topk(const float* __restrict__ scores, unsigned long long* __restrict__ mbits) {
  int t = blockIdx.x; int l = threadIdx.x;
  __shared__ unsigned short tmp[64];
  unsigned long long* mrow = mbits + (size_t)t * 16;
  if (t < kTOPK) {
    if (l < 16) {
      int lo = l * 64, hi = lo + 63;
      unsigned long long bits;
      if (hi <= t) bits = ~0ull;
      else if (lo > t) bits = 0ull;
      else bits = (1ull << (t - lo + 1)) - 1ull;
      mrow[l] = bits;
    }
    return;
  }
  unsigned key[16];
  const float* srow = scores + (size_t)t * kT;
#pragma unroll
  for (int i = 0; i < 16; i++) {
    int s = l * 16 + i;
    key[i] = (s <= t) ? sortkey(srow[s]) : 0u;
  }
  unsigned prefix = 0; int remaining = kTOPK;
  for (int bit = 31; bit >= 0; bit--) {
    unsigned himask = 0xFFFFFFFFu << bit;
    unsigned cmp = prefix | (1u << bit);
    int c = 0;
#pragma unroll
    for (int i = 0; i < 16; i++) c += ((key[i] & himask) == cmp) ? 1 : 0;
    c = wsum_i(c);
    if (c >= remaining) prefix = cmp; else remaining -= c;
  }
  int ceq = 0, cgt = 0;
#pragma unroll
  for (int i = 0; i < 16; i++) { ceq += (key[i] == prefix) ? 1 : 0; cgt += (key[i] > prefix) ? 1 : 0; }
  int v = ceq;
#pragma unroll
  for (int o = 1; o < 64; o <<= 1) { int u = __shfl_up(v, o, 64); if (l >= o) v += u; }
  int rank = v - ceq;
  int need = kTOPK - wsum_i(cgt);
  unsigned short mybits = 0;
#pragma unroll
  for (int i = 0; i < 16; i++) {
    int sel;
    if (key[i] > prefix) sel = 1;
    else if (key[i] == prefix) { sel = (rank < need) ? 1 : 0; rank++; }
    else sel = 0;
    mybits |= (unsigned short)(sel << i);
  }
  tmp[l] = mybits;
  __syncthreads();
  if (l < 16) {
    mrow[l] = (unsigned long long)tmp[4 * l] | ((unsigned long long)tmp[4 * l + 1] << 16) |
              ((unsigned long long)tmp[4 * l + 2] << 32) | ((unsigned long long)tmp[4 * l + 3] << 48);
  }
}

__global__ __launch_bounds__(64) void k_route(const float* __restrict__ hs2, const float* __restrict__ wg,
                                              int* __restrict__ cnt, int* __restrict__ toki,
                                              float* __restrict__ tokw) {
  int t = blockIdx.x; int l = threadIdx.x;
  float acc[8] = {};
  for (int d = l; d < kD; d += 64) {
    float hv = hs2[(size_t)t * kD + d];
    const float* wr = wg + (size_t)d * 8;
#pragma unroll
    for (int e = 0; e < 8; e++) acc[e] += hv * wr[e];
  }
#pragma unroll
  for (int e = 0; e < 8; e++) acc[e] = wsum(acc[e]);
  if (l == 0) {
    float g[8];
#pragma unroll
    for (int e = 0; e < 8; e++) g[e] = 1.0f / (1.0f + expf(-acc[e]));
    int i0 = 0;
    for (int e = 1; e < 8; e++) if (g[e] > g[i0]) i0 = e;
    int i1 = (i0 == 0) ? 1 : 0;
    for (int e = 0; e < 8; e++) if (e != i0 && g[e] > g[i1]) i1 = e;
    float ssum = g[i0] + g[i1];
    float w0 = g[i0] / ssum * 2.5f, w1 = g[i1] / ssum * 2.5f;
    int s0 = atomicAdd(&cnt[i0], 1); toki[i0 * kT + s0] = t; tokw[i0 * kT + s0] = w0;
    int s1 = atomicAdd(&cnt[i1], 1); toki[i1 * kT + s1] = t; tokw[i1 * kT + s1] = w1;
  }
}

// ---------------- launch ----------------
extern "C" void kernel_launch(void* const* d_in, const int* in_sizes, int n_in,
                              void* d_out, int out_size, void* d_ws, size_t ws_size,
                              hipStream_t stream) {
  (void)in_sizes; (void)n_in; (void)out_size; (void)ws_size;
  const int*   positions  = (const int*)d_in[0];
  const float* hidden     = (const float*)d_in[1];
  const float* residual   = (const float*)d_in[2];
  const float* input_ln_w = (const float*)d_in[3];
  const float* post_ln_w  = (const float*)d_in[4];
  const float* w_qkv_a    = (const float*)d_in[5];
  const float* q_a_ln_w   = (const float*)d_in[6];
  const float* w_q_b      = (const float*)d_in[7];
  const float* kv_a_ln_w  = (const float*)d_in[8];
  const float* w_kv_b     = (const float*)d_in[9];
  const float* w_o        = (const float*)d_in[10];
  const float* w_idx_q_b  = (const float*)d_in[11];
  const float* w_idx_k    = (const float*)d_in[12];
  const float* idx_k_ln_w = (const float*)d_in[13];
  const float* idx_k_ln_b = (const float*)d_in[14];
  const float* w_idx_w    = (const float*)d_in[15];
  const float* w_gate     = (const float*)d_in[16];
  const float* w_moe_gate = (const float*)d_in[17];
  const float* w_moe_up   = (const float*)d_in[18];
  const float* w_moe_down = (const float*)d_in[19];
  const float* w_sh_gate  = (const float*)d_in[20];
  const float* w_sh_up    = (const float*)d_in[21];
  const float* w_sh_down  = (const float*)d_in[22];

  float* out0 = (float*)d_out;
  float* out1 = out0 + (size_t)kT * kD;

  char* W = (char*)d_ws;
  size_t off = 0;
  auto alloc = [&](size_t bytes) { char* p = W + off; off += (bytes + 255) & ~(size_t)255; return p; };
  // f32 buffers
  float* resid   = (float*)alloc((size_t)kT * kD * 4);
  float* hs      = (float*)alloc((size_t)kT * kD * 4);
  float* qkvF    = (float*)alloc((size_t)kT * kQKV_F * 4);
  float* qb      = (float*)alloc((size_t)kT * kH * kQKD * 4);
  float* kvb     = (float*)alloc((size_t)kT * kH * 256 * 4);
  float* iqb     = (float*)alloc((size_t)kT * kIH * kID * 4);
  float* iksc    = (float*)alloc(kT * 4);
  float* iqsc    = (float*)alloc((size_t)kT * kIH * 4);
  float* iwb     = (float*)alloc((size_t)kT * kIH * 4);
  float* kpe     = (float*)alloc((size_t)kT * kROPE * 4);
  float* scoresb = (float*)alloc((size_t)kT * kT * 4);
  float* hs2     = (float*)alloc((size_t)kT * kD * 4);
  unsigned long long* mbits = (unsigned long long*)alloc((size_t)kT * 16 * 8);
  float* tokw    = (float*)alloc((size_t)kE * kT * 4);
  int*   toki    = (int*)alloc((size_t)kE * kT * 4);
  int*   cnt     = (int*)alloc(64);
  // split-K partial buffer ALIASED onto kvb+iqb (33.5 MB contiguous, both 256-aligned sizes).
  // Safe: qkvP is fully consumed by k_reduce4 before kvb/iqb are first written (same stream).
  float* qkvP    = kvb; // needs 4*kT*kQKV_F*4 = 25.2 MB <= 33.5 MB
  // bf16 activations
  u16* hs_h   = (u16*)alloc((size_t)kT * kD * 2);
  u16* hs_l   = (u16*)alloc((size_t)kT * kD * 2);
  u16* qc_h   = (u16*)alloc((size_t)kT * kQL * 2);
  u16* qc_l   = (u16*)alloc((size_t)kT * kQL * 2);
  u16* kvc_h  = (u16*)alloc((size_t)kT * kKVL * 2);
  u16* o_bf   = (u16*)alloc((size_t)kT * kH * kVD * 2);
  u16* hs2_h  = (u16*)alloc((size_t)kT * kD * 2);
  u16* sg_bf  = (u16*)alloc((size_t)kT * kF * 2);
  u16* hmid_bf= (u16*)alloc((size_t)kE * kT * kF * 2);
  u16* iq_bf  = (u16*)alloc((size_t)kT * kIH * kID * 2);
  u16* ik_bf  = (u16*)alloc((size_t)kT * kID * 2);
  // bf16 transposed weights (qkv fused buffer holds qkv rows 0..1407 + ik rows 1408..1535)
  u16* qkvBT_h = (u16*)alloc((size_t)kQKV_F * kD * 2);
  u16* qkvBT_l = (u16*)alloc((size_t)kQKV_F * kD * 2);
  u16* qbBT    = (u16*)alloc((size_t)kH * kQKD * kQL * 2);
  u16* kvbBT   = (u16*)alloc((size_t)kH * 256 * kKVL * 2);
  u16* woBT    = (u16*)alloc((size_t)kD * kH * kVD * 2);
  u16* iqBT_h  = (u16*)alloc((size_t)kIH * kID * kQL * 2);
  u16* iqBT_l  = (u16*)alloc((size_t)kIH * kID * kQL * 2);
  u16* shgBT   = (u16*)alloc((size_t)kF * kD * 2);
  u16* shuBT   = (u16*)alloc((size_t)kF * kD * 2);
  u16* shdBT   = (u16*)alloc((size_t)kD * kF * 2);
  u16* moegBT  = (u16*)alloc((size_t)kE * kF * kD * 2);
  u16* moeuBT  = (u16*)alloc((size_t)kE * kF * kD * 2);
  u16* moedBT  = (u16*)alloc((size_t)kE * kD * kF * 2);

  // ---- weight prep (runs every launch; inputs are constant) ----
  { dim3 g(kQKV_NP / 32, kD / 32); k_transpose_w<<<g, 256, 0, stream>>>(w_qkv_a, qkvBT_h, qkvBT_l, kD, kQKV_N, kQKV_NP); }
  { dim3 g(kID / 32, kD / 32); k_transpose_w<<<g, 256, 0, stream>>>(w_idx_k, qkvBT_h + (size_t)kIKOFF * kD, qkvBT_l + (size_t)kIKOFF * kD, kD, kID, kID); }
  { dim3 g(kH * kQKD / 32, kQL / 32); k_transpose_w<<<g, 256, 0, stream>>>(w_q_b, qbBT, nullptr, kQL, kH * kQKD, kH * kQKD); }
  { dim3 g(kH * 256 / 32, kKVL / 32); k_transpose_w<<<g, 256, 0, stream>>>(w_kv_b, kvbBT, nullptr, kKVL, kH * 256, kH * 256); }
  { dim3 g(kD / 32, kH * kVD / 32); k_transpose_w<<<g, 256, 0, stream>>>(w_o, woBT, nullptr, kH * kVD, kD, kD); }
  { dim3 g(kIH * kID / 32, kQL / 32); k_transpose_w<<<g, 256, 0, stream>>>(w_idx_q_b, iqBT_h, iqBT_l, kQL, kIH * kID, kIH * kID); }
  { dim3 g(kF / 32, kD / 32); k_transpose_w<<<g, 256, 0, stream>>>(w_sh_gate, shgBT, nullptr, kD, kF, kF); }
  { dim3 g(kF / 32, kD / 32); k_transpose_w<<<g, 256, 0, stream>>>(w_sh_up, shuBT, nullptr, kD, kF, kF); }
  { dim3 g(kD / 32, kF / 32); k_transpose_w<<<g, 256, 0, stream>>>(w_sh_down, shdBT, nullptr, kF, kD, kD); }
  { dim3 g(kF / 32, kD / 32, kE); k_transpose_w<<<g, 256, 0, stream>>>(w_moe_gate, moegBT, nullptr, kD, kF, kF); }
  { dim3 g(kF / 32, kD / 32, kE); k_transpose_w<<<g, 256, 0, stream>>>(w_moe_up, moeuBT, nullptr, kD, kF, kF); }
  { dim3 g(kD / 32, kF / 32, kE); k_transpose_w<<<g, 256, 0, stream>>>(w_moe_down, moedBT, nullptr, kF, kD, kD); }

  // ---- forward ----
  k_add_rms<<<kT, 256, 0, stream>>>(hidden, residual, input_ln_w, resid, hs, hs_h, hs_l);
  // fused qkv+ik GEMM, split-K x4 over K=2048; partials in qkvP (aliased), reduced into qkvF
  { dim3 g(kQKV_F / 128, kT / 128, 4); k_gemm_splitk<<<g, 256, 0, stream>>>(hs_h, hs_l, qkvBT_h, qkvBT_l, qkvP, kT, kQKV_F, kD, kD / 4); }
  { int n4 = kT * kQKV_F / 4; k_reduce4<<<(n4 + 255) / 256, 256, 0, stream>>>(qkvP, qkvF, n4); }
  k_rms_rows<<<kT, 256, 0, stream>>>(qkvF, kQKV_F, 0, q_a_ln_w, nullptr, qc_h, qc_l, kQL);
  k_rms_rows<<<kT, 256, 0, stream>>>(qkvF, kQKV_F, kQL, kv_a_ln_w, nullptr, kvc_h, nullptr, kKVL);
  { dim3 g(kH * kQKD / 128, kT / 128); k_gemm_bt<<<g, 256, 0, stream>>>(qc_h, qbBT, qb, nullptr, kT, kH * kQKD, kQL); }
  { dim3 g(kIH * kID / 128, kT / 128); k_gemm_split<<<g, 256, 0, stream>>>(qc_h, qc_l, iqBT_h, iqBT_l, iqb, kT, kIH * kID, kQL); }
  { dim3 g(kH * 256 / 128, kT / 128); k_gemm_bt<<<g, 256, 0, stream>>>(kvc_h, kvbBT, kvb, nullptr, kT, kH * 256, kKVL); }
  k_rope_q<<<kT, 256, 0, stream>>>(qb, positions);
  k_rope_iq<<<kT, 256, 0, stream>>>(iqb, positions);
  k_rope_kpe<<<kT, 64, 0, stream>>>(qkvF, kQKV_F, positions, kpe);
  k_quant_rows<<<kT * kIH, 64, 0, stream>>>(iqb, iq_bf, iqsc);
  k_ik_process<<<kT, 64, 0, stream>>>(qkvF + kIKOFF, kQKV_F, idx_k_ln_w, idx_k_ln_b, positions, ik_bf, iksc);
  k_iw_fused<<<kT, 256, 0, stream>>>(hs, w_idx_w, iqsc, iwb);
  { dim3 g(kT / 128, kT / 4); k_scores_mfma<<<g, 256, 0, stream>>>(iq_bf, ik_bf, iksc, iwb, scoresb); }
  k_topk<<<kT, 64, 0, stream>>>(scoresb, mbits);
  { dim3 g(kT / 64, kH); k_attn_mfma<<<g, 256, 0, stream>>>(qb, kvb, kpe, mbits, o_bf); }
  { dim3 g(kD / 128, kT / 128); k_gemm_bt<<<g, 256, 0, stream>>>(o_bf, woBT, out1, resid, kT, kD, kH * kVD); }
  k_rms_rows<<<kT, 256, 0, stream>>>(out1, kD, 0, post_ln_w, hs2, hs2_h, nullptr, kD);
  hipMemsetAsync(cnt, 0, 8 * sizeof(int), stream);
  k_route<<<kT, 64, 0, stream>>>(hs2, w_gate, cnt, toki, tokw);
  { dim3 g(kF / 128, kT / 128, 1); k_dual_bt<<<g, 256, 0, stream>>>(hs2_h, shgBT, shuBT, sg_bf, nullptr, nullptr, kT, kF, kD); }
  { dim3 g(kD / 128, kT / 128); k_gemm_bt<<<g, 256, 0, stream>>>(sg_bf, shdBT, out0, nullptr, kT, kD, kF); }
  { dim3 g(kF / 128, kT / 128, kE); k_dual_bt<<<g, 256, 0, stream>>>(hs2_h, moegBT, moeuBT, hmid_bf, toki, cnt, kT, kF, kD); }
  { dim3 g(kD / 128, kT / 128, kE); k_down_bt<<<g, 256, 0, stream>>>(hmid_bf, moedBT, toki, tokw, cnt, out0); }
}

// Round 5
// 951.105 us; speedup vs baseline: 1.5370x; 1.0570x over previous
//
#include <hip/hip_runtime.h>

namespace {
constexpr int kT = 1024, kD = 2048, kH = 16, kNOPE = 128, kROPE = 64, kVD = 128, kQKD = 192;
constexpr int kQL = 768, kKVL = 512, kIH = 32, kID = 128, kTOPK = 256, kE = 8, kF = 1024;
constexpr int kQKV_N = kQL + kKVL + kROPE; // 1344
constexpr int kQKV_NP = 1408;              // padded to 128
constexpr int kIKOFF = 1408;               // ik columns start here in fused buffer
constexpr int kQKV_F = 1536;               // fused qkv+ik padded width
}

typedef __attribute__((ext_vector_type(4))) float floatx4;
typedef __attribute__((ext_vector_type(8))) short short8;
typedef unsigned short u16;

// ---------------- device helpers ----------------
__device__ __forceinline__ float wsum(float v) {
#pragma unroll
  for (int o = 32; o; o >>= 1) v += __shfl_xor(v, o, 64);
  return v;
}
__device__ __forceinline__ float wmax64(float v) {
#pragma unroll
  for (int o = 32; o; o >>= 1) v = fmaxf(v, __shfl_xor(v, o, 64));
  return v;
}
__device__ __forceinline__ int wsum_i(int v) {
#pragma unroll
  for (int o = 32; o; o >>= 1) v += __shfl_xor(v, o, 64);
  return v;
}
__device__ __forceinline__ float bsum256(float v, float* red) {
  v = wsum(v);
  if ((threadIdx.x & 63) == 0) red[threadIdx.x >> 6] = v;
  __syncthreads();
  float t = red[0] + red[1] + red[2] + red[3];
  __syncthreads();
  return t;
}
__device__ __forceinline__ unsigned sortkey(float f) {
  unsigned b = __float_as_uint(f);
  return (b & 0x80000000u) ? ~b : (b | 0x80000000u);
}
__device__ __forceinline__ float pow2ceil(float z) {
  unsigned b = __float_as_uint(z);
  if ((b & 0x7FFFFFu) == 0) return z;
  return __uint_as_float((((b >> 23) & 0xFFu) + 1u) << 23);
}
__device__ __forceinline__ float fp8q(float x) {
  float ax = fabsf(x);
  float q;
  if (ax < 0.015625f) {
    q = rintf(ax * 512.0f) * 0.001953125f;
  } else {
    unsigned b = __float_as_uint(ax);
    int e = (int)((b >> 23) & 0xFF) - 127;
    float quant = __uint_as_float((unsigned)(e - 3 + 127) << 23);
    float rq    = __uint_as_float((unsigned)(127 - (e - 3)) << 23);
    q = rintf(ax * rq) * quant;
  }
  return copysignf(q, x);
}
__device__ __forceinline__ u16 f2bf(float x) {
  unsigned u = __float_as_uint(x);
  u += 0x7FFFu + ((u >> 16) & 1u);
  return (u16)(u >> 16);
}
__device__ __forceinline__ float bf2f(u16 h) { return __uint_as_float((unsigned)h << 16); }

// async global->LDS, 16B per lane; lds ptr must be wave-uniform (HW adds lane*16)
__device__ __forceinline__ void gld_lds16(const void* g, void* l) {
  __builtin_amdgcn_global_load_lds(
      (const __attribute__((address_space(1))) unsigned int*)(unsigned long long)g,
      (__attribute__((address_space(3))) unsigned int*)(unsigned int)(unsigned long long)l,
      16, 0, 0);
}
// stage 128 rows x 32 bf16 cols; wave stages rows [wave*32, wave*32+32)
__device__ __forceinline__ void stage_tile(const u16* g, size_t strideUs, u16* tile, int wave, int lane) {
  int r = lane >> 2, c = lane & 3;
  const u16* gp = g + (size_t)(wave * 32 + r) * strideUs + c * 8;
  gld_lds16(gp, tile + (wave * 32) * 32);
  gld_lds16(gp + (size_t)16 * strideUs, tile + (wave * 32 + 16) * 32);
}
// stage 64 rows x 32 bf16 cols; wave stages rows [wave*16, wave*16+16) in ONE gld
__device__ __forceinline__ void stage_tile64(const u16* g, size_t strideUs, u16* tile, int wave, int lane) {
  int r = lane >> 2, c = lane & 3;
  gld_lds16(g + (size_t)(wave * 16 + r) * strideUs + c * 8, tile + (wave * 16) * 32);
}

// ---------------- weight prep: f32 [K][N] -> bf16 BT [Npad][K] (+optional lo) ----------------
__global__ __launch_bounds__(256) void k_transpose_w(const float* __restrict__ in, u16* __restrict__ hi,
                                                     u16* __restrict__ lo, int K, int N, int Npad) {
  __shared__ float tile[32][33];
  int n0 = blockIdx.x * 32, k0 = blockIdx.y * 32;
  const float* ip = in + (size_t)blockIdx.z * K * N;
  u16* hp = hi + (size_t)blockIdx.z * Npad * K;
  u16* lp = lo ? lo + (size_t)blockIdx.z * Npad * K : nullptr;
  int t = threadIdx.x;
  int r = t >> 3, c4 = (t & 7) << 2;
  if (n0 < N) {
    float4 v = *(const float4*)&ip[(size_t)(k0 + r) * N + n0 + c4];
    tile[r][c4] = v.x; tile[r][c4 + 1] = v.y; tile[r][c4 + 2] = v.z; tile[r][c4 + 3] = v.w;
  } else {
    tile[r][c4] = 0.f; tile[r][c4 + 1] = 0.f; tile[r][c4 + 2] = 0.f; tile[r][c4 + 3] = 0.f;
  }
  __syncthreads();
  int n = t >> 3, kq = (t & 7) << 2;
  ushort4 h4, l4;
#pragma unroll
  for (int j = 0; j < 4; j++) {
    float f = tile[kq + j][n];
    u16 h = f2bf(f);
    ((u16*)&h4)[j] = h;
    ((u16*)&l4)[j] = f2bf(f - bf2f(h));
  }
  *(ushort4*)&hp[(size_t)(n0 + n) * K + k0 + kq] = h4;
  if (lp) *(ushort4*)&lp[(size_t)(n0 + n) * K + k0 + kq] = l4;
}

// ---------------- GEMM family: bf16 A [M][K], bf16 BT [N][K], global_load_lds staging ----------
// 128x128 tile, BK=32, 4 waves in 2x2 quadrants.

__global__ __launch_bounds__(256) void k_gemm_bt(const u16* __restrict__ A, const u16* __restrict__ BT,
                                                 float* __restrict__ C, const float* __restrict__ addend,
                                                 int M, int N, int K) {
  __shared__ __align__(16) u16 As[128 * 32];
  __shared__ __align__(16) u16 Bs[128 * 32];
  int tid = threadIdx.x, wave = tid >> 6, lane = tid & 63;
  int bm = blockIdx.y * 128, bn = blockIdx.x * 128;
  int wy = (wave >> 1) * 64, wx = (wave & 1) * 64;
  int lm = lane & 15, lk = lane >> 4;
  const u16* Ab = A + (size_t)bm * K;
  const u16* Bb = BT + (size_t)bn * K;
  floatx4 acc[4][4] = {};
  for (int k0 = 0; k0 < K; k0 += 32) {
    stage_tile(Ab + k0, K, As, wave, lane);
    stage_tile(Bb + k0, K, Bs, wave, lane);
    __syncthreads();
    short8 af[4], bfr[4];
#pragma unroll
    for (int mt = 0; mt < 4; mt++) af[mt] = *(short8*)&As[(wy + mt * 16 + lm) * 32 + lk * 8];
#pragma unroll
    for (int nt = 0; nt < 4; nt++) bfr[nt] = *(short8*)&Bs[(wx + nt * 16 + lm) * 32 + lk * 8];
#pragma unroll
    for (int mt = 0; mt < 4; mt++)
#pragma unroll
      for (int nt = 0; nt < 4; nt++)
        acc[mt][nt] = __builtin_amdgcn_mfma_f32_16x16x32_bf16(af[mt], bfr[nt], acc[mt][nt], 0, 0, 0);
    __syncthreads();
  }
#pragma unroll
  for (int mt = 0; mt < 4; mt++)
#pragma unroll
    for (int nt = 0; nt < 4; nt++)
#pragma unroll
      for (int r = 0; r < 4; r++) {
        int m = bm + wy + mt * 16 + lk * 4 + r;
        int n = bn + wx + nt * 16 + lm;
        float v = acc[mt][nt][r];
        if (addend) v += addend[(size_t)m * N + n];
        C[(size_t)m * N + n] = v;
      }
}

// 3-term split-precision GEMM: C = Ahi*Bhi + Ahi*Blo + Alo*Bhi (f32-class accuracy).
// N may be < padded BT rows; C guarded & strided by N.
__global__ __launch_bounds__(256) void k_gemm_split(const u16* __restrict__ Ah, const u16* __restrict__ Al,
                                                    const u16* __restrict__ Bh, const u16* __restrict__ Bl,
                                                    float* __restrict__ C, int M, int N, int K) {
  __shared__ __align__(16) u16 Ahs[128 * 32];
  __shared__ __align__(16) u16 Als[128 * 32];
  __shared__ __align__(16) u16 Bhs[128 * 32];
  __shared__ __align__(16) u16 Bls[128 * 32];
  int tid = threadIdx.x, wave = tid >> 6, lane = tid & 63;
  int bm = blockIdx.y * 128, bn = blockIdx.x * 128;
  int wy = (wave >> 1) * 64, wx = (wave & 1) * 64;
  int lm = lane & 15, lk = lane >> 4;
  floatx4 acc[4][4] = {};
  for (int k0 = 0; k0 < K; k0 += 32) {
    stage_tile(Ah + (size_t)bm * K + k0, K, Ahs, wave, lane);
    stage_tile(Al + (size_t)bm * K + k0, K, Als, wave, lane);
    stage_tile(Bh + (size_t)bn * K + k0, K, Bhs, wave, lane);
    stage_tile(Bl + (size_t)bn * K + k0, K, Bls, wave, lane);
    __syncthreads();
    short8 ah[4], al[4], bh[4], bl[4];
#pragma unroll
    for (int mt = 0; mt < 4; mt++) { ah[mt] = *(short8*)&Ahs[(wy + mt * 16 + lm) * 32 + lk * 8];
                                     al[mt] = *(short8*)&Als[(wy + mt * 16 + lm) * 32 + lk * 8]; }
#pragma unroll
    for (int nt = 0; nt < 4; nt++) { bh[nt] = *(short8*)&Bhs[(wx + nt * 16 + lm) * 32 + lk * 8];
                                     bl[nt] = *(short8*)&Bls[(wx + nt * 16 + lm) * 32 + lk * 8]; }
#pragma unroll
    for (int mt = 0; mt < 4; mt++)
#pragma unroll
      for (int nt = 0; nt < 4; nt++) {
        floatx4 a = acc[mt][nt];
        a = __builtin_amdgcn_mfma_f32_16x16x32_bf16(al[mt], bh[nt], a, 0, 0, 0);
        a = __builtin_amdgcn_mfma_f32_16x16x32_bf16(ah[mt], bl[nt], a, 0, 0, 0);
        a = __builtin_amdgcn_mfma_f32_16x16x32_bf16(ah[mt], bh[nt], a, 0, 0, 0);
        acc[mt][nt] = a;
      }
    __syncthreads();
  }
#pragma unroll
  for (int mt = 0; mt < 4; mt++)
#pragma unroll
    for (int nt = 0; nt < 4; nt++)
#pragma unroll
      for (int r = 0; r < 4; r++) {
        int m = bm + wy + mt * 16 + lk * 4 + r;
        int n = bn + wx + nt * 16 + lm;
        if (n < N) C[(size_t)m * N + n] = acc[mt][nt][r];
      }
}

// split-K 3-term GEMM: partial C per kz chunk, unguarded padded-N writes.
// Cp layout: [KSPLIT][M][Npad] f32.
__global__ __launch_bounds__(256) void k_gemm_splitk(const u16* __restrict__ Ah, const u16* __restrict__ Al,
                                                     const u16* __restrict__ Bh, const u16* __restrict__ Bl,
                                                     float* __restrict__ Cp, int M, int Npad, int K, int kchunk) {
  __shared__ __align__(16) u16 Ahs[128 * 32];
  __shared__ __align__(16) u16 Als[128 * 32];
  __shared__ __align__(16) u16 Bhs[128 * 32];
  __shared__ __align__(16) u16 Bls[128 * 32];
  int tid = threadIdx.x, wave = tid >> 6, lane = tid & 63;
  int bm = blockIdx.y * 128, bn = blockIdx.x * 128;
  int kz = blockIdx.z;
  int kbeg = kz * kchunk, kend = kbeg + kchunk;
  int wy = (wave >> 1) * 64, wx = (wave & 1) * 64;
  int lm = lane & 15, lk = lane >> 4;
  floatx4 acc[4][4] = {};
  for (int k0 = kbeg; k0 < kend; k0 += 32) {
    stage_tile(Ah + (size_t)bm * K + k0, K, Ahs, wave, lane);
    stage_tile(Al + (size_t)bm * K + k0, K, Als, wave, lane);
    stage_tile(Bh + (size_t)bn * K + k0, K, Bhs, wave, lane);
    stage_tile(Bl + (size_t)bn * K + k0, K, Bls, wave, lane);
    __syncthreads();
    short8 ah[4], al[4], bh[4], bl[4];
#pragma unroll
    for (int mt = 0; mt < 4; mt++) { ah[mt] = *(short8*)&Ahs[(wy + mt * 16 + lm) * 32 + lk * 8];
                                     al[mt] = *(short8*)&Als[(wy + mt * 16 + lm) * 32 + lk * 8]; }
#pragma unroll
    for (int nt = 0; nt < 4; nt++) { bh[nt] = *(short8*)&Bhs[(wx + nt * 16 + lm) * 32 + lk * 8];
                                     bl[nt] = *(short8*)&Bls[(wx + nt * 16 + lm) * 32 + lk * 8]; }
#pragma unroll
    for (int mt = 0; mt < 4; mt++)
#pragma unroll
      for (int nt = 0; nt < 4; nt++) {
        floatx4 a = acc[mt][nt];
        a = __builtin_amdgcn_mfma_f32_16x16x32_bf16(al[mt], bh[nt], a, 0, 0, 0);
        a = __builtin_amdgcn_mfma_f32_16x16x32_bf16(ah[mt], bl[nt], a, 0, 0, 0);
        a = __builtin_amdgcn_mfma_f32_16x16x32_bf16(ah[mt], bh[nt], a, 0, 0, 0);
        acc[mt][nt] = a;
      }
    __syncthreads();
  }
  float* Co = Cp + (size_t)kz * M * Npad;
#pragma unroll
  for (int mt = 0; mt < 4; mt++)
#pragma unroll
    for (int nt = 0; nt < 4; nt++)
#pragma unroll
      for (int r = 0; r < 4; r++) {
        int m = bm + wy + mt * 16 + lk * 4 + r;
        int n = bn + wx + nt * 16 + lm;
        Co[(size_t)m * Npad + n] = acc[mt][nt][r];
      }
}

// sum 4 partials: C[i] = sum_z Cp[z][i], vectorized float4
__global__ __launch_bounds__(256) void k_reduce4(const float* __restrict__ Cp, float* __restrict__ C, int n4) {
  int i = blockIdx.x * 256 + threadIdx.x;
  if (i >= n4) return;
  const floatx4* p = (const floatx4*)Cp;
  floatx4 v = p[i] + p[i + n4] + p[i + 2 * n4] + p[i + 3 * n4];
  ((floatx4*)C)[i] = v;
}

// dual-B gate+up with silu epilogue -> bf16 out; 64x64 tile (4 waves, 2x2 quadrants of 32x32).
// optional row gather (MoE), z = expert. 3 gld_lds per wave per K-step.
__global__ __launch_bounds__(256) void k_dual_bt64(const u16* __restrict__ A, const u16* __restrict__ GT,
                                                   const u16* __restrict__ UT, u16* __restrict__ out,
                                                   const int* __restrict__ toki, const int* __restrict__ cnt,
                                                   int M, int N, int K) {
  int e = blockIdx.z;
  int n_rows = toki ? cnt[e] : M;
  int bm = blockIdx.y * 64;
  if (bm >= n_rows) return;
  int bn = blockIdx.x * 64;
  const int* tk = toki ? (toki + e * kT) : nullptr;
  const u16* Gb = GT + (size_t)e * N * K + (size_t)bn * K;
  const u16* Ub = UT + (size_t)e * N * K + (size_t)bn * K;
  u16* oP = out + (size_t)e * kT * N;
  __shared__ __align__(16) u16 As[64 * 32];
  __shared__ __align__(16) u16 Gs[64 * 32];
  __shared__ __align__(16) u16 Us[64 * 32];
  int tid = threadIdx.x, wave = tid >> 6, lane = tid & 63;
  int wy = (wave >> 1) * 32, wx = (wave & 1) * 32;
  int lm = lane & 15, lk = lane >> 4;
  int r = lane >> 2, c = lane & 3;
  int r0 = bm + wave * 16 + r;
  size_t arow = tk ? (size_t)((r0 < n_rows) ? tk[r0] : 0) : (size_t)r0;
  floatx4 ag[2][2] = {}, au[2][2] = {};
  for (int k0 = 0; k0 < K; k0 += 32) {
    gld_lds16(A + arow * K + k0 + c * 8, As + (wave * 16) * 32);
    stage_tile64(Gb + k0, K, Gs, wave, lane);
    stage_tile64(Ub + k0, K, Us, wave, lane);
    __syncthreads();
    short8 af[2], gf[2], uf[2];
#pragma unroll
    for (int mt = 0; mt < 2; mt++) af[mt] = *(short8*)&As[(wy + mt * 16 + lm) * 32 + lk * 8];
#pragma unroll
    for (int nt = 0; nt < 2; nt++) { gf[nt] = *(short8*)&Gs[(wx + nt * 16 + lm) * 32 + lk * 8];
                                     uf[nt] = *(short8*)&Us[(wx + nt * 16 + lm) * 32 + lk * 8]; }
#pragma unroll
    for (int mt = 0; mt < 2; mt++)
#pragma unroll
      for (int nt = 0; nt < 2; nt++) {
        ag[mt][nt] = __builtin_amdgcn_mfma_f32_16x16x32_bf16(af[mt], gf[nt], ag[mt][nt], 0, 0, 0);
        au[mt][nt] = __builtin_amdgcn_mfma_f32_16x16x32_bf16(af[mt], uf[nt], au[mt][nt], 0, 0, 0);
      }
    __syncthreads();
  }
#pragma unroll
  for (int mt = 0; mt < 2; mt++)
#pragma unroll
    for (int nt = 0; nt < 2; nt++)
#pragma unroll
      for (int r2 = 0; r2 < 4; r2++) {
        int gm = bm + wy + mt * 16 + lk * 4 + r2;
        if (gm >= n_rows) continue;
        int n = bn + wx + nt * 16 + lm;
        float gv = ag[mt][nt][r2], uv = au[mt][nt][r2];
        oP[(size_t)gm * N + n] = f2bf(gv * (1.0f / (1.0f + expf(-gv))) * uv);
      }
}

// down: out[tok] += w * (hmid[e] @ wd[e]); 64x128 tile; atomic scatter f32
__global__ __launch_bounds__(256) void k_down_bt64(const u16* __restrict__ hmid, const u16* __restrict__ DT,
                                                   const int* __restrict__ toki, const float* __restrict__ tokw,
                                                   const int* __restrict__ cnt, float* __restrict__ out) {
  int e = blockIdx.z;
  int n_rows = cnt[e];
  int bm = blockIdx.y * 64;
  if (bm >= n_rows) return;
  int bn = blockIdx.x * 128;
  const u16* Ab = hmid + (size_t)e * kT * kF + (size_t)bm * kF;
  const u16* Bb = DT + (size_t)e * kD * kF + (size_t)bn * kF;
  __shared__ __align__(16) u16 As[64 * 32];
  __shared__ __align__(16) u16 Bs[128 * 32];
  int tid = threadIdx.x, wave = tid >> 6, lane = tid & 63;
  int wy = (wave >> 1) * 32, wx = (wave & 1) * 64;
  int lm = lane & 15, lk = lane >> 4;
  floatx4 acc[2][4] = {};
  for (int k0 = 0; k0 < kF; k0 += 32) {
    stage_tile64(Ab + k0, kF, As, wave, lane);
    stage_tile(Bb + k0, kF, Bs, wave, lane);
    __syncthreads();
    short8 af[2], bfr[4];
#pragma unroll
    for (int mt = 0; mt < 2; mt++) af[mt] = *(short8*)&As[(wy + mt * 16 + lm) * 32 + lk * 8];
#pragma unroll
    for (int nt = 0; nt < 4; nt++) bfr[nt] = *(short8*)&Bs[(wx + nt * 16 + lm) * 32 + lk * 8];
#pragma unroll
    for (int mt = 0; mt < 2; mt++)
#pragma unroll
      for (int nt = 0; nt < 4; nt++)
        acc[mt][nt] = __builtin_amdgcn_mfma_f32_16x16x32_bf16(af[mt], bfr[nt], acc[mt][nt], 0, 0, 0);
    __syncthreads();
  }
#pragma unroll
  for (int mt = 0; mt < 2; mt++)
#pragma unroll
    for (int r = 0; r < 4; r++) {
      int gm = bm + wy + mt * 16 + lk * 4 + r;
      if (gm >= n_rows) continue;
      int tt = toki[e * kT + gm];
      float w = tokw[e * kT + gm];
#pragma unroll
      for (int nt = 0; nt < 4; nt++) {
        int n = bn + wx + nt * 16 + lm;
        atomicAdd(&out[(size_t)tt * kD + n], w * acc[mt][nt][r]);
      }
    }
}

// ---------------- flash MFMA attention (bf16 out) ----------------
__global__ __launch_bounds__(256) void k_attn_mfma(const float* __restrict__ q, const float* __restrict__ kv,
                                                   const float* __restrict__ kpe,
                                                   const unsigned long long* __restrict__ mbits,
                                                   u16* __restrict__ o) {
  __shared__ __align__(16) u16 Ks[64 * 200];
  __shared__ __align__(16) u16 Vs[128 * 72];
  __shared__ __align__(16) u16 Ps[4 * 16 * 72];
  int h = blockIdx.y;
  int qb = gridDim.x - 1 - blockIdx.x;
  int qbase = qb * 64;
  int tid = threadIdx.x;
  int wave = tid >> 6, lane = tid & 63;
  int lm = lane & 15, lk = lane >> 4;
  short8 qf[6];
  {
    const float* qrow = q + ((size_t)(qbase + wave * 16 + lm) * kH + h) * kQKD;
#pragma unroll
    for (int ks = 0; ks < 6; ks++) {
      const float4 a0 = *(const float4*)&qrow[ks * 32 + lk * 8];
      const float4 a1 = *(const float4*)&qrow[ks * 32 + lk * 8 + 4];
      short8 f;
      f[0] = (short)f2bf(a0.x); f[1] = (short)f2bf(a0.y); f[2] = (short)f2bf(a0.z); f[3] = (short)f2bf(a0.w);
      f[4] = (short)f2bf(a1.x); f[5] = (short)f2bf(a1.y); f[6] = (short)f2bf(a1.z); f[7] = (short)f2bf(a1.w);
      qf[ks] = f;
    }
  }
  float m_r[4] = {-1e30f, -1e30f, -1e30f, -1e30f};
  float l_r[4] = {};
  floatx4 Oacc[8] = {};
  int sr = tid >> 2, sj = tid & 3;
  int nch = qb + 1;
  for (int ch = 0; ch < nch; ch++) {
    int s0 = ch << 6;
    __syncthreads();
    {
      const float* kvrow = kv + ((size_t)(s0 + sr) * kH + h) * 256;
      const float* kprow = kpe + (size_t)(s0 + sr) * 64;
#pragma unroll
      for (int i = 0; i < 12; i++) {
        int c4 = (i << 2) + sj;
        float4 v4 = (c4 < 32) ? *(const float4*)&kvrow[c4 * 4] : *(const float4*)&kprow[(c4 - 32) * 4];
        ushort4 p; p.x = f2bf(v4.x); p.y = f2bf(v4.y); p.z = f2bf(v4.z); p.w = f2bf(v4.w);
        *(ushort4*)&Ks[sr * 200 + c4 * 4] = p;
      }
      const float* vrow = kvrow + 128;
#pragma unroll
      for (int i = 0; i < 8; i++) {
        int c4 = (i << 2) + sj;
        float4 v4 = *(const float4*)&vrow[c4 * 4];
        Vs[(c4 * 4 + 0) * 72 + sr] = f2bf(v4.x);
        Vs[(c4 * 4 + 1) * 72 + sr] = f2bf(v4.y);
        Vs[(c4 * 4 + 2) * 72 + sr] = f2bf(v4.z);
        Vs[(c4 * 4 + 3) * 72 + sr] = f2bf(v4.w);
      }
    }
    __syncthreads();
    floatx4 sacc[4] = {};
#pragma unroll
    for (int ks = 0; ks < 6; ks++) {
      short8 kf[4];
#pragma unroll
      for (int nt = 0; nt < 4; nt++) kf[nt] = *(short8*)&Ks[(nt * 16 + lm) * 200 + ks * 32 + lk * 8];
#pragma unroll
      for (int nt = 0; nt < 4; nt++)
        sacc[nt] = __builtin_amdgcn_mfma_f32_16x16x32_bf16(qf[ks], kf[nt], sacc[nt], 0, 0, 0);
    }
    unsigned long long mw[4];
#pragma unroll
    for (int r = 0; r < 4; r++) mw[r] = mbits[(size_t)(qbase + wave * 16 + lk * 4 + r) * 16 + ch];
    float mx[4] = {-1e30f, -1e30f, -1e30f, -1e30f};
#pragma unroll
    for (int nt = 0; nt < 4; nt++)
#pragma unroll
      for (int r = 0; r < 4; r++) {
        int sel = (int)((mw[r] >> (nt * 16 + lm)) & 1ull);
        float sv = sel ? sacc[nt][r] * 0.07216878364870323f : -1e30f;
        sacc[nt][r] = sv;
        mx[r] = fmaxf(mx[r], sv);
      }
#pragma unroll
    for (int off = 1; off < 16; off <<= 1)
#pragma unroll
      for (int r = 0; r < 4; r++) mx[r] = fmaxf(mx[r], __shfl_xor(mx[r], off, 64));
    float al[4], psum[4] = {};
#pragma unroll
    for (int r = 0; r < 4; r++) {
      float mnew = fmaxf(m_r[r], mx[r]);
      al[r] = __expf(m_r[r] - mnew);
      m_r[r] = mnew;
    }
#pragma unroll
    for (int nt = 0; nt < 4; nt++)
#pragma unroll
      for (int r = 0; r < 4; r++) {
        float p = (sacc[nt][r] > -0.9e30f) ? __expf(sacc[nt][r] - m_r[r]) : 0.0f;
        psum[r] += p;
        Ps[wave * 1152 + (lk * 4 + r) * 72 + nt * 16 + lm] = f2bf(p);
      }
#pragma unroll
    for (int off = 1; off < 16; off <<= 1)
#pragma unroll
      for (int r = 0; r < 4; r++) psum[r] += __shfl_xor(psum[r], off, 64);
#pragma unroll
    for (int r = 0; r < 4; r++) l_r[r] = l_r[r] * al[r] + psum[r];
#pragma unroll
    for (int nv = 0; nv < 8; nv++)
#pragma unroll
      for (int r = 0; r < 4; r++) Oacc[nv][r] *= al[r];
    short8 pf[2];
#pragma unroll
    for (int k2 = 0; k2 < 2; k2++) pf[k2] = *(short8*)&Ps[wave * 1152 + lm * 72 + k2 * 32 + lk * 8];
#pragma unroll
    for (int k2 = 0; k2 < 2; k2++)
#pragma unroll
      for (int nv = 0; nv < 8; nv++) {
        short8 vf = *(short8*)&Vs[(nv * 16 + lm) * 72 + k2 * 32 + lk * 8];
        Oacc[nv] = __builtin_amdgcn_mfma_f32_16x16x32_bf16(pf[k2], vf, Oacc[nv], 0, 0, 0);
      }
  }
  float invl[4];
#pragma unroll
  for (int r = 0; r < 4; r++) invl[r] = 1.0f / l_r[r];
#pragma unroll
  for (int nv = 0; nv < 8; nv++)
#pragma unroll
    for (int r = 0; r < 4; r++) {
      int t_row = qbase + wave * 16 + lk * 4 + r;
      o[((size_t)t_row * kH + h) * kVD + nv * 16 + lm] = f2bf(Oacc[nv][r] * invl[r]);
    }
}

// ---------------- norm / small kernels ----------------
__global__ __launch_bounds__(256) void k_add_rms(const float* __restrict__ h, const float* __restrict__ r,
                                                 const float* __restrict__ w, float* __restrict__ resid,
                                                 float* __restrict__ out, u16* __restrict__ oh,
                                                 u16* __restrict__ ol) {
  __shared__ float row[kD];
  __shared__ float red[4];
  int t = blockIdx.x;
  size_t base = (size_t)t * kD;
  float ss = 0.f;
  for (int c = threadIdx.x; c < kD; c += 256) {
    float v = h[base + c] + r[base + c];
    row[c] = v; resid[base + c] = v; ss += v * v;
  }
  float tot = bsum256(ss, red);
  float inv = 1.0f / sqrtf(tot * (1.0f / kD) + 1e-6f);
  for (int c = threadIdx.x; c < kD; c += 256) {
    float v = row[c] * inv * w[c];
    out[base + c] = v;
    u16 hb = f2bf(v);
    oh[base + c] = hb;
    ol[base + c] = f2bf(v - bf2f(hb));
  }
}

// rmsnorm with optional f32 / bf16-hi / bf16-lo outputs
__global__ __launch_bounds__(256) void k_rms_rows(const float* __restrict__ in, int stride, int off,
                                                  const float* __restrict__ w, float* __restrict__ outf,
                                                  u16* __restrict__ oh, u16* __restrict__ ol, int cols) {
  __shared__ float row[kD];
  __shared__ float red[4];
  int t = blockIdx.x;
  const float* x = in + (size_t)t * stride + off;
  float ss = 0.f;
  for (int c = threadIdx.x; c < cols; c += 256) { float v = x[c]; row[c] = v; ss += v * v; }
  float tot = bsum256(ss, red);
  float inv = 1.0f / sqrtf(tot / (float)cols + 1e-6f);
  for (int c = threadIdx.x; c < cols; c += 256) {
    float v = row[c] * inv * w[c];
    if (outf) outf[(size_t)t * cols + c] = v;
    if (oh) {
      u16 hb = f2bf(v);
      oh[(size_t)t * cols + c] = hb;
      if (ol) ol[(size_t)t * cols + c] = f2bf(v - bf2f(hb));
    }
  }
}

// fused iw = (hs @ w_idx_w) * iqsc * ID^-0.5 * IH^-0.5
__global__ __launch_bounds__(256) void k_iw_fused(const float* __restrict__ hs, const float* __restrict__ w,
                                                  const float* __restrict__ iqsc, float* __restrict__ out) {
  __shared__ float red[4][32];
  int t = blockIdx.x;
  int tid = threadIdx.x;
  int h = tid & 31, g = tid >> 5;
  const float* hrow = hs + (size_t)t * kD;
  float acc = 0.f;
#pragma unroll 4
  for (int d = g; d < kD; d += 8) acc += hrow[d] * w[(size_t)d * kIH + h];
  acc += __shfl_xor(acc, 32, 64);
  int wave = tid >> 6, lane = tid & 63;
  if (lane < 32) red[wave][lane] = acc;
  __syncthreads();
  if (tid < 32) {
    float v = red[0][tid] + red[1][tid] + red[2][tid] + red[3][tid];
    out[t * kIH + tid] = v * iqsc[t * kIH + tid] * 0.08838834764831845f * 0.17677669529663687f;
  }
}

__global__ __launch_bounds__(256) void k_rope_q(float* __restrict__ q, const int* __restrict__ pos) {
  int t = blockIdx.x;
  float p = (float)pos[t];
  for (int idx = threadIdx.x; idx < kH * 32; idx += 256) {
    int h = idx >> 5, j = idx & 31;
    float invf = 1.0f / powf(10000.0f, (float)j * 0.03125f);
    float ang = p * invf; float s, c; sincosf(ang, &s, &c);
    size_t base = ((size_t)t * kH + h) * kQKD + kNOPE + 2 * j;
    float x1 = q[base], x2 = q[base + 1];
    q[base] = x1 * c - x2 * s;
    q[base + 1] = x2 * c + x1 * s;
  }
}

__global__ __launch_bounds__(256) void k_rope_iq(float* __restrict__ iq, const int* __restrict__ pos) {
  int t = blockIdx.x;
  float p = (float)pos[t];
  for (int idx = threadIdx.x; idx < kIH * 32; idx += 256) {
    int h = idx >> 5, j = idx & 31;
    float invf = 1.0f / powf(10000.0f, (float)j * 0.03125f);
    float ang = p * invf; float s, c; sincosf(ang, &s, &c);
    size_t base = ((size_t)t * kIH + h) * kID + 2 * j;
    float x1 = iq[base], x2 = iq[base + 1];
    iq[base] = x1 * c - x2 * s;
    iq[base + 1] = x2 * c + x1 * s;
  }
}

__global__ __launch_bounds__(64) void k_rope_kpe(const float* __restrict__ qkv, int stride,
                                                 const int* __restrict__ pos, float* __restrict__ kpe) {
  int t = blockIdx.x; int j = threadIdx.x;
  if (j >= 32) return;
  float p = (float)pos[t];
  float invf = 1.0f / powf(10000.0f, (float)j * 0.03125f);
  float ang = p * invf; float s, c; sincosf(ang, &s, &c);
  const float* src = qkv + (size_t)t * stride + kQL + kKVL;
  float x1 = src[2 * j], x2 = src[2 * j + 1];
  kpe[(size_t)t * 64 + 2 * j] = x1 * c - x2 * s;
  kpe[(size_t)t * 64 + 2 * j + 1] = x2 * c + x1 * s;
}

// quantize rows of f32 [rows][kID] -> fp8-grid values stored as bf16 (exact), + pow2 scale
__global__ __launch_bounds__(64) void k_quant_rows(const float* __restrict__ x, u16* __restrict__ outq,
                                                   float* __restrict__ scales) {
  int row = blockIdx.x;
  const float* p = x + (size_t)row * kID;
  int l = threadIdx.x;
  float v0 = p[2 * l], v1 = p[2 * l + 1];
  float am = wmax64(fmaxf(fabsf(v0), fabsf(v1)));
  float scale = pow2ceil(fmaxf(am / 448.0f, 1e-10f));
  float inv = 1.0f / scale;
  float q0 = fp8q(fminf(fmaxf(v0 * inv, -448.f), 448.f));
  float q1 = fp8q(fminf(fmaxf(v1 * inv, -448.f), 448.f));
  ushort2 pk; pk.x = f2bf(q0); pk.y = f2bf(q1);
  *(ushort2*)&outq[(size_t)row * kID + 2 * l] = pk;
  if (l == 0) scales[row] = scale;
}

__global__ __launch_bounds__(64) void k_ik_process(const float* __restrict__ raw, int stride,
                                                   const float* __restrict__ w,
                                                   const float* __restrict__ b, const int* __restrict__ pos,
                                                   u16* __restrict__ outq, float* __restrict__ scales) {
  int t = blockIdx.x; int l = threadIdx.x;
  const float* x = raw + (size_t)t * stride;
  float x0 = x[2 * l], x1 = x[2 * l + 1];
  float mean = wsum(x0 + x1) * (1.0f / 128.0f);
  float d0 = x0 - mean, d1 = x1 - mean;
  float var = wsum(d0 * d0 + d1 * d1) * (1.0f / 128.0f);
  float inv = 1.0f / sqrtf(var + 1e-6f);
  float y0 = d0 * inv * w[2 * l] + b[2 * l];
  float y1 = d1 * inv * w[2 * l + 1] + b[2 * l + 1];
  if (l < 32) {
    float p = (float)pos[t];
    float invf = 1.0f / powf(10000.0f, (float)l * 0.03125f);
    float ang = p * invf; float sn, cs; sincosf(ang, &sn, &cs);
    float r0 = y0 * cs - y1 * sn, r1 = y1 * cs + y0 * sn;
    y0 = r0; y1 = r1;
  }
  float am = wmax64(fmaxf(fabsf(y0), fabsf(y1)));
  float scale = pow2ceil(fmaxf(am / 448.0f, 1e-10f));
  float is = 1.0f / scale;
  float q0 = fp8q(fminf(fmaxf(y0 * is, -448.f), 448.f));
  float q1 = fp8q(fminf(fmaxf(y1 * is, -448.f), 448.f));
  ushort2 pk; pk.x = f2bf(q0); pk.y = f2bf(q1);
  *(ushort2*)&outq[(size_t)t * kID + 2 * l] = pk;
  if (l == 0) scales[t] = scale;
}

// MFMA indexer scores: scores[t][s] = sum_h iw[t][h] * relu( (iq[t,h,:] . ik[s,:]) * iksc[s] )
__global__ __launch_bounds__(256) void k_scores_mfma(const u16* __restrict__ iq, const u16* __restrict__ ik,
                                                     const float* __restrict__ iksc, const float* __restrict__ iw,
                                                     float* __restrict__ scores) {
  int tb = blockIdx.y * 4;   // 4 tokens per block
  int bn = blockIdx.x * 128; // source base
  if (bn > tb + 3) return;   // entirely s > t
  __shared__ __align__(16) u16 As[128 * 32];
  __shared__ __align__(16) u16 Bs[128 * 32];
  int tid = threadIdx.x, wave = tid >> 6, lane = tid & 63;
  int wy = (wave >> 1) * 64, wx = (wave & 1) * 64;
  int lm = lane & 15, lk = lane >> 4;
  const u16* Ab = iq + (size_t)(tb * kIH) * kID;
  const u16* Bb = ik + (size_t)bn * kID;
  floatx4 acc[4][4] = {};
  for (int k0 = 0; k0 < kID; k0 += 32) {
    stage_tile(Ab + k0, kID, As, wave, lane);
    stage_tile(Bb + k0, kID, Bs, wave, lane);
    __syncthreads();
    short8 af[4], bfr[4];
#pragma unroll
    for (int mt = 0; mt < 4; mt++) af[mt] = *(short8*)&As[(wy + mt * 16 + lm) * 32 + lk * 8];
#pragma unroll
    for (int nt = 0; nt < 4; nt++) bfr[nt] = *(short8*)&Bs[(wx + nt * 16 + lm) * 32 + lk * 8];
#pragma unroll
    for (int mt = 0; mt < 4; mt++)
#pragma unroll
      for (int nt = 0; nt < 4; nt++)
        acc[mt][nt] = __builtin_amdgcn_mfma_f32_16x16x32_bf16(af[mt], bfr[nt], acc[mt][nt], 0, 0, 0);
    __syncthreads();
  }
  float scv[4];
#pragma unroll
  for (int nt = 0; nt < 4; nt++) scv[nt] = iksc[bn + wx + nt * 16 + lm];
  float iwv[4][4];
#pragma unroll
  for (int mt = 0; mt < 4; mt++)
#pragma unroll
    for (int r = 0; r < 4; r++)
      iwv[mt][r] = iw[(tb + (wy >> 5) + (mt >> 1)) * kIH + (mt & 1) * 16 + lk * 4 + r];
#pragma unroll
  for (int tp = 0; tp < 2; tp++) {
    int tglob = tb + (wy >> 5) + tp;
#pragma unroll
    for (int nt = 0; nt < 4; nt++) {
      float v = 0.f;
#pragma unroll
      for (int mh = 0; mh < 2; mh++) {
        int mt = tp * 2 + mh;
#pragma unroll
        for (int r = 0; r < 4; r++)
          v += fmaxf(acc[mt][nt][r] * scv[nt], 0.f) * iwv[mt][r];
      }
      v += __shfl_xor(v, 16, 64);
      v += __shfl_xor(v, 32, 64);
      if (lk == 0) scores[(size_t)tglob * kT + bn + wx + nt * 16 + lm] = v;
    }
  }
}

__global__ __launch_bounds__(64) void k_topk(const float* __restrict__ scores, unsigned long long* __restrict__ mbits) {
  int t = blockIdx.x; int l = threadIdx.x;
  __shared__ unsigned short tmp[64];
  unsigned long long* mrow = mbits + (size_t)t * 16;
  if (t < kTOPK) {
    if (l < 16) {
      int lo = l * 64, hi = lo + 63;
      unsigned long long bits;
      if (hi <= t) bits = ~0ull;
      else if (lo > t) bits = 0ull;
      else bits = (1ull << (t - lo + 1)) - 1ull;
      mrow[l] = bits;
    }
    return;
  }
  unsigned key[16];
  const float* srow = scores + (size_t)t * kT;
#pragma unroll
  for (int i = 0; i < 16; i++) {
    int s = l * 16 + i;
    key[i] = (s <= t) ? sortkey(srow[s]) : 0u;
  }
  unsigned prefix = 0; int remaining = kTOPK;
  for (int bit = 31; bit >= 0; bit--) {
    unsigned himask = 0xFFFFFFFFu << bit;
    unsigned cmp = prefix | (1u << bit);
    int c = 0;
#pragma unroll
    for (int i = 0; i < 16; i++) c += ((key[i] & himask) == cmp) ? 1 : 0;
    c = wsum_i(c);
    if (c >= remaining) prefix = cmp; else remaining -= c;
  }
  int ceq = 0, cgt = 0;
#pragma unroll
  for (int i = 0; i < 16; i++) { ceq += (key[i] == prefix) ? 1 : 0; cgt += (key[i] > prefix) ? 1 : 0; }
  int v = ceq;
#pragma unroll
  for (int o = 1; o < 64; o <<= 1) { int u = __shfl_up(v, o, 64); if (l >= o) v += u; }
  int rank = v - ceq;
  int need = kTOPK - wsum_i(cgt);
  unsigned short mybits = 0;
#pragma unroll
  for (int i = 0; i < 16; i++) {
    int sel;
    if (key[i] > prefix) sel = 1;
    else if (key[i] == prefix) { sel = (rank < need) ? 1 : 0; rank++; }
    else sel = 0;
    mybits |= (unsigned short)(sel << i);
  }
  tmp[l] = mybits;
  __syncthreads();
  if (l < 16) {
    mrow[l] = (unsigned long long)tmp[4 * l] | ((unsigned long long)tmp[4 * l + 1] << 16) |
              ((unsigned long long)tmp[4 * l + 2] << 32) | ((unsigned long long)tmp[4 * l + 3] << 48);
  }
}

__global__ __launch_bounds__(64) void k_route(const float* __restrict__ hs2, const float* __restrict__ wg,
                                              int* __restrict__ cnt, int* __restrict__ toki,
                                              float* __restrict__ tokw) {
  int t = blockIdx.x; int l = threadIdx.x;
  float acc[8] = {};
  for (int d = l; d < kD; d += 64) {
    float hv = hs2[(size_t)t * kD + d];
    const float* wr = wg + (size_t)d * 8;
#pragma unroll
    for (int e = 0; e < 8; e++) acc[e] += hv * wr[e];
  }
#pragma unroll
  for (int e = 0; e < 8; e++) acc[e] = wsum(acc[e]);
  if (l == 0) {
    float g[8];
#pragma unroll
    for (int e = 0; e < 8; e++) g[e] = 1.0f / (1.0f + expf(-acc[e]));
    int i0 = 0;
    for (int e = 1; e < 8; e++) if (g[e] > g[i0]) i0 = e;
    int i1 = (i0 == 0) ? 1 : 0;
    for (int e = 0; e < 8; e++) if (e != i0 && g[e] > g[i1]) i1 = e;
    float ssum = g[i0] + g[i1];
    float w0 = g[i0] / ssum * 2.5f, w1 = g[i1] / ssum * 2.5f;
    int s0 = atomicAdd(&cnt[i0], 1); toki[i0 * kT + s0] = t; tokw[i0 * kT + s0] = w0;
    int s1 = atomicAdd(&cnt[i1], 1); toki[i1 * kT + s1] = t; tokw[i1 * kT + s1] = w1;
  }
}

// ---------------- launch ----------------
extern "C" void kernel_launch(void* const* d_in, const int* in_sizes, int n_in,
                              void* d_out, int out_size, void* d_ws, size_t ws_size,
                              hipStream_t stream) {
  (void)in_sizes; (void)n_in; (void)out_size; (void)ws_size;
  const int*   positions  = (const int*)d_in[0];
  const float* hidden     = (const float*)d_in[1];
  const float* residual   = (const float*)d_in[2];
  const float* input_ln_w = (const float*)d_in[3];
  const float* post_ln_w  = (const float*)d_in[4];
  const float* w_qkv_a    = (const float*)d_in[5];
  const float* q_a_ln_w   = (const float*)d_in[6];
  const float* w_q_b      = (const float*)d_in[7];
  const float* kv_a_ln_w  = (const float*)d_in[8];
  const float* w_kv_b     = (const float*)d_in[9];
  const float* w_o        = (const float*)d_in[10];
  const float* w_idx_q_b  = (const float*)d_in[11];
  const float* w_idx_k    = (const float*)d_in[12];
  const float* idx_k_ln_w = (const float*)d_in[13];
  const float* idx_k_ln_b = (const float*)d_in[14];
  const float* w_idx_w    = (const float*)d_in[15];
  const float* w_gate     = (const float*)d_in[16];
  const float* w_moe_gate = (const float*)d_in[17];
  const float* w_moe_up   = (const float*)d_in[18];
  const float* w_moe_down = (const float*)d_in[19];
  const float* w_sh_gate  = (const float*)d_in[20];
  const float* w_sh_up    = (const float*)d_in[21];
  const float* w_sh_down  = (const float*)d_in[22];

  float* out0 = (float*)d_out;
  float* out1 = out0 + (size_t)kT * kD;

  char* W = (char*)d_ws;
  size_t off = 0;
  auto alloc = [&](size_t bytes) { char* p = W + off; off += (bytes + 255) & ~(size_t)255; return p; };
  // f32 buffers
  float* resid   = (float*)alloc((size_t)kT * kD * 4);
  float* hs      = (float*)alloc((size_t)kT * kD * 4);
  float* qkvF    = (float*)alloc((size_t)kT * kQKV_F * 4);
  float* qb      = (float*)alloc((size_t)kT * kH * kQKD * 4);
  float* kvb     = (float*)alloc((size_t)kT * kH * 256 * 4);
  float* iqb     = (float*)alloc((size_t)kT * kIH * kID * 4);
  float* iksc    = (float*)alloc(kT * 4);
  float* iqsc    = (float*)alloc((size_t)kT * kIH * 4);
  float* iwb     = (float*)alloc((size_t)kT * kIH * 4);
  float* kpe     = (float*)alloc((size_t)kT * kROPE * 4);
  float* scoresb = (float*)alloc((size_t)kT * kT * 4);
  float* hs2     = (float*)alloc((size_t)kT * kD * 4);
  unsigned long long* mbits = (unsigned long long*)alloc((size_t)kT * 16 * 8);
  float* tokw    = (float*)alloc((size_t)kE * kT * 4);
  int*   toki    = (int*)alloc((size_t)kE * kT * 4);
  int*   cnt     = (int*)alloc(64);
  // split-K partial buffer ALIASED onto kvb+iqb (33.5 MB contiguous, both 256-aligned sizes).
  // Safe: qkvP is fully consumed by k_reduce4 before kvb/iqb are first written (same stream).
  float* qkvP    = kvb; // needs 4*kT*kQKV_F*4 = 25.2 MB <= 33.5 MB
  // bf16 activations
  u16* hs_h   = (u16*)alloc((size_t)kT * kD * 2);
  u16* hs_l   = (u16*)alloc((size_t)kT * kD * 2);
  u16* qc_h   = (u16*)alloc((size_t)kT * kQL * 2);
  u16* qc_l   = (u16*)alloc((size_t)kT * kQL * 2);
  u16* kvc_h  = (u16*)alloc((size_t)kT * kKVL * 2);
  u16* o_bf   = (u16*)alloc((size_t)kT * kH * kVD * 2);
  u16* hs2_h  = (u16*)alloc((size_t)kT * kD * 2);
  u16* sg_bf  = (u16*)alloc((size_t)kT * kF * 2);
  u16* hmid_bf= (u16*)alloc((size_t)kE * kT * kF * 2);
  u16* iq_bf  = (u16*)alloc((size_t)kT * kIH * kID * 2);
  u16* ik_bf  = (u16*)alloc((size_t)kT * kID * 2);
  // bf16 transposed weights (qkv fused buffer holds qkv rows 0..1407 + ik rows 1408..1535)
  u16* qkvBT_h = (u16*)alloc((size_t)kQKV_F * kD * 2);
  u16* qkvBT_l = (u16*)alloc((size_t)kQKV_F * kD * 2);
  u16* qbBT    = (u16*)alloc((size_t)kH * kQKD * kQL * 2);
  u16* kvbBT   = (u16*)alloc((size_t)kH * 256 * kKVL * 2);
  u16* woBT    = (u16*)alloc((size_t)kD * kH * kVD * 2);
  u16* iqBT_h  = (u16*)alloc((size_t)kIH * kID * kQL * 2);
  u16* iqBT_l  = (u16*)alloc((size_t)kIH * kID * kQL * 2);
  u16* shgBT   = (u16*)alloc((size_t)kF * kD * 2);
  u16* shuBT   = (u16*)alloc((size_t)kF * kD * 2);
  u16* shdBT   = (u16*)alloc((size_t)kD * kF * 2);
  u16* moegBT  = (u16*)alloc((size_t)kE * kF * kD * 2);
  u16* moeuBT  = (u16*)alloc((size_t)kE * kF * kD * 2);
  u16* moedBT  = (u16*)alloc((size_t)kE * kD * kF * 2);

  // ---- weight prep (runs every launch; inputs are constant) ----
  { dim3 g(kQKV_NP / 32, kD / 32); k_transpose_w<<<g, 256, 0, stream>>>(w_qkv_a, qkvBT_h, qkvBT_l, kD, kQKV_N, kQKV_NP); }
  { dim3 g(kID / 32, kD / 32); k_transpose_w<<<g, 256, 0, stream>>>(w_idx_k, qkvBT_h + (size_t)kIKOFF * kD, qkvBT_l + (size_t)kIKOFF * kD, kD, kID, kID); }
  { dim3 g(kH * kQKD / 32, kQL / 32); k_transpose_w<<<g, 256, 0, stream>>>(w_q_b, qbBT, nullptr, kQL, kH * kQKD, kH * kQKD); }
  { dim3 g(kH * 256 / 32, kKVL / 32); k_transpose_w<<<g, 256, 0, stream>>>(w_kv_b, kvbBT, nullptr, kKVL, kH * 256, kH * 256); }
  { dim3 g(kD / 32, kH * kVD / 32); k_transpose_w<<<g, 256, 0, stream>>>(w_o, woBT, nullptr, kH * kVD, kD, kD); }
  { dim3 g(kIH * kID / 32, kQL / 32); k_transpose_w<<<g, 256, 0, stream>>>(w_idx_q_b, iqBT_h, iqBT_l, kQL, kIH * kID, kIH * kID); }
  { dim3 g(kF / 32, kD / 32); k_transpose_w<<<g, 256, 0, stream>>>(w_sh_gate, shgBT, nullptr, kD, kF, kF); }
  { dim3 g(kF / 32, kD / 32); k_transpose_w<<<g, 256, 0, stream>>>(w_sh_up, shuBT, nullptr, kD, kF, kF); }
  { dim3 g(kD / 32, kF / 32); k_transpose_w<<<g, 256, 0, stream>>>(w_sh_down, shdBT, nullptr, kF, kD, kD); }
  { dim3 g(kF / 32, kD / 32, kE); k_transpose_w<<<g, 256, 0, stream>>>(w_moe_gate, moegBT, nullptr, kD, kF, kF); }
  { dim3 g(kF / 32, kD / 32, kE); k_transpose_w<<<g, 256, 0, stream>>>(w_moe_up, moeuBT, nullptr, kD, kF, kF); }
  { dim3 g(kD / 32, kF / 32, kE); k_transpose_w<<<g, 256, 0, stream>>>(w_moe_down, moedBT, nullptr, kF, kD, kD); }

  // ---- forward ----
  k_add_rms<<<kT, 256, 0, stream>>>(hidden, residual, input_ln_w, resid, hs, hs_h, hs_l);
  // fused qkv+ik GEMM, split-K x4 over K=2048; partials in qkvP (aliased), reduced into qkvF
  { dim3 g(kQKV_F / 128, kT / 128, 4); k_gemm_splitk<<<g, 256, 0, stream>>>(hs_h, hs_l, qkvBT_h, qkvBT_l, qkvP, kT, kQKV_F, kD, kD / 4); }
  { int n4 = kT * kQKV_F / 4; k_reduce4<<<(n4 + 255) / 256, 256, 0, stream>>>(qkvP, qkvF, n4); }
  k_rms_rows<<<kT, 256, 0, stream>>>(qkvF, kQKV_F, 0, q_a_ln_w, nullptr, qc_h, qc_l, kQL);
  k_rms_rows<<<kT, 256, 0, stream>>>(qkvF, kQKV_F, kQL, kv_a_ln_w, nullptr, kvc_h, nullptr, kKVL);
  { dim3 g(kH * kQKD / 128, kT / 128); k_gemm_bt<<<g, 256, 0, stream>>>(qc_h, qbBT, qb, nullptr, kT, kH * kQKD, kQL); }
  { dim3 g(kIH * kID / 128, kT / 128); k_gemm_split<<<g, 256, 0, stream>>>(qc_h, qc_l, iqBT_h, iqBT_l, iqb, kT, kIH * kID, kQL); }
  { dim3 g(kH * 256 / 128, kT / 128); k_gemm_bt<<<g, 256, 0, stream>>>(kvc_h, kvbBT, kvb, nullptr, kT, kH * 256, kKVL); }
  k_rope_q<<<kT, 256, 0, stream>>>(qb, positions);
  k_rope_iq<<<kT, 256, 0, stream>>>(iqb, positions);
  k_rope_kpe<<<kT, 64, 0, stream>>>(qkvF, kQKV_F, positions, kpe);
  k_quant_rows<<<kT * kIH, 64, 0, stream>>>(iqb, iq_bf, iqsc);
  k_ik_process<<<kT, 64, 0, stream>>>(qkvF + kIKOFF, kQKV_F, idx_k_ln_w, idx_k_ln_b, positions, ik_bf, iksc);
  k_iw_fused<<<kT, 256, 0, stream>>>(hs, w_idx_w, iqsc, iwb);
  { dim3 g(kT / 128, kT / 4); k_scores_mfma<<<g, 256, 0, stream>>>(iq_bf, ik_bf, iksc, iwb, scoresb); }
  k_topk<<<kT, 64, 0, stream>>>(scoresb, mbits);
  { dim3 g(kT / 64, kH); k_attn_mfma<<<g, 256, 0, stream>>>(qb, kvb, kpe, mbits, o_bf); }
  { dim3 g(kD / 128, kT / 128); k_gemm_bt<<<g, 256, 0, stream>>>(o_bf, woBT, out1, resid, kT, kD, kH * kVD); }
  k_rms_rows<<<kT, 256, 0, stream>>>(out1, kD, 0, post_ln_w, hs2, hs2_h, nullptr, kD);
  hipMemsetAsync(cnt, 0, 8 * sizeof(int), stream);
  k_route<<<kT, 64, 0, stream>>>(hs2, w_gate, cnt, toki, tokw);
  { dim3 g(kF / 64, kT / 64, 1); k_dual_bt64<<<g, 256, 0, stream>>>(hs2_h, shgBT, shuBT, sg_bf, nullptr, nullptr, kT, kF, kD); }
  { dim3 g(kD / 128, kT / 128); k_gemm_bt<<<g, 256, 0, stream>>>(sg_bf, shdBT, out0, nullptr, kT, kD, kF); }
  { dim3 g(kF / 64, kT / 64, kE); k_dual_bt64<<<g, 256, 0, stream>>>(hs2_h, moegBT, moeuBT, hmid_bf, toki, cnt, kT, kF, kD); }
  { dim3 g(kD / 128, kT / 64, kE); k_down_bt64<<<g, 256, 0, stream>>>(hmid_bf, moedBT, toki, tokw, cnt, out0); }
}

// Round 6
// 918.735 us; speedup vs baseline: 1.5911x; 1.0352x over previous
//
#include <hip/hip_runtime.h>

namespace {
constexpr int kT = 1024, kD = 2048, kH = 16, kNOPE = 128, kROPE = 64, kVD = 128, kQKD = 192;
constexpr int kQL = 768, kKVL = 512, kIH = 32, kID = 128, kTOPK = 256, kE = 8, kF = 1024;
constexpr int kQKV_N = kQL + kKVL + kROPE; // 1344
constexpr int kQKV_NP = 1408;              // padded to 128
constexpr int kIKOFF = 1408;               // ik columns start here in fused buffer
constexpr int kQKV_F = 1536;               // fused qkv+ik padded width
}

typedef __attribute__((ext_vector_type(4))) float floatx4;
typedef __attribute__((ext_vector_type(8))) short short8;
typedef unsigned short u16;

// ---------------- device helpers ----------------
__device__ __forceinline__ float wsum(float v) {
#pragma unroll
  for (int o = 32; o; o >>= 1) v += __shfl_xor(v, o, 64);
  return v;
}
__device__ __forceinline__ float wmax64(float v) {
#pragma unroll
  for (int o = 32; o; o >>= 1) v = fmaxf(v, __shfl_xor(v, o, 64));
  return v;
}
__device__ __forceinline__ int wsum_i(int v) {
#pragma unroll
  for (int o = 32; o; o >>= 1) v += __shfl_xor(v, o, 64);
  return v;
}
__device__ __forceinline__ float bsum256(float v, float* red) {
  v = wsum(v);
  if ((threadIdx.x & 63) == 0) red[threadIdx.x >> 6] = v;
  __syncthreads();
  float t = red[0] + red[1] + red[2] + red[3];
  __syncthreads();
  return t;
}
__device__ __forceinline__ unsigned sortkey(float f) {
  unsigned b = __float_as_uint(f);
  return (b & 0x80000000u) ? ~b : (b | 0x80000000u);
}
__device__ __forceinline__ float pow2ceil(float z) {
  unsigned b = __float_as_uint(z);
  if ((b & 0x7FFFFFu) == 0) return z;
  return __uint_as_float((((b >> 23) & 0xFFu) + 1u) << 23);
}
__device__ __forceinline__ float fp8q(float x) {
  float ax = fabsf(x);
  float q;
  if (ax < 0.015625f) {
    q = rintf(ax * 512.0f) * 0.001953125f;
  } else {
    unsigned b = __float_as_uint(ax);
    int e = (int)((b >> 23) & 0xFF) - 127;
    float quant = __uint_as_float((unsigned)(e - 3 + 127) << 23);
    float rq    = __uint_as_float((unsigned)(127 - (e - 3)) << 23);
    q = rintf(ax * rq) * quant;
  }
  return copysignf(q, x);
}
__device__ __forceinline__ u16 f2bf(float x) {
  unsigned u = __float_as_uint(x);
  u += 0x7FFFu + ((u >> 16) & 1u);
  return (u16)(u >> 16);
}
__device__ __forceinline__ float bf2f(u16 h) { return __uint_as_float((unsigned)h << 16); }

// async global->LDS, 16B per lane; lds ptr must be wave-uniform (HW adds lane*16)
__device__ __forceinline__ void gld_lds16(const void* g, void* l) {
  __builtin_amdgcn_global_load_lds(
      (const __attribute__((address_space(1))) unsigned int*)(unsigned long long)g,
      (__attribute__((address_space(3))) unsigned int*)(unsigned int)(unsigned long long)l,
      16, 0, 0);
}
// stage 128 rows x 32 bf16 cols; wave stages rows [wave*32, wave*32+32)
__device__ __forceinline__ void stage_tile(const u16* g, size_t strideUs, u16* tile, int wave, int lane) {
  int r = lane >> 2, c = lane & 3;
  const u16* gp = g + (size_t)(wave * 32 + r) * strideUs + c * 8;
  gld_lds16(gp, tile + (wave * 32) * 32);
  gld_lds16(gp + (size_t)16 * strideUs, tile + (wave * 32 + 16) * 32);
}
// stage 64 rows x 32 bf16 cols; wave stages rows [wave*16, wave*16+16) in ONE gld
__device__ __forceinline__ void stage_tile64(const u16* g, size_t strideUs, u16* tile, int wave, int lane) {
  int r = lane >> 2, c = lane & 3;
  gld_lds16(g + (size_t)(wave * 16 + r) * strideUs + c * 8, tile + (wave * 16) * 32);
}

// ---------------- weight prep: f32 [K][N] -> bf16 BT [Npad][K] (+optional lo) ----------------
__global__ __launch_bounds__(256) void k_transpose_w(const float* __restrict__ in, u16* __restrict__ hi,
                                                     u16* __restrict__ lo, int K, int N, int Npad) {
  __shared__ float tile[32][33];
  int n0 = blockIdx.x * 32, k0 = blockIdx.y * 32;
  const float* ip = in + (size_t)blockIdx.z * K * N;
  u16* hp = hi + (size_t)blockIdx.z * Npad * K;
  u16* lp = lo ? lo + (size_t)blockIdx.z * Npad * K : nullptr;
  int t = threadIdx.x;
  int r = t >> 3, c4 = (t & 7) << 2;
  if (n0 < N) {
    float4 v = *(const float4*)&ip[(size_t)(k0 + r) * N + n0 + c4];
    tile[r][c4] = v.x; tile[r][c4 + 1] = v.y; tile[r][c4 + 2] = v.z; tile[r][c4 + 3] = v.w;
  } else {
    tile[r][c4] = 0.f; tile[r][c4 + 1] = 0.f; tile[r][c4 + 2] = 0.f; tile[r][c4 + 3] = 0.f;
  }
  __syncthreads();
  int n = t >> 3, kq = (t & 7) << 2;
  ushort4 h4, l4;
#pragma unroll
  for (int j = 0; j < 4; j++) {
    float f = tile[kq + j][n];
    u16 h = f2bf(f);
    ((u16*)&h4)[j] = h;
    ((u16*)&l4)[j] = f2bf(f - bf2f(h));
  }
  *(ushort4*)&hp[(size_t)(n0 + n) * K + k0 + kq] = h4;
  if (lp) *(ushort4*)&lp[(size_t)(n0 + n) * K + k0 + kq] = l4;
}

// ---------------- GEMM family: bf16 A [M][K], bf16 BT [N][K], global_load_lds staging ----------
// 128x128 tile, BK=32, 4 waves in 2x2 quadrants.

__global__ __launch_bounds__(256) void k_gemm_bt(const u16* __restrict__ A, const u16* __restrict__ BT,
                                                 float* __restrict__ C, const float* __restrict__ addend,
                                                 int M, int N, int K) {
  __shared__ __align__(16) u16 As[128 * 32];
  __shared__ __align__(16) u16 Bs[128 * 32];
  int tid = threadIdx.x, wave = tid >> 6, lane = tid & 63;
  int bm = blockIdx.y * 128, bn = blockIdx.x * 128;
  int wy = (wave >> 1) * 64, wx = (wave & 1) * 64;
  int lm = lane & 15, lk = lane >> 4;
  const u16* Ab = A + (size_t)bm * K;
  const u16* Bb = BT + (size_t)bn * K;
  floatx4 acc[4][4] = {};
  for (int k0 = 0; k0 < K; k0 += 32) {
    stage_tile(Ab + k0, K, As, wave, lane);
    stage_tile(Bb + k0, K, Bs, wave, lane);
    __syncthreads();
    short8 af[4], bfr[4];
#pragma unroll
    for (int mt = 0; mt < 4; mt++) af[mt] = *(short8*)&As[(wy + mt * 16 + lm) * 32 + lk * 8];
#pragma unroll
    for (int nt = 0; nt < 4; nt++) bfr[nt] = *(short8*)&Bs[(wx + nt * 16 + lm) * 32 + lk * 8];
#pragma unroll
    for (int mt = 0; mt < 4; mt++)
#pragma unroll
      for (int nt = 0; nt < 4; nt++)
        acc[mt][nt] = __builtin_amdgcn_mfma_f32_16x16x32_bf16(af[mt], bfr[nt], acc[mt][nt], 0, 0, 0);
    __syncthreads();
  }
#pragma unroll
  for (int mt = 0; mt < 4; mt++)
#pragma unroll
    for (int nt = 0; nt < 4; nt++)
#pragma unroll
      for (int r = 0; r < 4; r++) {
        int m = bm + wy + mt * 16 + lk * 4 + r;
        int n = bn + wx + nt * 16 + lm;
        float v = acc[mt][nt][r];
        if (addend) v += addend[(size_t)m * N + n];
        C[(size_t)m * N + n] = v;
      }
}

// 3-term split-precision GEMM: C = Ahi*Bhi + Ahi*Blo + Alo*Bhi (f32-class accuracy).
// N may be < padded BT rows; C guarded & strided by N.
__global__ __launch_bounds__(256) void k_gemm_split(const u16* __restrict__ Ah, const u16* __restrict__ Al,
                                                    const u16* __restrict__ Bh, const u16* __restrict__ Bl,
                                                    float* __restrict__ C, int M, int N, int K) {
  __shared__ __align__(16) u16 Ahs[128 * 32];
  __shared__ __align__(16) u16 Als[128 * 32];
  __shared__ __align__(16) u16 Bhs[128 * 32];
  __shared__ __align__(16) u16 Bls[128 * 32];
  int tid = threadIdx.x, wave = tid >> 6, lane = tid & 63;
  int bm = blockIdx.y * 128, bn = blockIdx.x * 128;
  int wy = (wave >> 1) * 64, wx = (wave & 1) * 64;
  int lm = lane & 15, lk = lane >> 4;
  floatx4 acc[4][4] = {};
  for (int k0 = 0; k0 < K; k0 += 32) {
    stage_tile(Ah + (size_t)bm * K + k0, K, Ahs, wave, lane);
    stage_tile(Al + (size_t)bm * K + k0, K, Als, wave, lane);
    stage_tile(Bh + (size_t)bn * K + k0, K, Bhs, wave, lane);
    stage_tile(Bl + (size_t)bn * K + k0, K, Bls, wave, lane);
    __syncthreads();
    short8 ah[4], al[4], bh[4], bl[4];
#pragma unroll
    for (int mt = 0; mt < 4; mt++) { ah[mt] = *(short8*)&Ahs[(wy + mt * 16 + lm) * 32 + lk * 8];
                                     al[mt] = *(short8*)&Als[(wy + mt * 16 + lm) * 32 + lk * 8]; }
#pragma unroll
    for (int nt = 0; nt < 4; nt++) { bh[nt] = *(short8*)&Bhs[(wx + nt * 16 + lm) * 32 + lk * 8];
                                     bl[nt] = *(short8*)&Bls[(wx + nt * 16 + lm) * 32 + lk * 8]; }
#pragma unroll
    for (int mt = 0; mt < 4; mt++)
#pragma unroll
      for (int nt = 0; nt < 4; nt++) {
        floatx4 a = acc[mt][nt];
        a = __builtin_amdgcn_mfma_f32_16x16x32_bf16(al[mt], bh[nt], a, 0, 0, 0);
        a = __builtin_amdgcn_mfma_f32_16x16x32_bf16(ah[mt], bl[nt], a, 0, 0, 0);
        a = __builtin_amdgcn_mfma_f32_16x16x32_bf16(ah[mt], bh[nt], a, 0, 0, 0);
        acc[mt][nt] = a;
      }
    __syncthreads();
  }
#pragma unroll
  for (int mt = 0; mt < 4; mt++)
#pragma unroll
    for (int nt = 0; nt < 4; nt++)
#pragma unroll
      for (int r = 0; r < 4; r++) {
        int m = bm + wy + mt * 16 + lk * 4 + r;
        int n = bn + wx + nt * 16 + lm;
        if (n < N) C[(size_t)m * N + n] = acc[mt][nt][r];
      }
}

// split-K 3-term GEMM: partial C per kz chunk, unguarded padded-N writes.
// Cp layout: [KSPLIT][M][Npad] f32.
__global__ __launch_bounds__(256) void k_gemm_splitk(const u16* __restrict__ Ah, const u16* __restrict__ Al,
                                                     const u16* __restrict__ Bh, const u16* __restrict__ Bl,
                                                     float* __restrict__ Cp, int M, int Npad, int K, int kchunk) {
  __shared__ __align__(16) u16 Ahs[128 * 32];
  __shared__ __align__(16) u16 Als[128 * 32];
  __shared__ __align__(16) u16 Bhs[128 * 32];
  __shared__ __align__(16) u16 Bls[128 * 32];
  int tid = threadIdx.x, wave = tid >> 6, lane = tid & 63;
  int bm = blockIdx.y * 128, bn = blockIdx.x * 128;
  int kz = blockIdx.z;
  int kbeg = kz * kchunk, kend = kbeg + kchunk;
  int wy = (wave >> 1) * 64, wx = (wave & 1) * 64;
  int lm = lane & 15, lk = lane >> 4;
  floatx4 acc[4][4] = {};
  for (int k0 = kbeg; k0 < kend; k0 += 32) {
    stage_tile(Ah + (size_t)bm * K + k0, K, Ahs, wave, lane);
    stage_tile(Al + (size_t)bm * K + k0, K, Als, wave, lane);
    stage_tile(Bh + (size_t)bn * K + k0, K, Bhs, wave, lane);
    stage_tile(Bl + (size_t)bn * K + k0, K, Bls, wave, lane);
    __syncthreads();
    short8 ah[4], al[4], bh[4], bl[4];
#pragma unroll
    for (int mt = 0; mt < 4; mt++) { ah[mt] = *(short8*)&Ahs[(wy + mt * 16 + lm) * 32 + lk * 8];
                                     al[mt] = *(short8*)&Als[(wy + mt * 16 + lm) * 32 + lk * 8]; }
#pragma unroll
    for (int nt = 0; nt < 4; nt++) { bh[nt] = *(short8*)&Bhs[(wx + nt * 16 + lm) * 32 + lk * 8];
                                     bl[nt] = *(short8*)&Bls[(wx + nt * 16 + lm) * 32 + lk * 8]; }
#pragma unroll
    for (int mt = 0; mt < 4; mt++)
#pragma unroll
      for (int nt = 0; nt < 4; nt++) {
        floatx4 a = acc[mt][nt];
        a = __builtin_amdgcn_mfma_f32_16x16x32_bf16(al[mt], bh[nt], a, 0, 0, 0);
        a = __builtin_amdgcn_mfma_f32_16x16x32_bf16(ah[mt], bl[nt], a, 0, 0, 0);
        a = __builtin_amdgcn_mfma_f32_16x16x32_bf16(ah[mt], bh[nt], a, 0, 0, 0);
        acc[mt][nt] = a;
      }
    __syncthreads();
  }
  float* Co = Cp + (size_t)kz * M * Npad;
#pragma unroll
  for (int mt = 0; mt < 4; mt++)
#pragma unroll
    for (int nt = 0; nt < 4; nt++)
#pragma unroll
      for (int r = 0; r < 4; r++) {
        int m = bm + wy + mt * 16 + lk * 4 + r;
        int n = bn + wx + nt * 16 + lm;
        Co[(size_t)m * Npad + n] = acc[mt][nt][r];
      }
}

// sum 4 partials: C[i] = sum_z Cp[z][i], vectorized float4
__global__ __launch_bounds__(256) void k_reduce4(const float* __restrict__ Cp, float* __restrict__ C, int n4) {
  int i = blockIdx.x * 256 + threadIdx.x;
  if (i >= n4) return;
  const floatx4* p = (const floatx4*)Cp;
  floatx4 v = p[i] + p[i + n4] + p[i + 2 * n4] + p[i + 3 * n4];
  ((floatx4*)C)[i] = v;
}

// merged dual-B gate+up (shared + all experts in one launch), 64x64 tile.
// z=0: shared FFN (A rows = all tokens, out=sgOut). z>=1: expert e=z-1 (gathered rows, out=moeOut).
__global__ __launch_bounds__(256) void k_dual_all(const u16* __restrict__ A,
                                                  const u16* __restrict__ shG, const u16* __restrict__ shU,
                                                  const u16* __restrict__ moeG, const u16* __restrict__ moeU,
                                                  u16* __restrict__ sgOut, u16* __restrict__ moeOut,
                                                  const int* __restrict__ toki, const int* __restrict__ cnt,
                                                  int N, int K) {
  int z = blockIdx.z;
  int n_rows;
  const int* tk;
  const u16 *Gb, *Ub;
  u16* oP;
  int bm = blockIdx.y * 64, bn = blockIdx.x * 64;
  if (z == 0) {
    n_rows = kT; tk = nullptr;
    Gb = shG + (size_t)bn * K; Ub = shU + (size_t)bn * K;
    oP = sgOut;
  } else {
    int e = z - 1;
    n_rows = cnt[e]; tk = toki + e * kT;
    Gb = moeG + (size_t)e * N * K + (size_t)bn * K;
    Ub = moeU + (size_t)e * N * K + (size_t)bn * K;
    oP = moeOut + (size_t)e * kT * N;
  }
  if (bm >= n_rows) return;
  __shared__ __align__(16) u16 As[64 * 32];
  __shared__ __align__(16) u16 Gs[64 * 32];
  __shared__ __align__(16) u16 Us[64 * 32];
  int tid = threadIdx.x, wave = tid >> 6, lane = tid & 63;
  int wy = (wave >> 1) * 32, wx = (wave & 1) * 32;
  int lm = lane & 15, lk = lane >> 4;
  int r = lane >> 2, c = lane & 3;
  int r0 = bm + wave * 16 + r;
  size_t arow = tk ? (size_t)((r0 < n_rows) ? tk[r0] : 0) : (size_t)r0;
  floatx4 ag[2][2] = {}, au[2][2] = {};
  for (int k0 = 0; k0 < K; k0 += 32) {
    gld_lds16(A + arow * K + k0 + c * 8, As + (wave * 16) * 32);
    stage_tile64(Gb + k0, K, Gs, wave, lane);
    stage_tile64(Ub + k0, K, Us, wave, lane);
    __syncthreads();
    short8 af[2], gf[2], uf[2];
#pragma unroll
    for (int mt = 0; mt < 2; mt++) af[mt] = *(short8*)&As[(wy + mt * 16 + lm) * 32 + lk * 8];
#pragma unroll
    for (int nt = 0; nt < 2; nt++) { gf[nt] = *(short8*)&Gs[(wx + nt * 16 + lm) * 32 + lk * 8];
                                     uf[nt] = *(short8*)&Us[(wx + nt * 16 + lm) * 32 + lk * 8]; }
#pragma unroll
    for (int mt = 0; mt < 2; mt++)
#pragma unroll
      for (int nt = 0; nt < 2; nt++) {
        ag[mt][nt] = __builtin_amdgcn_mfma_f32_16x16x32_bf16(af[mt], gf[nt], ag[mt][nt], 0, 0, 0);
        au[mt][nt] = __builtin_amdgcn_mfma_f32_16x16x32_bf16(af[mt], uf[nt], au[mt][nt], 0, 0, 0);
      }
    __syncthreads();
  }
#pragma unroll
  for (int mt = 0; mt < 2; mt++)
#pragma unroll
    for (int nt = 0; nt < 2; nt++)
#pragma unroll
      for (int r2 = 0; r2 < 4; r2++) {
        int gm = bm + wy + mt * 16 + lk * 4 + r2;
        if (gm >= n_rows) continue;
        int n = bn + wx + nt * 16 + lm;
        float gv = ag[mt][nt][r2], uv = au[mt][nt][r2];
        oP[(size_t)gm * N + n] = f2bf(gv * (1.0f / (1.0f + expf(-gv))) * uv);
      }
}

// merged down projection (shared + experts): atomicAdd into ZEROED out.
// z=0: out += sg @ shD (weight 1, token=row). z>=1: out[tok] += w * (hmid[e] @ moeD[e]).
// 64x128 tile.
__global__ __launch_bounds__(256) void k_down_all(const u16* __restrict__ sg, const u16* __restrict__ shD,
                                                  const u16* __restrict__ hmid, const u16* __restrict__ moeD,
                                                  const int* __restrict__ toki, const float* __restrict__ tokw,
                                                  const int* __restrict__ cnt, float* __restrict__ out) {
  int z = blockIdx.z;
  int bm = blockIdx.y * 64, bn = blockIdx.x * 128;
  int n_rows;
  const u16 *Ab, *Bb;
  if (z == 0) {
    n_rows = kT;
    Ab = sg + (size_t)bm * kF;
    Bb = shD + (size_t)bn * kF;
  } else {
    int e = z - 1;
    n_rows = cnt[e];
    Ab = hmid + (size_t)e * kT * kF + (size_t)bm * kF;
    Bb = moeD + (size_t)e * kD * kF + (size_t)bn * kF;
  }
  if (bm >= n_rows) return;
  __shared__ __align__(16) u16 As[64 * 32];
  __shared__ __align__(16) u16 Bs[128 * 32];
  int tid = threadIdx.x, wave = tid >> 6, lane = tid & 63;
  int wy = (wave >> 1) * 32, wx = (wave & 1) * 64;
  int lm = lane & 15, lk = lane >> 4;
  floatx4 acc[2][4] = {};
  for (int k0 = 0; k0 < kF; k0 += 32) {
    stage_tile64(Ab + k0, kF, As, wave, lane);
    stage_tile(Bb + k0, kF, Bs, wave, lane);
    __syncthreads();
    short8 af[2], bfr[4];
#pragma unroll
    for (int mt = 0; mt < 2; mt++) af[mt] = *(short8*)&As[(wy + mt * 16 + lm) * 32 + lk * 8];
#pragma unroll
    for (int nt = 0; nt < 4; nt++) bfr[nt] = *(short8*)&Bs[(wx + nt * 16 + lm) * 32 + lk * 8];
#pragma unroll
    for (int mt = 0; mt < 2; mt++)
#pragma unroll
      for (int nt = 0; nt < 4; nt++)
        acc[mt][nt] = __builtin_amdgcn_mfma_f32_16x16x32_bf16(af[mt], bfr[nt], acc[mt][nt], 0, 0, 0);
    __syncthreads();
  }
#pragma unroll
  for (int mt = 0; mt < 2; mt++)
#pragma unroll
    for (int r = 0; r < 4; r++) {
      int gm = bm + wy + mt * 16 + lk * 4 + r;
      if (gm >= n_rows) continue;
      int tt; float w;
      if (z == 0) { tt = gm; w = 1.0f; }
      else { tt = toki[(z - 1) * kT + gm]; w = tokw[(z - 1) * kT + gm]; }
#pragma unroll
      for (int nt = 0; nt < 4; nt++) {
        int n = bn + wx + nt * 16 + lm;
        atomicAdd(&out[(size_t)tt * kD + n], w * acc[mt][nt][r]);
      }
    }
}

// ---------------- flash MFMA attention (bf16 out) ----------------
__global__ __launch_bounds__(256) void k_attn_mfma(const float* __restrict__ q, const float* __restrict__ kv,
                                                   const float* __restrict__ kpe,
                                                   const unsigned long long* __restrict__ mbits,
                                                   u16* __restrict__ o) {
  __shared__ __align__(16) u16 Ks[64 * 200];
  __shared__ __align__(16) u16 Vs[128 * 72];
  __shared__ __align__(16) u16 Ps[4 * 16 * 72];
  int h = blockIdx.y;
  int qb = gridDim.x - 1 - blockIdx.x;
  int qbase = qb * 64;
  int tid = threadIdx.x;
  int wave = tid >> 6, lane = tid & 63;
  int lm = lane & 15, lk = lane >> 4;
  short8 qf[6];
  {
    const float* qrow = q + ((size_t)(qbase + wave * 16 + lm) * kH + h) * kQKD;
#pragma unroll
    for (int ks = 0; ks < 6; ks++) {
      const float4 a0 = *(const float4*)&qrow[ks * 32 + lk * 8];
      const float4 a1 = *(const float4*)&qrow[ks * 32 + lk * 8 + 4];
      short8 f;
      f[0] = (short)f2bf(a0.x); f[1] = (short)f2bf(a0.y); f[2] = (short)f2bf(a0.z); f[3] = (short)f2bf(a0.w);
      f[4] = (short)f2bf(a1.x); f[5] = (short)f2bf(a1.y); f[6] = (short)f2bf(a1.z); f[7] = (short)f2bf(a1.w);
      qf[ks] = f;
    }
  }
  float m_r[4] = {-1e30f, -1e30f, -1e30f, -1e30f};
  float l_r[4] = {};
  floatx4 Oacc[8] = {};
  int sr = tid >> 2, sj = tid & 3;
  int nch = qb + 1;
  for (int ch = 0; ch < nch; ch++) {
    int s0 = ch << 6;
    __syncthreads();
    {
      const float* kvrow = kv + ((size_t)(s0 + sr) * kH + h) * 256;
      const float* kprow = kpe + (size_t)(s0 + sr) * 64;
#pragma unroll
      for (int i = 0; i < 12; i++) {
        int c4 = (i << 2) + sj;
        float4 v4 = (c4 < 32) ? *(const float4*)&kvrow[c4 * 4] : *(const float4*)&kprow[(c4 - 32) * 4];
        ushort4 p; p.x = f2bf(v4.x); p.y = f2bf(v4.y); p.z = f2bf(v4.z); p.w = f2bf(v4.w);
        *(ushort4*)&Ks[sr * 200 + c4 * 4] = p;
      }
      const float* vrow = kvrow + 128;
#pragma unroll
      for (int i = 0; i < 8; i++) {
        int c4 = (i << 2) + sj;
        float4 v4 = *(const float4*)&vrow[c4 * 4];
        Vs[(c4 * 4 + 0) * 72 + sr] = f2bf(v4.x);
        Vs[(c4 * 4 + 1) * 72 + sr] = f2bf(v4.y);
        Vs[(c4 * 4 + 2) * 72 + sr] = f2bf(v4.z);
        Vs[(c4 * 4 + 3) * 72 + sr] = f2bf(v4.w);
      }
    }
    __syncthreads();
    floatx4 sacc[4] = {};
#pragma unroll
    for (int ks = 0; ks < 6; ks++) {
      short8 kf[4];
#pragma unroll
      for (int nt = 0; nt < 4; nt++) kf[nt] = *(short8*)&Ks[(nt * 16 + lm) * 200 + ks * 32 + lk * 8];
#pragma unroll
      for (int nt = 0; nt < 4; nt++)
        sacc[nt] = __builtin_amdgcn_mfma_f32_16x16x32_bf16(qf[ks], kf[nt], sacc[nt], 0, 0, 0);
    }
    unsigned long long mw[4];
#pragma unroll
    for (int r = 0; r < 4; r++) mw[r] = mbits[(size_t)(qbase + wave * 16 + lk * 4 + r) * 16 + ch];
    float mx[4] = {-1e30f, -1e30f, -1e30f, -1e30f};
#pragma unroll
    for (int nt = 0; nt < 4; nt++)
#pragma unroll
      for (int r = 0; r < 4; r++) {
        int sel = (int)((mw[r] >> (nt * 16 + lm)) & 1ull);
        float sv = sel ? sacc[nt][r] * 0.07216878364870323f : -1e30f;
        sacc[nt][r] = sv;
        mx[r] = fmaxf(mx[r], sv);
      }
#pragma unroll
    for (int off = 1; off < 16; off <<= 1)
#pragma unroll
      for (int r = 0; r < 4; r++) mx[r] = fmaxf(mx[r], __shfl_xor(mx[r], off, 64));
    float al[4], psum[4] = {};
#pragma unroll
    for (int r = 0; r < 4; r++) {
      float mnew = fmaxf(m_r[r], mx[r]);
      al[r] = __expf(m_r[r] - mnew);
      m_r[r] = mnew;
    }
#pragma unroll
    for (int nt = 0; nt < 4; nt++)
#pragma unroll
      for (int r = 0; r < 4; r++) {
        float p = (sacc[nt][r] > -0.9e30f) ? __expf(sacc[nt][r] - m_r[r]) : 0.0f;
        psum[r] += p;
        Ps[wave * 1152 + (lk * 4 + r) * 72 + nt * 16 + lm] = f2bf(p);
      }
#pragma unroll
    for (int off = 1; off < 16; off <<= 1)
#pragma unroll
      for (int r = 0; r < 4; r++) psum[r] += __shfl_xor(psum[r], off, 64);
#pragma unroll
    for (int r = 0; r < 4; r++) l_r[r] = l_r[r] * al[r] + psum[r];
#pragma unroll
    for (int nv = 0; nv < 8; nv++)
#pragma unroll
      for (int r = 0; r < 4; r++) Oacc[nv][r] *= al[r];
    short8 pf[2];
#pragma unroll
    for (int k2 = 0; k2 < 2; k2++) pf[k2] = *(short8*)&Ps[wave * 1152 + lm * 72 + k2 * 32 + lk * 8];
#pragma unroll
    for (int k2 = 0; k2 < 2; k2++)
#pragma unroll
      for (int nv = 0; nv < 8; nv++) {
        short8 vf = *(short8*)&Vs[(nv * 16 + lm) * 72 + k2 * 32 + lk * 8];
        Oacc[nv] = __builtin_amdgcn_mfma_f32_16x16x32_bf16(pf[k2], vf, Oacc[nv], 0, 0, 0);
      }
  }
  float invl[4];
#pragma unroll
  for (int r = 0; r < 4; r++) invl[r] = 1.0f / l_r[r];
#pragma unroll
  for (int nv = 0; nv < 8; nv++)
#pragma unroll
    for (int r = 0; r < 4; r++) {
      int t_row = qbase + wave * 16 + lk * 4 + r;
      o[((size_t)t_row * kH + h) * kVD + nv * 16 + lm] = f2bf(Oacc[nv][r] * invl[r]);
    }
}

// ---------------- norm / small kernels ----------------
__global__ __launch_bounds__(256) void k_add_rms(const float* __restrict__ h, const float* __restrict__ r,
                                                 const float* __restrict__ w, float* __restrict__ resid,
                                                 float* __restrict__ out, u16* __restrict__ oh,
                                                 u16* __restrict__ ol) {
  __shared__ float row[kD];
  __shared__ float red[4];
  int t = blockIdx.x;
  size_t base = (size_t)t * kD;
  float ss = 0.f;
  for (int c = threadIdx.x; c < kD; c += 256) {
    float v = h[base + c] + r[base + c];
    row[c] = v; resid[base + c] = v; ss += v * v;
  }
  float tot = bsum256(ss, red);
  float inv = 1.0f / sqrtf(tot * (1.0f / kD) + 1e-6f);
  for (int c = threadIdx.x; c < kD; c += 256) {
    float v = row[c] * inv * w[c];
    out[base + c] = v;
    u16 hb = f2bf(v);
    oh[base + c] = hb;
    ol[base + c] = f2bf(v - bf2f(hb));
  }
}

// rmsnorm with optional f32 / bf16-hi / bf16-lo outputs
__global__ __launch_bounds__(256) void k_rms_rows(const float* __restrict__ in, int stride, int off,
                                                  const float* __restrict__ w, float* __restrict__ outf,
                                                  u16* __restrict__ oh, u16* __restrict__ ol, int cols) {
  __shared__ float row[kD];
  __shared__ float red[4];
  int t = blockIdx.x;
  const float* x = in + (size_t)t * stride + off;
  float ss = 0.f;
  for (int c = threadIdx.x; c < cols; c += 256) { float v = x[c]; row[c] = v; ss += v * v; }
  float tot = bsum256(ss, red);
  float inv = 1.0f / sqrtf(tot / (float)cols + 1e-6f);
  for (int c = threadIdx.x; c < cols; c += 256) {
    float v = row[c] * inv * w[c];
    if (outf) outf[(size_t)t * cols + c] = v;
    if (oh) {
      u16 hb = f2bf(v);
      oh[(size_t)t * cols + c] = hb;
      if (ol) ol[(size_t)t * cols + c] = f2bf(v - bf2f(hb));
    }
  }
}

// fused iw = (hs @ w_idx_w) * iqsc * ID^-0.5 * IH^-0.5
__global__ __launch_bounds__(256) void k_iw_fused(const float* __restrict__ hs, const float* __restrict__ w,
                                                  const float* __restrict__ iqsc, float* __restrict__ out) {
  __shared__ float red[4][32];
  int t = blockIdx.x;
  int tid = threadIdx.x;
  int h = tid & 31, g = tid >> 5;
  const float* hrow = hs + (size_t)t * kD;
  float acc = 0.f;
#pragma unroll 4
  for (int d = g; d < kD; d += 8) acc += hrow[d] * w[(size_t)d * kIH + h];
  acc += __shfl_xor(acc, 32, 64);
  int wave = tid >> 6, lane = tid & 63;
  if (lane < 32) red[wave][lane] = acc;
  __syncthreads();
  if (tid < 32) {
    float v = red[0][tid] + red[1][tid] + red[2][tid] + red[3][tid];
    out[t * kIH + tid] = v * iqsc[t * kIH + tid] * 0.08838834764831845f * 0.17677669529663687f;
  }
}

__global__ __launch_bounds__(256) void k_rope_q(float* __restrict__ q, const int* __restrict__ pos) {
  int t = blockIdx.x;
  float p = (float)pos[t];
  for (int idx = threadIdx.x; idx < kH * 32; idx += 256) {
    int h = idx >> 5, j = idx & 31;
    float invf = 1.0f / powf(10000.0f, (float)j * 0.03125f);
    float ang = p * invf; float s, c; sincosf(ang, &s, &c);
    size_t base = ((size_t)t * kH + h) * kQKD + kNOPE + 2 * j;
    float x1 = q[base], x2 = q[base + 1];
    q[base] = x1 * c - x2 * s;
    q[base + 1] = x2 * c + x1 * s;
  }
}

__global__ __launch_bounds__(256) void k_rope_iq(float* __restrict__ iq, const int* __restrict__ pos) {
  int t = blockIdx.x;
  float p = (float)pos[t];
  for (int idx = threadIdx.x; idx < kIH * 32; idx += 256) {
    int h = idx >> 5, j = idx & 31;
    float invf = 1.0f / powf(10000.0f, (float)j * 0.03125f);
    float ang = p * invf; float s, c; sincosf(ang, &s, &c);
    size_t base = ((size_t)t * kIH + h) * kID + 2 * j;
    float x1 = iq[base], x2 = iq[base + 1];
    iq[base] = x1 * c - x2 * s;
    iq[base + 1] = x2 * c + x1 * s;
  }
}

__global__ __launch_bounds__(64) void k_rope_kpe(const float* __restrict__ qkv, int stride,
                                                 const int* __restrict__ pos, float* __restrict__ kpe) {
  int t = blockIdx.x; int j = threadIdx.x;
  if (j >= 32) return;
  float p = (float)pos[t];
  float invf = 1.0f / powf(10000.0f, (float)j * 0.03125f);
  float ang = p * invf; float s, c; sincosf(ang, &s, &c);
  const float* src = qkv + (size_t)t * stride + kQL + kKVL;
  float x1 = src[2 * j], x2 = src[2 * j + 1];
  kpe[(size_t)t * 64 + 2 * j] = x1 * c - x2 * s;
  kpe[(size_t)t * 64 + 2 * j + 1] = x2 * c + x1 * s;
}

// quantize rows of f32 [rows][kID] -> fp8-grid values stored as bf16 (exact), + pow2 scale
__global__ __launch_bounds__(64) void k_quant_rows(const float* __restrict__ x, u16* __restrict__ outq,
                                                   float* __restrict__ scales) {
  int row = blockIdx.x;
  const float* p = x + (size_t)row * kID;
  int l = threadIdx.x;
  float v0 = p[2 * l], v1 = p[2 * l + 1];
  float am = wmax64(fmaxf(fabsf(v0), fabsf(v1)));
  float scale = pow2ceil(fmaxf(am / 448.0f, 1e-10f));
  float inv = 1.0f / scale;
  float q0 = fp8q(fminf(fmaxf(v0 * inv, -448.f), 448.f));
  float q1 = fp8q(fminf(fmaxf(v1 * inv, -448.f), 448.f));
  ushort2 pk; pk.x = f2bf(q0); pk.y = f2bf(q1);
  *(ushort2*)&outq[(size_t)row * kID + 2 * l] = pk;
  if (l == 0) scales[row] = scale;
}

__global__ __launch_bounds__(64) void k_ik_process(const float* __restrict__ raw, int stride,
                                                   const float* __restrict__ w,
                                                   const float* __restrict__ b, const int* __restrict__ pos,
                                                   u16* __restrict__ outq, float* __restrict__ scales) {
  int t = blockIdx.x; int l = threadIdx.x;
  const float* x = raw + (size_t)t * stride;
  float x0 = x[2 * l], x1 = x[2 * l + 1];
  float mean = wsum(x0 + x1) * (1.0f / 128.0f);
  float d0 = x0 - mean, d1 = x1 - mean;
  float var = wsum(d0 * d0 + d1 * d1) * (1.0f / 128.0f);
  float inv = 1.0f / sqrtf(var + 1e-6f);
  float y0 = d0 * inv * w[2 * l] + b[2 * l];
  float y1 = d1 * inv * w[2 * l + 1] + b[2 * l + 1];
  if (l < 32) {
    float p = (float)pos[t];
    float invf = 1.0f / powf(10000.0f, (float)l * 0.03125f);
    float ang = p * invf; float sn, cs; sincosf(ang, &sn, &cs);
    float r0 = y0 * cs - y1 * sn, r1 = y1 * cs + y0 * sn;
    y0 = r0; y1 = r1;
  }
  float am = wmax64(fmaxf(fabsf(y0), fabsf(y1)));
  float scale = pow2ceil(fmaxf(am / 448.0f, 1e-10f));
  float is = 1.0f / scale;
  float q0 = fp8q(fminf(fmaxf(y0 * is, -448.f), 448.f));
  float q1 = fp8q(fminf(fmaxf(y1 * is, -448.f), 448.f));
  ushort2 pk; pk.x = f2bf(q0); pk.y = f2bf(q1);
  *(ushort2*)&outq[(size_t)t * kID + 2 * l] = pk;
  if (l == 0) scales[t] = scale;
}

// MFMA indexer scores: scores[t][s] = sum_h iw[t][h] * relu( (iq[t,h,:] . ik[s,:]) * iksc[s] )
__global__ __launch_bounds__(256) void k_scores_mfma(const u16* __restrict__ iq, const u16* __restrict__ ik,
                                                     const float* __restrict__ iksc, const float* __restrict__ iw,
                                                     float* __restrict__ scores) {
  int tb = blockIdx.y * 4;   // 4 tokens per block
  int bn = blockIdx.x * 128; // source base
  if (bn > tb + 3) return;   // entirely s > t
  __shared__ __align__(16) u16 As[128 * 32];
  __shared__ __align__(16) u16 Bs[128 * 32];
  int tid = threadIdx.x, wave = tid >> 6, lane = tid & 63;
  int wy = (wave >> 1) * 64, wx = (wave & 1) * 64;
  int lm = lane & 15, lk = lane >> 4;
  const u16* Ab = iq + (size_t)(tb * kIH) * kID;
  const u16* Bb = ik + (size_t)bn * kID;
  floatx4 acc[4][4] = {};
  for (int k0 = 0; k0 < kID; k0 += 32) {
    stage_tile(Ab + k0, kID, As, wave, lane);
    stage_tile(Bb + k0, kID, Bs, wave, lane);
    __syncthreads();
    short8 af[4], bfr[4];
#pragma unroll
    for (int mt = 0; mt < 4; mt++) af[mt] = *(short8*)&As[(wy + mt * 16 + lm) * 32 + lk * 8];
#pragma unroll
    for (int nt = 0; nt < 4; nt++) bfr[nt] = *(short8*)&Bs[(wx + nt * 16 + lm) * 32 + lk * 8];
#pragma unroll
    for (int mt = 0; mt < 4; mt++)
#pragma unroll
      for (int nt = 0; nt < 4; nt++)
        acc[mt][nt] = __builtin_amdgcn_mfma_f32_16x16x32_bf16(af[mt], bfr[nt], acc[mt][nt], 0, 0, 0);
    __syncthreads();
  }
  float scv[4];
#pragma unroll
  for (int nt = 0; nt < 4; nt++) scv[nt] = iksc[bn + wx + nt * 16 + lm];
  float iwv[4][4];
#pragma unroll
  for (int mt = 0; mt < 4; mt++)
#pragma unroll
    for (int r = 0; r < 4; r++)
      iwv[mt][r] = iw[(tb + (wy >> 5) + (mt >> 1)) * kIH + (mt & 1) * 16 + lk * 4 + r];
#pragma unroll
  for (int tp = 0; tp < 2; tp++) {
    int tglob = tb + (wy >> 5) + tp;
#pragma unroll
    for (int nt = 0; nt < 4; nt++) {
      float v = 0.f;
#pragma unroll
      for (int mh = 0; mh < 2; mh++) {
        int mt = tp * 2 + mh;
#pragma unroll
        for (int r = 0; r < 4; r++)
          v += fmaxf(acc[mt][nt][r] * scv[nt], 0.f) * iwv[mt][r];
      }
      v += __shfl_xor(v, 16, 64);
      v += __shfl_xor(v, 32, 64);
      if (lk == 0) scores[(size_t)tglob * kT + bn + wx + nt * 16 + lm] = v;
    }
  }
}

__global__ __launch_bounds__(64) void k_topk(const float* __restrict__ scores, unsigned long long* __restrict__ mbits) {
  int t = blockIdx.x; int l = threadIdx.x;
  __shared__ unsigned short tmp[64];
  unsigned long long* mrow = mbits + (size_t)t * 16;
  if (t < kTOPK) {
    if (l < 16) {
      int lo = l * 64, hi = lo + 63;
      unsigned long long bits;
      if (hi <= t) bits = ~0ull;
      else if (lo > t) bits = 0ull;
      else bits = (1ull << (t - lo + 1)) - 1ull;
      mrow[l] = bits;
    }
    return;
  }
  unsigned key[16];
  const float* srow = scores + (size_t)t * kT;
#pragma unroll
  for (int i = 0; i < 16; i++) {
    int s = l * 16 + i;
    key[i] = (s <= t) ? sortkey(srow[s]) : 0u;
  }
  unsigned prefix = 0; int remaining = kTOPK;
  for (int bit = 31; bit >= 0; bit--) {
    unsigned himask = 0xFFFFFFFFu << bit;
    unsigned cmp = prefix | (1u << bit);
    int c = 0;
#pragma unroll
    for (int i = 0; i < 16; i++) c += ((key[i] & himask) == cmp) ? 1 : 0;
    c = wsum_i(c);
    if (c >= remaining) prefix = cmp; else remaining -= c;
  }
  int ceq = 0, cgt = 0;
#pragma unroll
  for (int i = 0; i < 16; i++) { ceq += (key[i] == prefix) ? 1 : 0; cgt += (key[i] > prefix) ? 1 : 0; }
  int v = ceq;
#pragma unroll
  for (int o = 1; o < 64; o <<= 1) { int u = __shfl_up(v, o, 64); if (l >= o) v += u; }
  int rank = v - ceq;
  int need = kTOPK - wsum_i(cgt);
  unsigned short mybits = 0;
#pragma unroll
  for (int i = 0; i < 16; i++) {
    int sel;
    if (key[i] > prefix) sel = 1;
    else if (key[i] == prefix) { sel = (rank < need) ? 1 : 0; rank++; }
    else sel = 0;
    mybits |= (unsigned short)(sel << i);
  }
  tmp[l] = mybits;
  __syncthreads();
  if (l < 16) {
    mrow[l] = (unsigned long long)tmp[4 * l] | ((unsigned long long)tmp[4 * l + 1] << 16) |
              ((unsigned long long)tmp[4 * l + 2] << 32) | ((unsigned long long)tmp[4 * l + 3] << 48);
  }
}

__global__ __launch_bounds__(64) void k_route(const float* __restrict__ hs2, const float* __restrict__ wg,
                                              int* __restrict__ cnt, int* __restrict__ toki,
                                              float* __restrict__ tokw) {
  int t = blockIdx.x; int l = threadIdx.x;
  float acc[8] = {};
  for (int d = l; d < kD; d += 64) {
    float hv = hs2[(size_t)t * kD + d];
    const float* wr = wg + (size_t)d * 8;
#pragma unroll
    for (int e = 0; e < 8; e++) acc[e] += hv * wr[e];
  }
#pragma unroll
  for (int e = 0; e < 8; e++) acc[e] = wsum(acc[e]);
  if (l == 0) {
    float g[8];
#pragma unroll
    for (int e = 0; e < 8; e++) g[e] = 1.0f / (1.0f + expf(-acc[e]));
    int i0 = 0;
    for (int e = 1; e < 8; e++) if (g[e] > g[i0]) i0 = e;
    int i1 = (i0 == 0) ? 1 : 0;
    for (int e = 0; e < 8; e++) if (e != i0 && g[e] > g[i1]) i1 = e;
    float ssum = g[i0] + g[i1];
    float w0 = g[i0] / ssum * 2.5f, w1 = g[i1] / ssum * 2.5f;
    int s0 = atomicAdd(&cnt[i0], 1); toki[i0 * kT + s0] = t; tokw[i0 * kT + s0] = w0;
    int s1 = atomicAdd(&cnt[i1], 1); toki[i1 * kT + s1] = t; tokw[i1 * kT + s1] = w1;
  }
}

// ---------------- launch ----------------
extern "C" void kernel_launch(void* const* d_in, const int* in_sizes, int n_in,
                              void* d_out, int out_size, void* d_ws, size_t ws_size,
                              hipStream_t stream) {
  (void)in_sizes; (void)n_in; (void)out_size; (void)ws_size;
  const int*   positions  = (const int*)d_in[0];
  const float* hidden     = (const float*)d_in[1];
  const float* residual   = (const float*)d_in[2];
  const float* input_ln_w = (const float*)d_in[3];
  const float* post_ln_w  = (const float*)d_in[4];
  const float* w_qkv_a    = (const float*)d_in[5];
  const float* q_a_ln_w   = (const float*)d_in[6];
  const float* w_q_b      = (const float*)d_in[7];
  const float* kv_a_ln_w  = (const float*)d_in[8];
  const float* w_kv_b     = (const float*)d_in[9];
  const float* w_o        = (const float*)d_in[10];
  const float* w_idx_q_b  = (const float*)d_in[11];
  const float* w_idx_k    = (const float*)d_in[12];
  const float* idx_k_ln_w = (const float*)d_in[13];
  const float* idx_k_ln_b = (const float*)d_in[14];
  const float* w_idx_w    = (const float*)d_in[15];
  const float* w_gate     = (const float*)d_in[16];
  const float* w_moe_gate = (const float*)d_in[17];
  const float* w_moe_up   = (const float*)d_in[18];
  const float* w_moe_down = (const float*)d_in[19];
  const float* w_sh_gate  = (const float*)d_in[20];
  const float* w_sh_up    = (const float*)d_in[21];
  const float* w_sh_down  = (const float*)d_in[22];

  float* out0 = (float*)d_out;
  float* out1 = out0 + (size_t)kT * kD;

  char* W = (char*)d_ws;
  size_t off = 0;
  auto alloc = [&](size_t bytes) { char* p = W + off; off += (bytes + 255) & ~(size_t)255; return p; };
  // f32 buffers
  float* resid   = (float*)alloc((size_t)kT * kD * 4);
  float* hs      = (float*)alloc((size_t)kT * kD * 4);
  float* qkvF    = (float*)alloc((size_t)kT * kQKV_F * 4);
  float* qb      = (float*)alloc((size_t)kT * kH * kQKD * 4);
  float* kvb     = (float*)alloc((size_t)kT * kH * 256 * 4);
  float* iqb     = (float*)alloc((size_t)kT * kIH * kID * 4);
  float* iksc    = (float*)alloc(kT * 4);
  float* iqsc    = (float*)alloc((size_t)kT * kIH * 4);
  float* iwb     = (float*)alloc((size_t)kT * kIH * 4);
  float* kpe     = (float*)alloc((size_t)kT * kROPE * 4);
  float* scoresb = (float*)alloc((size_t)kT * kT * 4);
  float* hs2     = (float*)alloc((size_t)kT * kD * 4);
  unsigned long long* mbits = (unsigned long long*)alloc((size_t)kT * 16 * 8);
  float* tokw    = (float*)alloc((size_t)kE * kT * 4);
  int*   toki    = (int*)alloc((size_t)kE * kT * 4);
  int*   cnt     = (int*)alloc(64);
  // split-K partial buffer ALIASED onto kvb+iqb (33.5 MB contiguous, both 256-aligned sizes).
  // Safe: qkvP is fully consumed by k_reduce4 before kvb/iqb are first written (same stream).
  float* qkvP    = kvb; // needs 4*kT*kQKV_F*4 = 25.2 MB <= 33.5 MB
  // bf16 activations
  u16* hs_h   = (u16*)alloc((size_t)kT * kD * 2);
  u16* hs_l   = (u16*)alloc((size_t)kT * kD * 2);
  u16* qc_h   = (u16*)alloc((size_t)kT * kQL * 2);
  u16* qc_l   = (u16*)alloc((size_t)kT * kQL * 2);
  u16* kvc_h  = (u16*)alloc((size_t)kT * kKVL * 2);
  u16* o_bf   = (u16*)alloc((size_t)kT * kH * kVD * 2);
  u16* hs2_h  = (u16*)alloc((size_t)kT * kD * 2);
  u16* sg_bf  = (u16*)alloc((size_t)kT * kF * 2);
  u16* hmid_bf= (u16*)alloc((size_t)kE * kT * kF * 2);
  u16* iq_bf  = (u16*)alloc((size_t)kT * kIH * kID * 2);
  u16* ik_bf  = (u16*)alloc((size_t)kT * kID * 2);
  // bf16 transposed weights (qkv fused buffer holds qkv rows 0..1407 + ik rows 1408..1535)
  u16* qkvBT_h = (u16*)alloc((size_t)kQKV_F * kD * 2);
  u16* qkvBT_l = (u16*)alloc((size_t)kQKV_F * kD * 2);
  u16* qbBT    = (u16*)alloc((size_t)kH * kQKD * kQL * 2);
  u16* kvbBT   = (u16*)alloc((size_t)kH * 256 * kKVL * 2);
  u16* woBT    = (u16*)alloc((size_t)kD * kH * kVD * 2);
  u16* iqBT_h  = (u16*)alloc((size_t)kIH * kID * kQL * 2);
  u16* iqBT_l  = (u16*)alloc((size_t)kIH * kID * kQL * 2);
  u16* shgBT   = (u16*)alloc((size_t)kF * kD * 2);
  u16* shuBT   = (u16*)alloc((size_t)kF * kD * 2);
  u16* shdBT   = (u16*)alloc((size_t)kD * kF * 2);
  u16* moegBT  = (u16*)alloc((size_t)kE * kF * kD * 2);
  u16* moeuBT  = (u16*)alloc((size_t)kE * kF * kD * 2);
  u16* moedBT  = (u16*)alloc((size_t)kE * kD * kF * 2);

  // ---- weight prep (runs every launch; inputs are constant) ----
  { dim3 g(kQKV_NP / 32, kD / 32); k_transpose_w<<<g, 256, 0, stream>>>(w_qkv_a, qkvBT_h, qkvBT_l, kD, kQKV_N, kQKV_NP); }
  { dim3 g(kID / 32, kD / 32); k_transpose_w<<<g, 256, 0, stream>>>(w_idx_k, qkvBT_h + (size_t)kIKOFF * kD, qkvBT_l + (size_t)kIKOFF * kD, kD, kID, kID); }
  { dim3 g(kH * kQKD / 32, kQL / 32); k_transpose_w<<<g, 256, 0, stream>>>(w_q_b, qbBT, nullptr, kQL, kH * kQKD, kH * kQKD); }
  { dim3 g(kH * 256 / 32, kKVL / 32); k_transpose_w<<<g, 256, 0, stream>>>(w_kv_b, kvbBT, nullptr, kKVL, kH * 256, kH * 256); }
  { dim3 g(kD / 32, kH * kVD / 32); k_transpose_w<<<g, 256, 0, stream>>>(w_o, woBT, nullptr, kH * kVD, kD, kD); }
  { dim3 g(kIH * kID / 32, kQL / 32); k_transpose_w<<<g, 256, 0, stream>>>(w_idx_q_b, iqBT_h, iqBT_l, kQL, kIH * kID, kIH * kID); }
  { dim3 g(kF / 32, kD / 32); k_transpose_w<<<g, 256, 0, stream>>>(w_sh_gate, shgBT, nullptr, kD, kF, kF); }
  { dim3 g(kF / 32, kD / 32); k_transpose_w<<<g, 256, 0, stream>>>(w_sh_up, shuBT, nullptr, kD, kF, kF); }
  { dim3 g(kD / 32, kF / 32); k_transpose_w<<<g, 256, 0, stream>>>(w_sh_down, shdBT, nullptr, kF, kD, kD); }
  { dim3 g(kF / 32, kD / 32, kE); k_transpose_w<<<g, 256, 0, stream>>>(w_moe_gate, moegBT, nullptr, kD, kF, kF); }
  { dim3 g(kF / 32, kD / 32, kE); k_transpose_w<<<g, 256, 0, stream>>>(w_moe_up, moeuBT, nullptr, kD, kF, kF); }
  { dim3 g(kD / 32, kF / 32, kE); k_transpose_w<<<g, 256, 0, stream>>>(w_moe_down, moedBT, nullptr, kF, kD, kD); }

  // ---- forward ----
  k_add_rms<<<kT, 256, 0, stream>>>(hidden, residual, input_ln_w, resid, hs, hs_h, hs_l);
  // fused qkv+ik GEMM, split-K x4 over K=2048; partials in qkvP (aliased), reduced into qkvF
  { dim3 g(kQKV_F / 128, kT / 128, 4); k_gemm_splitk<<<g, 256, 0, stream>>>(hs_h, hs_l, qkvBT_h, qkvBT_l, qkvP, kT, kQKV_F, kD, kD / 4); }
  { int n4 = kT * kQKV_F / 4; k_reduce4<<<(n4 + 255) / 256, 256, 0, stream>>>(qkvP, qkvF, n4); }
  k_rms_rows<<<kT, 256, 0, stream>>>(qkvF, kQKV_F, 0, q_a_ln_w, nullptr, qc_h, qc_l, kQL);
  k_rms_rows<<<kT, 256, 0, stream>>>(qkvF, kQKV_F, kQL, kv_a_ln_w, nullptr, kvc_h, nullptr, kKVL);
  { dim3 g(kH * kQKD / 128, kT / 128); k_gemm_bt<<<g, 256, 0, stream>>>(qc_h, qbBT, qb, nullptr, kT, kH * kQKD, kQL); }
  { dim3 g(kIH * kID / 128, kT / 128); k_gemm_split<<<g, 256, 0, stream>>>(qc_h, qc_l, iqBT_h, iqBT_l, iqb, kT, kIH * kID, kQL); }
  { dim3 g(kH * 256 / 128, kT / 128); k_gemm_bt<<<g, 256, 0, stream>>>(kvc_h, kvbBT, kvb, nullptr, kT, kH * 256, kKVL); }
  k_rope_q<<<kT, 256, 0, stream>>>(qb, positions);
  k_rope_iq<<<kT, 256, 0, stream>>>(iqb, positions);
  k_rope_kpe<<<kT, 64, 0, stream>>>(qkvF, kQKV_F, positions, kpe);
  k_quant_rows<<<kT * kIH, 64, 0, stream>>>(iqb, iq_bf, iqsc);
  k_ik_process<<<kT, 64, 0, stream>>>(qkvF + kIKOFF, kQKV_F, idx_k_ln_w, idx_k_ln_b, positions, ik_bf, iksc);
  k_iw_fused<<<kT, 256, 0, stream>>>(hs, w_idx_w, iqsc, iwb);
  { dim3 g(kT / 128, kT / 4); k_scores_mfma<<<g, 256, 0, stream>>>(iq_bf, ik_bf, iksc, iwb, scoresb); }
  k_topk<<<kT, 64, 0, stream>>>(scoresb, mbits);
  { dim3 g(kT / 64, kH); k_attn_mfma<<<g, 256, 0, stream>>>(qb, kvb, kpe, mbits, o_bf); }
  { dim3 g(kD / 128, kT / 128); k_gemm_bt<<<g, 256, 0, stream>>>(o_bf, woBT, out1, resid, kT, kD, kH * kVD); }
  k_rms_rows<<<kT, 256, 0, stream>>>(out1, kD, 0, post_ln_w, hs2, hs2_h, nullptr, kD);
  hipMemsetAsync(cnt, 0, 8 * sizeof(int), stream);
  k_route<<<kT, 64, 0, stream>>>(hs2, w_gate, cnt, toki, tokw);
  // merged shared+expert gate/up: z=0 shared, z=1..8 experts
  { dim3 g(kF / 64, kT / 64, kE + 1);
    k_dual_all<<<g, 256, 0, stream>>>(hs2_h, shgBT, shuBT, moegBT, moeuBT, sg_bf, hmid_bf, toki, cnt, kF, kD); }
  // merged down projection into zeroed out0
  hipMemsetAsync(out0, 0, (size_t)kT * kD * 4, stream);
  { dim3 g(kD / 128, kT / 64, kE + 1);
    k_down_all<<<g, 256, 0, stream>>>(sg_bf, shdBT, hmid_bf, moedBT, toki, tokw, cnt, out0); }
}